// Round 5
// baseline (460.049 us; speedup 1.0000x reference)
//
#include <hip/hip_runtime.h>

// GCN-VAE encoder forward on MI355X — R9: fuse gather_hidden + GEMM2.
//
// agg[d] = dinv[d] * ( hs[d] + sum_{s in N(d)} hs[s] ),  hs := h*dinv
// hs1, hs2 stored bf16 (RTN) -> gather traffic halves.
// hidden kept bf16 hi+lo (exact split) -> GEMM2 keeps 3-term precision,
// but (R9) hidden is NEVER materialized to HBM: gather_gemm2 builds the
// 64x128 hidden tile in LDS (gather+relu+split2, swizzled) and feeds the
// MFMA K-loop directly. Kills 102MB of sequential HBM (write+read) and a
// launch. R8 post-mortem: gathers are at the random-256B BW wall (~3.8TB/s,
// unroll/NT neutral) -> only traffic cuts help.
//
// A-tile LDS swizzle: 16B granule slot = c ^ (row&7). write 16 slots/quarter
// (2-way free), read 8 slots per 8 rows (2-way free).
//
// R6: GEMM1 2-phase global_load_lds pipeline (src-side XOR swizzle).
// R5 CSR build: group_count -> goff_scan -> partition -> build_csr.
//
// ws: hs1[N*128]bf | (2 reserved slots) | hs2[N*128]bf (aliased staged[E]
//     during CSR build) | cnt[N] | dinv[N] | rowptr[N] | cursor[N] |
//     bsum[512] | bcat[128] | w1t_h/l | wct_h/l | csr[E]

#define TPB 256
#define GSHIFT 9
#define GSIZE 512
#define PART_M 8192  // edges per partition WG

typedef __attribute__((ext_vector_type(8))) short short8;
typedef __attribute__((ext_vector_type(4))) short short4v;
typedef __attribute__((ext_vector_type(4))) float floatx4;
typedef __attribute__((ext_vector_type(4))) unsigned int uint4v;

__device__ __forceinline__ void split2(float v, short& hi, short& lo) {
    unsigned u = __float_as_uint(v);
    float hf = __uint_as_float(u & 0xFFFF0000u);
    float lf = v - hf;                       // exact
    hi = (short)(u >> 16);
    lo = (short)(__float_as_uint(lf) >> 16);
}

__device__ __forceinline__ short bf16_rtn(float v) {
    unsigned u = __float_as_uint(v);
    u += 0x7FFF + ((u >> 16) & 1);           // round to nearest even
    return (short)(u >> 16);
}

__device__ __forceinline__ void addrow(float* a, uint4v v) {
    a[0] += __uint_as_float(v[0] << 16); a[1] += __uint_as_float(v[0] & 0xFFFF0000u);
    a[2] += __uint_as_float(v[1] << 16); a[3] += __uint_as_float(v[1] & 0xFFFF0000u);
    a[4] += __uint_as_float(v[2] << 16); a[5] += __uint_as_float(v[2] & 0xFFFF0000u);
    a[6] += __uint_as_float(v[3] << 16); a[7] += __uint_as_float(v[3] & 0xFFFF0000u);
}

// shared gather loop: acc += sum of neighbor rows (16B chunk per lane)
__device__ __forceinline__ void gather_accum(float* acc, const int* __restrict__ csr,
                                             int start, int deg, const uint4v* hp,
                                             int lane) {
    int j = 0;
    for (; j + 3 < deg; j += 4) {
        int s0 = csr[start + j], s1 = csr[start + j + 1];
        int s2 = csr[start + j + 2], s3 = csr[start + j + 3];
        uint4v v0 = hp[(size_t)s0 * 16 + lane];
        uint4v v1 = hp[(size_t)s1 * 16 + lane];
        uint4v v2 = hp[(size_t)s2 * 16 + lane];
        uint4v v3 = hp[(size_t)s3 * 16 + lane];
        addrow(acc, v0);
        addrow(acc, v1);
        addrow(acc, v2);
        addrow(acc, v3);
    }
    if (j + 1 < deg) {
        int s0 = csr[start + j], s1 = csr[start + j + 1];
        uint4v v0 = hp[(size_t)s0 * 16 + lane];
        uint4v v1 = hp[(size_t)s1 * 16 + lane];
        addrow(acc, v0);
        addrow(acc, v1);
        j += 2;
    }
    if (j < deg) addrow(acc, hp[(size_t)csr[start + j] * 16 + lane]);
}

// async 16B global -> LDS (linear dest: wave-uniform base + lane*16)
__device__ __forceinline__ void gload_lds16(const void* g, void* l) {
    __builtin_amdgcn_global_load_lds(
        (const __attribute__((address_space(1))) unsigned int*)g,
        (__attribute__((address_space(3))) unsigned int*)l, 16, 0, 0);
}

// ---------------- CSR build, stage 1: group-level histogram ----------------
__global__ __launch_bounds__(TPB) void group_count(const int* __restrict__ dst,
                                                   int* __restrict__ ghist, int E) {
    __shared__ int h[256];
    int t = threadIdx.x;
    h[t] = 0;
    __syncthreads();
    int stride = gridDim.x * TPB;
    for (int k = blockIdx.x * TPB + t; k < E; k += stride)
        atomicAdd(&h[dst[k] >> GSHIFT], 1);
    __syncthreads();
    if (h[t]) atomicAdd(&ghist[t], h[t]);
}

// ---------------- stage 2: exclusive scan of group counts ----------------
__global__ __launch_bounds__(256) void goff_scan(const int* __restrict__ ghist,
                                                 int* __restrict__ goff, int ngrp) {
    __shared__ int sc[256];
    int t = threadIdx.x;
    int v = (t < ngrp) ? ghist[t] : 0;
    sc[t] = v;
    __syncthreads();
#pragma unroll
    for (int off = 1; off < 256; off <<= 1) {
        int x = (t >= off) ? sc[t - off] : 0;
        __syncthreads();
        sc[t] += x;
        __syncthreads();
    }
    goff[t] = sc[t] - v;                 // exclusive; == E for t >= ngrp
    if (t == 255) goff[256] = sc[255];   // sentinel = E
}

// ---------------- stage 3: partition edges into group segments ----------------
__global__ __launch_bounds__(256) void partition_kernel(const int* __restrict__ src,
                                                        const int* __restrict__ dst,
                                                        const int* __restrict__ goff,
                                                        int* __restrict__ gcur,
                                                        int* __restrict__ staged, int E) {
    __shared__ int sorted[PART_M];
    __shared__ int sc[256];
    __shared__ int lstart[257];
    __shared__ int cur[256];
    __shared__ int gb[256];
    int t = threadIdx.x;
    int base = blockIdx.x * PART_M;
    int mloc = min(PART_M, E - base);

    sc[t] = 0;
    cur[t] = 0;
    __syncthreads();
    for (int k = t; k < mloc; k += 256)
        atomicAdd(&sc[dst[base + k] >> GSHIFT], 1);
    __syncthreads();
    int v = sc[t];
    __syncthreads();
    sc[t] = v;
    __syncthreads();
#pragma unroll
    for (int off = 1; off < 256; off <<= 1) {
        int x = (t >= off) ? sc[t - off] : 0;
        __syncthreads();
        sc[t] += x;
        __syncthreads();
    }
    lstart[t] = sc[t] - v;
    if (t == 255) lstart[256] = sc[255];
    gb[t] = goff[t] + atomicAdd(&gcur[t], v);
    __syncthreads();
    for (int k = t; k < mloc; k += 256) {
        int d = dst[base + k];
        int s = src[base + k];
        int b = d >> GSHIFT;
        int pos = lstart[b] + atomicAdd(&cur[b], 1);
        sorted[pos] = (s << GSHIFT) | (d & (GSIZE - 1));
    }
    __syncthreads();
    for (int e = t; e < mloc; e += 256) {
        int lo = 0, hi = 256;
        while (hi - lo > 1) {
            int mid = (lo + hi) >> 1;
            if (lstart[mid] <= e) lo = mid; else hi = mid;
        }
        staged[gb[lo] + (e - lstart[lo])] = sorted[e];
    }
}

// ---------------- stage 4: per-group CSR finalize ----------------
__global__ __launch_bounds__(512) void build_csr(const int* __restrict__ staged,
                                                 const int* __restrict__ goff,
                                                 int* __restrict__ cnt,
                                                 float* __restrict__ dinv,
                                                 int* __restrict__ rowptr,
                                                 int* __restrict__ csr, int N) {
    __shared__ int hist[512];
    __shared__ int sc[512];
    __shared__ int lrow[512];
    __shared__ int cur[512];
    int t = threadIdx.x;
    int g = blockIdx.x;
    int s0 = goff[g], s1 = goff[g + 1];
    hist[t] = 0;
    cur[t] = 0;
    __syncthreads();
    for (int k = s0 + t; k < s1; k += 512)
        atomicAdd(&hist[staged[k] & (GSIZE - 1)], 1);
    __syncthreads();
    int v = hist[t];
    sc[t] = v;
    __syncthreads();
#pragma unroll
    for (int off = 1; off < 512; off <<= 1) {
        int x = (t >= off) ? sc[t - off] : 0;
        __syncthreads();
        sc[t] += x;
        __syncthreads();
    }
    int rp = s0 + sc[t] - v;
    lrow[t] = rp;
    int node = (g << GSHIFT) + t;
    if (node < N) {
        rowptr[node] = rp;
        cnt[node] = v;
        dinv[node] = rsqrtf(1.0f + (float)v);
    }
    __syncthreads();
    for (int k = s0 + t; k < s1; k += 512) {
        int p = staged[k];
        int dl = p & (GSIZE - 1);
        int pos = lrow[dl] + atomicAdd(&cur[dl], 1);
        csr[pos] = p >> GSHIFT;
    }
}

// ---------------- weight prep: transpose + hi/lo split ----------------
__global__ void prep_w1t(const float* __restrict__ w1, short* __restrict__ th,
                         short* __restrict__ tl) {
    int t = blockIdx.x * TPB + threadIdx.x;  // t < 128*256
    int k = t & 255, n = t >> 8;
    float v = w1[(size_t)k * 128 + n];
    short h, l;
    split2(v, h, l);
    th[t] = h;
    tl[t] = l;
}

__global__ void prep_wcatt(const float* __restrict__ w2, const float* __restrict__ b2,
                           const float* __restrict__ w3, const float* __restrict__ b3,
                           short* __restrict__ th, short* __restrict__ tl,
                           float* __restrict__ bcat) {
    int t = blockIdx.x * TPB + threadIdx.x;  // t < 128*128
    int k = t & 127, n = t >> 7;
    float v = (n < 64) ? w2[(size_t)k * 64 + n] : w3[(size_t)k * 64 + (n - 64)];
    short h, l;
    split2(v, h, l);
    th[t] = h;
    tl[t] = l;
    if (t < 64) { bcat[t] = b2[t]; bcat[64 + t] = b3[t]; }
}

// ---------------- MFMA GEMM1 (pipelined): Cb[M,128]bf = (A_f32[M,K] @ B) * rs ----------------
__global__ __launch_bounds__(TPB) void gemm_mfma_f32in(const float* __restrict__ A,
                                                       const short* __restrict__ Bth,
                                                       const short* __restrict__ Btl,
                                                       const float* __restrict__ rs,
                                                       short* __restrict__ Cb, int M, int K) {
    __shared__ float Af[2][64 * 32];           // 2 x 8KB, granule col ^= (row&7)
    __shared__ short Bh[2][128 * 32];          // 2 x 8KB, granule col ^= ((row>>1)&3)
    __shared__ short Bl[2][128 * 32];
    int t = threadIdx.x;
    int wave = t >> 6, lane = t & 63, quad = lane >> 4, l16 = lane & 15;
    int bm0 = blockIdx.x * 64;

    floatx4 acc[8];
#pragma unroll
    for (int nt = 0; nt < 8; ++nt) acc[nt] = (floatx4){0.f, 0.f, 0.f, 0.f};

    auto stage = [&](int pb, int k0) {
#pragma unroll
        for (int i = 0; i < 2; ++i) {
            int g = i * 256 + t;
            int row = g >> 3, col = g & 7;
            int gr = bm0 + row;
            if (gr >= M) gr = M - 1;           // clamp: no per-lane predication
            int scol = col ^ (row & 7);
            gload_lds16(A + (size_t)gr * K + k0 + scol * 4,
                        &Af[pb][(i * 256 + wave * 64) * 4]);
        }
#pragma unroll
        for (int i = 0; i < 2; ++i) {
            int g = i * 256 + t;
            int row = g >> 2, col = g & 3;
            int scol = col ^ ((row >> 1) & 3);
            size_t off = (size_t)row * K + k0 + scol * 8;
            int lb = (i * 256 + wave * 64) * 8;
            gload_lds16(Bth + off, &Bh[pb][lb]);
            gload_lds16(Btl + off, &Bl[pb][lb]);
        }
    };

    int nk = K >> 5;
    stage(0, 0);
    __syncthreads();
    int am = wave * 16 + l16;
    int ac0 = ((quad * 2 + 0) ^ (am & 7)) * 4;
    int ac1 = ((quad * 2 + 1) ^ (am & 7)) * 4;
    int bc = (quad ^ ((l16 >> 1) & 3)) * 8;
    for (int ks = 0; ks < nk; ++ks) {
        int pb = ks & 1;
        if (ks + 1 < nk) stage(pb ^ 1, (ks + 1) << 5);
        float4 fa0 = *(const float4*)&Af[pb][am * 32 + ac0];
        float4 fa1 = *(const float4*)&Af[pb][am * 32 + ac1];
        short8 a_h, a_l;
        {
            short h, l;
            split2(fa0.x, h, l); a_h[0] = h; a_l[0] = l;
            split2(fa0.y, h, l); a_h[1] = h; a_l[1] = l;
            split2(fa0.z, h, l); a_h[2] = h; a_l[2] = l;
            split2(fa0.w, h, l); a_h[3] = h; a_l[3] = l;
            split2(fa1.x, h, l); a_h[4] = h; a_l[4] = l;
            split2(fa1.y, h, l); a_h[5] = h; a_l[5] = l;
            split2(fa1.z, h, l); a_h[6] = h; a_l[6] = l;
            split2(fa1.w, h, l); a_h[7] = h; a_l[7] = l;
        }
#pragma unroll
        for (int nt = 0; nt < 8; ++nt) {
            int bn = nt * 16 + l16;
            short8 b_h = *(const short8*)&Bh[pb][bn * 32 + bc];
            short8 b_l = *(const short8*)&Bl[pb][bn * 32 + bc];
            acc[nt] = __builtin_amdgcn_mfma_f32_16x16x32_bf16(a_l, b_h, acc[nt], 0, 0, 0);
            acc[nt] = __builtin_amdgcn_mfma_f32_16x16x32_bf16(a_h, b_l, acc[nt], 0, 0, 0);
            acc[nt] = __builtin_amdgcn_mfma_f32_16x16x32_bf16(a_h, b_h, acc[nt], 0, 0, 0);
        }
        __syncthreads();
    }
#pragma unroll
    for (int reg = 0; reg < 4; ++reg) {
        int gr = bm0 + wave * 16 + quad * 4 + reg;
        if (gr < M) {
            float s = rs[gr];
            short* cp = Cb + (size_t)gr * 128;
#pragma unroll
            for (int nt = 0; nt < 8; ++nt) cp[nt * 16 + l16] = bf16_rtn(acc[nt][reg] * s);
        }
    }
}

// ---------------- fused gather+GEMM2: hs2 = ((relu(agg1)+b) @ Wcat) * dinv ----------------
// Phase 1: gather 64 hidden rows (relu(dinv*(self+nbrs)+b1)) -> LDS hi/lo,
//          granule slot = c ^ (row&7). B k-step 0 prefetch hides under it.
// Phase 2: K=128 MFMA loop, A from static LDS, B double-buffered gload_lds.
__global__ __launch_bounds__(TPB) void gather_gemm2(const int* __restrict__ csr,
                                                    const int* __restrict__ rowptr,
                                                    const int* __restrict__ cnt,
                                                    const float* __restrict__ dinv,
                                                    const short* __restrict__ hs,
                                                    const float* __restrict__ b1,
                                                    const short* __restrict__ Bth,
                                                    const short* __restrict__ Btl,
                                                    short* __restrict__ Cb, int N) {
    __shared__ short Ah[64 * 128], Al[64 * 128];       // 16KB each, swizzled
    __shared__ short Bh[2][128 * 32], Bl[2][128 * 32]; // 8KB each buf
    int t = threadIdx.x;
    int wave = t >> 6, lane = t & 63, quad = lane >> 4, l16 = lane & 15;
    int bm0 = blockIdx.x * 64;

    auto stageB = [&](int pb, int k0) {
#pragma unroll
        for (int i = 0; i < 2; ++i) {
            int g = i * 256 + t;
            int row = g >> 2, col = g & 3;
            int scol = col ^ ((row >> 1) & 3);
            size_t off = (size_t)row * 128 + k0 + scol * 8;
            int lb = (i * 256 + wave * 64) * 8;
            gload_lds16(Bth + off, &Bh[pb][lb]);
            gload_lds16(Btl + off, &Bl[pb][lb]);
        }
    };

    stageB(0, 0);  // prefetch B k-step 0 under the gather

    // ---- phase 1: gather + relu + split2 -> LDS A tile ----
    {
        const uint4v* hp = (const uint4v*)hs;
        int nrow = t >> 4;  // 0..15 (node within sweep), l16 = 16B granule
        float4 c0 = ((const float4*)b1)[l16 * 2];
        float4 c1 = ((const float4*)b1)[l16 * 2 + 1];
        float bb[8] = {c0.x, c0.y, c0.z, c0.w, c1.x, c1.y, c1.z, c1.w};
#pragma unroll
        for (int sw = 0; sw < 4; ++sw) {
            int r = sw * 16 + nrow;
            int nid = bm0 + r;
            int nc = (nid < N) ? nid : N - 1;
            int start = rowptr[nc];
            int deg = cnt[nc];
            float acc[8] = {0, 0, 0, 0, 0, 0, 0, 0};
            addrow(acc, __builtin_nontemporal_load(&hp[(size_t)nc * 16 + l16]));
            gather_accum(acc, csr, start, deg, hp, l16);
            float di = dinv[nc];
            unsigned hiw[8];
            short low[8];
#pragma unroll
            for (int i = 0; i < 8; ++i) {
                float h = fmaxf(fmaf(di, acc[i], bb[i]), 0.f);
                unsigned u = __float_as_uint(h);
                hiw[i] = u >> 16;
                float hf = __uint_as_float(u & 0xFFFF0000u);
                low[i] = bf16_rtn(h - hf);
            }
            uint4v ph, pl;
            ph[0] = hiw[0] | (hiw[1] << 16);
            ph[1] = hiw[2] | (hiw[3] << 16);
            ph[2] = hiw[4] | (hiw[5] << 16);
            ph[3] = hiw[6] | (hiw[7] << 16);
            pl[0] = (unsigned short)low[0] | ((unsigned)(unsigned short)low[1] << 16);
            pl[1] = (unsigned short)low[2] | ((unsigned)(unsigned short)low[3] << 16);
            pl[2] = (unsigned short)low[4] | ((unsigned)(unsigned short)low[5] << 16);
            pl[3] = (unsigned short)low[6] | ((unsigned)(unsigned short)low[7] << 16);
            int slot = l16 ^ (r & 7);
            *(uint4v*)&Ah[r * 128 + slot * 8] = ph;
            *(uint4v*)&Al[r * 128 + slot * 8] = pl;
        }
    }
    __syncthreads();  // A complete; B buf0 complete (vmcnt drained at barrier)

    // ---- phase 2: MFMA K-loop ----
    floatx4 acc2[8];
#pragma unroll
    for (int nt = 0; nt < 8; ++nt) acc2[nt] = (floatx4){0.f, 0.f, 0.f, 0.f};
    int am = wave * 16 + l16;
    int bc = (quad ^ ((l16 >> 1) & 3)) * 8;
    for (int ks = 0; ks < 4; ++ks) {
        int pb = ks & 1;
        if (ks + 1 < 4) stageB(pb ^ 1, (ks + 1) * 32);
        int c = ks * 4 + quad;
        int slot = c ^ (am & 7);
        short8 a_h = *(const short8*)&Ah[am * 128 + slot * 8];
        short8 a_l = *(const short8*)&Al[am * 128 + slot * 8];
#pragma unroll
        for (int nt = 0; nt < 8; ++nt) {
            int bn = nt * 16 + l16;
            short8 b_h = *(const short8*)&Bh[pb][bn * 32 + bc];
            short8 b_l = *(const short8*)&Bl[pb][bn * 32 + bc];
            acc2[nt] = __builtin_amdgcn_mfma_f32_16x16x32_bf16(a_l, b_h, acc2[nt], 0, 0, 0);
            acc2[nt] = __builtin_amdgcn_mfma_f32_16x16x32_bf16(a_h, b_l, acc2[nt], 0, 0, 0);
            acc2[nt] = __builtin_amdgcn_mfma_f32_16x16x32_bf16(a_h, b_h, acc2[nt], 0, 0, 0);
        }
        __syncthreads();
    }
#pragma unroll
    for (int reg = 0; reg < 4; ++reg) {
        int gr = bm0 + wave * 16 + quad * 4 + reg;
        if (gr < N) {
            float s = dinv[gr];
            short* cp = Cb + (size_t)gr * 128;
#pragma unroll
            for (int nt = 0; nt < 8; ++nt) cp[nt * 16 + l16] = bf16_rtn(acc2[nt][reg] * s);
        }
    }
}

// ---------------- gather 2: out = dinv*(self+sum nbrs) + bcat -> f32 mu|logvar ----------------
__global__ __launch_bounds__(TPB) void gather_out(const int* __restrict__ csr,
                                                  const int* __restrict__ rowptr,
                                                  const int* __restrict__ cnt,
                                                  const float* __restrict__ dinv,
                                                  const short* __restrict__ hs,
                                                  const float* __restrict__ bcat,
                                                  float* __restrict__ out, int N) {
    size_t t = (size_t)blockIdx.x * TPB + threadIdx.x;
    int nid = (int)(t >> 4);
    int lane = threadIdx.x & 15;
    if (nid >= N) return;
    int start = rowptr[nid];
    int deg = cnt[nid];
    const uint4v* hp = (const uint4v*)hs;
    float acc[8] = {0, 0, 0, 0, 0, 0, 0, 0};
    addrow(acc, __builtin_nontemporal_load(&hp[(size_t)nid * 16 + lane]));
    gather_accum(acc, csr, start, deg, hp, lane);
    float di = dinv[nid];
    float4 b0 = ((const float4*)bcat)[lane * 2];
    float4 b1v = ((const float4*)bcat)[lane * 2 + 1];
    floatx4 r0, r1;
    r0[0] = fmaf(di, acc[0], b0.x);
    r0[1] = fmaf(di, acc[1], b0.y);
    r0[2] = fmaf(di, acc[2], b0.z);
    r0[3] = fmaf(di, acc[3], b0.w);
    r1[0] = fmaf(di, acc[4], b1v.x);
    r1[1] = fmaf(di, acc[5], b1v.y);
    r1[2] = fmaf(di, acc[6], b1v.z);
    r1[3] = fmaf(di, acc[7], b1v.w);
    int f = lane * 8;  // 0..120
    float* dp = (f < 64) ? (out + (size_t)nid * 64 + f)
                         : (out + (size_t)N * 64 + (size_t)nid * 64 + (f - 64));
    __builtin_nontemporal_store(r0, (floatx4*)dp);
    __builtin_nontemporal_store(r1, (floatx4*)(dp + 4));
}

extern "C" void kernel_launch(void* const* d_in, const int* in_sizes, int n_in,
                              void* d_out, int out_size, void* d_ws, size_t ws_size,
                              hipStream_t stream) {
    const float* x  = (const float*)d_in[0];
    const float* w1 = (const float*)d_in[1];
    const float* b1 = (const float*)d_in[2];
    const float* w2 = (const float*)d_in[3];
    const float* b2 = (const float*)d_in[4];
    const float* w3 = (const float*)d_in[5];
    const float* b3 = (const float*)d_in[6];
    const int*   ei = (const int*)d_in[7];

    const int N = in_sizes[0] / 256;   // 100000
    const int E = in_sizes[7] / 2;     // 1600000
    const int K1 = 256;

    float* out = (float*)d_out;

    // workspace carve-up (layout stable; slots 1-2 now unused)
    size_t nh = (size_t)N * 128;
    short* hs1    = (short*)d_ws;          // N*128 bf16
    short* hs2    = hs1 + 3 * nh;          // (skips 2 reserved slots)
    int*   cnt    = (int*)(hs2 + nh);
    float* dinv   = (float*)(cnt + N);
    int*   rowptr = (int*)(dinv + N);
    int*   cursor = rowptr + N;            // reused: ghist | gcur | goff
    int*   bsum   = cursor + N;
    float* bcat   = (float*)(bsum + 512);
    short* w1t_h  = (short*)(bcat + 128);
    short* w1t_l  = w1t_h + 128 * 256;
    short* wct_h  = w1t_l + 128 * 256;
    short* wct_l  = wct_h + 128 * 128;
    int*   csr    = (int*)(wct_l + 128 * 128);

    const int* srcp = ei;
    const int* dstp = ei + E;

    const int ngrp = (N + GSIZE - 1) >> GSHIFT;   // 196
    int* ghist  = cursor;        // [256]
    int* gcur   = cursor + 256;  // [256]
    int* goff   = cursor + 512;  // [257]
    int* staged = (int*)hs2;     // alias: hs2 not live until gather_gemm2

    // 0) zero group counters/cursors
    hipMemsetAsync(cursor, 0, 512 * sizeof(int), stream);

    // 1) CSR build: group hist -> scan -> partition -> per-group finalize
    int gc_blocks = (E + TPB * 16 - 1) / (TPB * 16);
    group_count<<<gc_blocks, TPB, 0, stream>>>(dstp, ghist, E);
    goff_scan<<<1, 256, 0, stream>>>(ghist, goff, ngrp);
    partition_kernel<<<(E + PART_M - 1) / PART_M, 256, 0, stream>>>(srcp, dstp, goff, gcur,
                                                                    staged, E);
    build_csr<<<ngrp, 512, 0, stream>>>(staged, goff, cnt, dinv, rowptr, csr, N);

    // 2) weight prep
    prep_w1t<<<(128 * 256) / TPB, TPB, 0, stream>>>(w1, w1t_h, w1t_l);
    prep_wcatt<<<(128 * 128) / TPB, TPB, 0, stream>>>(w2, b2, w3, b3, wct_h, wct_l, bcat);

    // 3) hs1 = (x @ w1) * dinv  -> bf16
    gemm_mfma_f32in<<<(N + 63) / 64, TPB, 0, stream>>>(x, w1t_h, w1t_l, dinv, hs1, N, K1);

    // 4) fused: hidden tile in LDS (gather+relu) -> GEMM2 -> hs2 bf16
    gather_gemm2<<<(N + 63) / 64, TPB, 0, stream>>>(csr, rowptr, cnt, dinv, hs1, b1,
                                                    wct_h, wct_l, hs2, N);

    // 5) out = dinv*(self+nbrs) + bcat -> mu | logvar (f32)
    size_t gthreads = (size_t)N * 16;
    gather_out<<<(unsigned)((gthreads + TPB - 1) / TPB), TPB, 0, stream>>>(
        csr, rowptr, cnt, dinv, hs2, bcat, out, N);
}

// Round 6
// 425.655 us; speedup vs baseline: 1.0808x; 1.0808x over previous
//
#include <hip/hip_runtime.h>

// GCN-VAE encoder forward on MI355X — R10: R8 structure + dispatch-count cuts.
//
// agg[d] = dinv[d] * ( hs[d] + sum_{s in N(d)} hs[s] ),  hs := h*dinv
// hs1, hs2 stored bf16 (RTN); hidden bf16 hi+lo (exact split).
//
// R9 post-mortem: fusing gather into the 64KB-LDS GEMM dropped occupancy
// 70%->18% and halved gather BW (125us vs 97us split). REVERTED to R8's
// separate kernels (gathers at the random-256B BW wall ~3.8TB/s).
//
// R10: attack inter-dispatch overhead (~100-140us of the 432us wall is not
// in any kernel): 11 -> 8 dispatches.
//   - prep_all: w1t split + wcat split + bcat + counter zeroing in ONE kernel
//     (replaces memset + prep_w1t + prep_wcatt).
//   - group_count: int4 edge loads + last-block-done pattern runs the 196-wide
//     goff scan inline (replaces goff_scan dispatch; no 1-block idle kernel).
//   - partition: int4 edge loads.
//
// ws: hs1[N*128]bf | hidH[N*128]bf | hidL[N*128]bf | hs2[N*128]bf (aliased as
//     staged[E] during CSR build) | cnt[N] | dinv[N] | rowptr[N] |
//     cursor[N] (ghist[256]|gcur[256]|done|goff[257]) | bsum[512] | bcat[128] |
//     w1t_h/l[128*256]bf | wct_h/l[128*128]bf | csr[E]

#define TPB 256
#define GSHIFT 9
#define GSIZE 512
#define PART_M 8192  // edges per partition WG

typedef __attribute__((ext_vector_type(8))) short short8;
typedef __attribute__((ext_vector_type(4))) short short4v;
typedef __attribute__((ext_vector_type(4))) float floatx4;
typedef __attribute__((ext_vector_type(4))) unsigned int uint4v;

__device__ __forceinline__ void split2(float v, short& hi, short& lo) {
    unsigned u = __float_as_uint(v);
    float hf = __uint_as_float(u & 0xFFFF0000u);
    float lf = v - hf;                       // exact
    hi = (short)(u >> 16);
    lo = (short)(__float_as_uint(lf) >> 16);
}

__device__ __forceinline__ short bf16_rtn(float v) {
    unsigned u = __float_as_uint(v);
    u += 0x7FFF + ((u >> 16) & 1);           // round to nearest even
    return (short)(u >> 16);
}

__device__ __forceinline__ void addrow(float* a, uint4v v) {
    a[0] += __uint_as_float(v[0] << 16); a[1] += __uint_as_float(v[0] & 0xFFFF0000u);
    a[2] += __uint_as_float(v[1] << 16); a[3] += __uint_as_float(v[1] & 0xFFFF0000u);
    a[4] += __uint_as_float(v[2] << 16); a[5] += __uint_as_float(v[2] & 0xFFFF0000u);
    a[6] += __uint_as_float(v[3] << 16); a[7] += __uint_as_float(v[3] & 0xFFFF0000u);
}

// shared gather loop: acc += sum of neighbor rows (16B chunk per lane)
__device__ __forceinline__ void gather_accum(float* acc, const int* __restrict__ csr,
                                             int start, int deg, const uint4v* hp,
                                             int lane) {
    int j = 0;
    for (; j + 3 < deg; j += 4) {
        int s0 = csr[start + j], s1 = csr[start + j + 1];
        int s2 = csr[start + j + 2], s3 = csr[start + j + 3];
        uint4v v0 = hp[(size_t)s0 * 16 + lane];
        uint4v v1 = hp[(size_t)s1 * 16 + lane];
        uint4v v2 = hp[(size_t)s2 * 16 + lane];
        uint4v v3 = hp[(size_t)s3 * 16 + lane];
        addrow(acc, v0);
        addrow(acc, v1);
        addrow(acc, v2);
        addrow(acc, v3);
    }
    if (j + 1 < deg) {
        int s0 = csr[start + j], s1 = csr[start + j + 1];
        uint4v v0 = hp[(size_t)s0 * 16 + lane];
        uint4v v1 = hp[(size_t)s1 * 16 + lane];
        addrow(acc, v0);
        addrow(acc, v1);
        j += 2;
    }
    if (j < deg) addrow(acc, hp[(size_t)csr[start + j] * 16 + lane]);
}

// async 16B global -> LDS (linear dest: wave-uniform base + lane*16)
__device__ __forceinline__ void gload_lds16(const void* g, void* l) {
    __builtin_amdgcn_global_load_lds(
        (const __attribute__((address_space(1))) unsigned int*)g,
        (__attribute__((address_space(3))) unsigned int*)l, 16, 0, 0);
}

// ---------------- prep_all: weight transpose/split + bias cat + counter zero ----------------
// blocks 0..127: w1t (128*256), 128..191: wcat (128*128)+bcat, 192: zero counters.
__global__ __launch_bounds__(TPB) void prep_all(const float* __restrict__ w1,
                                                const float* __restrict__ w2,
                                                const float* __restrict__ b2,
                                                const float* __restrict__ w3,
                                                const float* __restrict__ b3,
                                                short* __restrict__ w1t_h,
                                                short* __restrict__ w1t_l,
                                                short* __restrict__ wct_h,
                                                short* __restrict__ wct_l,
                                                float* __restrict__ bcat,
                                                int* __restrict__ cursor) {
    int b = blockIdx.x, t0 = threadIdx.x;
    if (b < 128) {
        int t = b * TPB + t0;                // < 128*256
        int k = t & 255, n = t >> 8;
        float v = w1[(size_t)k * 128 + n];
        short h, l;
        split2(v, h, l);
        w1t_h[t] = h;
        w1t_l[t] = l;
    } else if (b < 192) {
        int t = (b - 128) * TPB + t0;        // < 128*128
        int k = t & 127, n = t >> 7;
        float v = (n < 64) ? w2[(size_t)k * 64 + n] : w3[(size_t)k * 64 + (n - 64)];
        short h, l;
        split2(v, h, l);
        wct_h[t] = h;
        wct_l[t] = l;
        if (t < 64) { bcat[t] = b2[t]; bcat[64 + t] = b3[t]; }
    } else {
        for (int i = t0; i < 513; i += TPB) cursor[i] = 0;  // ghist|gcur|done
    }
}

// ---------------- CSR stage 1: group histogram + inline scan (last block) ----------------
__global__ __launch_bounds__(TPB) void group_count(const int* __restrict__ dst,
                                                   int* __restrict__ cursor, int E) {
    int* ghist = cursor;          // [256]
    int* done  = cursor + 512;    // [1]
    int* goff  = cursor + 513;    // [257]
    __shared__ int h[256];
    __shared__ int lastFlag;
    int t = threadIdx.x;
    h[t] = 0;
    __syncthreads();
    const int4* d4 = (const int4*)dst;
    int E4 = E >> 2;
    int stride = gridDim.x * TPB;
    for (int k = blockIdx.x * TPB + t; k < E4; k += stride) {
        int4 v = d4[k];
        atomicAdd(&h[v.x >> GSHIFT], 1);
        atomicAdd(&h[v.y >> GSHIFT], 1);
        atomicAdd(&h[v.z >> GSHIFT], 1);
        atomicAdd(&h[v.w >> GSHIFT], 1);
    }
    // scalar tail (E not multiple of 4)
    for (int k = (E4 << 2) + blockIdx.x * TPB + t; k < E; k += stride)
        atomicAdd(&h[dst[k] >> GSHIFT], 1);
    __syncthreads();
    if (h[t]) atomicAdd(&ghist[t], h[t]);
    __threadfence();
    __syncthreads();
    if (t == 0) lastFlag = (atomicAdd(done, 1) == (int)gridDim.x - 1);
    __syncthreads();
    if (!lastFlag) return;
    // last-finishing block: exclusive scan ghist -> goff (all ghist adds fenced)
    int v = atomicAdd(&ghist[t], 0);     // device-coherent read
    h[t] = v;
    __syncthreads();
#pragma unroll
    for (int off = 1; off < 256; off <<= 1) {
        int x = (t >= off) ? h[t - off] : 0;
        __syncthreads();
        h[t] += x;
        __syncthreads();
    }
    goff[t] = h[t] - v;
    if (t == 255) goff[256] = h[255];
}

// ---------------- stage 3: partition edges into group segments ----------------
__global__ __launch_bounds__(256) void partition_kernel(const int* __restrict__ src,
                                                        const int* __restrict__ dst,
                                                        const int* __restrict__ goff,
                                                        int* __restrict__ gcur,
                                                        int* __restrict__ staged, int E) {
    __shared__ int sorted[PART_M];
    __shared__ int sc[256];
    __shared__ int lstart[257];
    __shared__ int cur[256];
    __shared__ int gb[256];
    int t = threadIdx.x;
    int base = blockIdx.x * PART_M;
    int mloc = min(PART_M, E - base);
    int m4 = mloc >> 2;                     // base,E mult of 4 -> exact

    sc[t] = 0;
    cur[t] = 0;
    __syncthreads();
    const int4* d4 = (const int4*)(dst + base);
    const int4* s4 = (const int4*)(src + base);
    for (int k = t; k < m4; k += 256) {
        int4 v = d4[k];
        atomicAdd(&sc[v.x >> GSHIFT], 1);
        atomicAdd(&sc[v.y >> GSHIFT], 1);
        atomicAdd(&sc[v.z >> GSHIFT], 1);
        atomicAdd(&sc[v.w >> GSHIFT], 1);
    }
    for (int k = (m4 << 2) + t; k < mloc; k += 256)
        atomicAdd(&sc[dst[base + k] >> GSHIFT], 1);
    __syncthreads();
    int v = sc[t];
    __syncthreads();
    sc[t] = v;
    __syncthreads();
#pragma unroll
    for (int off = 1; off < 256; off <<= 1) {
        int x = (t >= off) ? sc[t - off] : 0;
        __syncthreads();
        sc[t] += x;
        __syncthreads();
    }
    lstart[t] = sc[t] - v;
    if (t == 255) lstart[256] = sc[255];
    gb[t] = goff[t] + atomicAdd(&gcur[t], v);
    __syncthreads();
    for (int k = t; k < m4; k += 256) {
        int4 dv = d4[k];
        int4 sv = s4[k];
        int b0 = dv.x >> GSHIFT;
        sorted[lstart[b0] + atomicAdd(&cur[b0], 1)] = (sv.x << GSHIFT) | (dv.x & (GSIZE - 1));
        int b1 = dv.y >> GSHIFT;
        sorted[lstart[b1] + atomicAdd(&cur[b1], 1)] = (sv.y << GSHIFT) | (dv.y & (GSIZE - 1));
        int b2 = dv.z >> GSHIFT;
        sorted[lstart[b2] + atomicAdd(&cur[b2], 1)] = (sv.z << GSHIFT) | (dv.z & (GSIZE - 1));
        int b3 = dv.w >> GSHIFT;
        sorted[lstart[b3] + atomicAdd(&cur[b3], 1)] = (sv.w << GSHIFT) | (dv.w & (GSIZE - 1));
    }
    for (int k = (m4 << 2) + t; k < mloc; k += 256) {
        int d = dst[base + k];
        int s = src[base + k];
        int b = d >> GSHIFT;
        sorted[lstart[b] + atomicAdd(&cur[b], 1)] = (s << GSHIFT) | (d & (GSIZE - 1));
    }
    __syncthreads();
    for (int e = t; e < mloc; e += 256) {
        int lo = 0, hi = 256;
        while (hi - lo > 1) {
            int mid = (lo + hi) >> 1;
            if (lstart[mid] <= e) lo = mid; else hi = mid;
        }
        staged[gb[lo] + (e - lstart[lo])] = sorted[e];
    }
}

// ---------------- stage 4: per-group CSR finalize ----------------
__global__ __launch_bounds__(512) void build_csr(const int* __restrict__ staged,
                                                 const int* __restrict__ goff,
                                                 int* __restrict__ cnt,
                                                 float* __restrict__ dinv,
                                                 int* __restrict__ rowptr,
                                                 int* __restrict__ csr, int N) {
    __shared__ int hist[512];
    __shared__ int sc[512];
    __shared__ int lrow[512];
    __shared__ int cur[512];
    int t = threadIdx.x;
    int g = blockIdx.x;
    int s0 = goff[g], s1 = goff[g + 1];
    hist[t] = 0;
    cur[t] = 0;
    __syncthreads();
    for (int k = s0 + t; k < s1; k += 512)
        atomicAdd(&hist[staged[k] & (GSIZE - 1)], 1);
    __syncthreads();
    int v = hist[t];
    sc[t] = v;
    __syncthreads();
#pragma unroll
    for (int off = 1; off < 512; off <<= 1) {
        int x = (t >= off) ? sc[t - off] : 0;
        __syncthreads();
        sc[t] += x;
        __syncthreads();
    }
    int rp = s0 + sc[t] - v;
    lrow[t] = rp;
    int node = (g << GSHIFT) + t;
    if (node < N) {
        rowptr[node] = rp;
        cnt[node] = v;
        dinv[node] = rsqrtf(1.0f + (float)v);
    }
    __syncthreads();
    for (int k = s0 + t; k < s1; k += 512) {
        int p = staged[k];
        int dl = p & (GSIZE - 1);
        int pos = lrow[dl] + atomicAdd(&cur[dl], 1);
        csr[pos] = p >> GSHIFT;
    }
}

// ---------------- MFMA GEMM1 (pipelined): Cb[M,128]bf = (A_f32[M,K] @ B) * rs ----------------
__global__ __launch_bounds__(TPB) void gemm_mfma_f32in(const float* __restrict__ A,
                                                       const short* __restrict__ Bth,
                                                       const short* __restrict__ Btl,
                                                       const float* __restrict__ rs,
                                                       short* __restrict__ Cb, int M, int K) {
    __shared__ float Af[2][64 * 32];           // 2 x 8KB, granule col ^= (row&7)
    __shared__ short Bh[2][128 * 32];          // 2 x 8KB, granule col ^= ((row>>1)&3)
    __shared__ short Bl[2][128 * 32];
    int t = threadIdx.x;
    int wave = t >> 6, lane = t & 63, quad = lane >> 4, l16 = lane & 15;
    int bm0 = blockIdx.x * 64;

    floatx4 acc[8];
#pragma unroll
    for (int nt = 0; nt < 8; ++nt) acc[nt] = (floatx4){0.f, 0.f, 0.f, 0.f};

    auto stage = [&](int pb, int k0) {
#pragma unroll
        for (int i = 0; i < 2; ++i) {
            int g = i * 256 + t;
            int row = g >> 3, col = g & 7;
            int gr = bm0 + row;
            if (gr >= M) gr = M - 1;           // clamp: no per-lane predication
            int scol = col ^ (row & 7);
            gload_lds16(A + (size_t)gr * K + k0 + scol * 4,
                        &Af[pb][(i * 256 + wave * 64) * 4]);
        }
#pragma unroll
        for (int i = 0; i < 2; ++i) {
            int g = i * 256 + t;
            int row = g >> 2, col = g & 3;
            int scol = col ^ ((row >> 1) & 3);
            size_t off = (size_t)row * K + k0 + scol * 8;
            int lb = (i * 256 + wave * 64) * 8;
            gload_lds16(Bth + off, &Bh[pb][lb]);
            gload_lds16(Btl + off, &Bl[pb][lb]);
        }
    };

    int nk = K >> 5;
    stage(0, 0);
    __syncthreads();
    int am = wave * 16 + l16;
    int ac0 = ((quad * 2 + 0) ^ (am & 7)) * 4;
    int ac1 = ((quad * 2 + 1) ^ (am & 7)) * 4;
    int bc = (quad ^ ((l16 >> 1) & 3)) * 8;
    for (int ks = 0; ks < nk; ++ks) {
        int pb = ks & 1;
        if (ks + 1 < nk) stage(pb ^ 1, (ks + 1) << 5);
        float4 fa0 = *(const float4*)&Af[pb][am * 32 + ac0];
        float4 fa1 = *(const float4*)&Af[pb][am * 32 + ac1];
        short8 a_h, a_l;
        {
            short h, l;
            split2(fa0.x, h, l); a_h[0] = h; a_l[0] = l;
            split2(fa0.y, h, l); a_h[1] = h; a_l[1] = l;
            split2(fa0.z, h, l); a_h[2] = h; a_l[2] = l;
            split2(fa0.w, h, l); a_h[3] = h; a_l[3] = l;
            split2(fa1.x, h, l); a_h[4] = h; a_l[4] = l;
            split2(fa1.y, h, l); a_h[5] = h; a_l[5] = l;
            split2(fa1.z, h, l); a_h[6] = h; a_l[6] = l;
            split2(fa1.w, h, l); a_h[7] = h; a_l[7] = l;
        }
#pragma unroll
        for (int nt = 0; nt < 8; ++nt) {
            int bn = nt * 16 + l16;
            short8 b_h = *(const short8*)&Bh[pb][bn * 32 + bc];
            short8 b_l = *(const short8*)&Bl[pb][bn * 32 + bc];
            acc[nt] = __builtin_amdgcn_mfma_f32_16x16x32_bf16(a_l, b_h, acc[nt], 0, 0, 0);
            acc[nt] = __builtin_amdgcn_mfma_f32_16x16x32_bf16(a_h, b_l, acc[nt], 0, 0, 0);
            acc[nt] = __builtin_amdgcn_mfma_f32_16x16x32_bf16(a_h, b_h, acc[nt], 0, 0, 0);
        }
        __syncthreads();
    }
#pragma unroll
    for (int reg = 0; reg < 4; ++reg) {
        int gr = bm0 + wave * 16 + quad * 4 + reg;
        if (gr < M) {
            float s = rs[gr];
            short* cp = Cb + (size_t)gr * 128;
#pragma unroll
            for (int nt = 0; nt < 8; ++nt) cp[nt * 16 + l16] = bf16_rtn(acc[nt][reg] * s);
        }
    }
}

// ---------------- MFMA GEMM2 (pipelined): Cb[M,128]bf = ((AH+AL)[M,K] @ B) * rs ----------------
__global__ __launch_bounds__(TPB) void gemm_mfma_bfin(const short* __restrict__ AH,
                                                      const short* __restrict__ AL,
                                                      const short* __restrict__ Bth,
                                                      const short* __restrict__ Btl,
                                                      const float* __restrict__ rs,
                                                      short* __restrict__ Cb, int M, int K) {
    __shared__ short Ah[2][64 * 32], Al[2][64 * 32];   // 2 x 4KB each
    __shared__ short Bh[2][128 * 32], Bl[2][128 * 32]; // 2 x 8KB each
    int t = threadIdx.x;
    int wave = t >> 6, lane = t & 63, quad = lane >> 4, l16 = lane & 15;
    int bm0 = blockIdx.x * 64;

    floatx4 acc[8];
#pragma unroll
    for (int nt = 0; nt < 8; ++nt) acc[nt] = (floatx4){0.f, 0.f, 0.f, 0.f};

    auto stage = [&](int pb, int k0) {
        {
            int row = t >> 2, col = t & 3;
            int gr = bm0 + row;
            if (gr >= M) gr = M - 1;
            int scol = col ^ ((row >> 1) & 3);
            size_t off = (size_t)gr * K + k0 + scol * 8;
            int lb = (wave * 64) * 8;
            gload_lds16(AH + off, &Ah[pb][lb]);
            gload_lds16(AL + off, &Al[pb][lb]);
        }
#pragma unroll
        for (int i = 0; i < 2; ++i) {
            int g = i * 256 + t;
            int row = g >> 2, col = g & 3;
            int scol = col ^ ((row >> 1) & 3);
            size_t off = (size_t)row * K + k0 + scol * 8;
            int lb = (i * 256 + wave * 64) * 8;
            gload_lds16(Bth + off, &Bh[pb][lb]);
            gload_lds16(Btl + off, &Bl[pb][lb]);
        }
    };

    int nk = K >> 5;
    stage(0, 0);
    __syncthreads();
    int am = wave * 16 + l16;
    int ac = (quad ^ ((am >> 1) & 3)) * 8;
    int bc = (quad ^ ((l16 >> 1) & 3)) * 8;
    for (int ks = 0; ks < nk; ++ks) {
        int pb = ks & 1;
        if (ks + 1 < nk) stage(pb ^ 1, (ks + 1) << 5);
        short8 a_h = *(const short8*)&Ah[pb][am * 32 + ac];
        short8 a_l = *(const short8*)&Al[pb][am * 32 + ac];
#pragma unroll
        for (int nt = 0; nt < 8; ++nt) {
            int bn = nt * 16 + l16;
            short8 b_h = *(const short8*)&Bh[pb][bn * 32 + bc];
            short8 b_l = *(const short8*)&Bl[pb][bn * 32 + bc];
            acc[nt] = __builtin_amdgcn_mfma_f32_16x16x32_bf16(a_l, b_h, acc[nt], 0, 0, 0);
            acc[nt] = __builtin_amdgcn_mfma_f32_16x16x32_bf16(a_h, b_l, acc[nt], 0, 0, 0);
            acc[nt] = __builtin_amdgcn_mfma_f32_16x16x32_bf16(a_h, b_h, acc[nt], 0, 0, 0);
        }
        __syncthreads();
    }
#pragma unroll
    for (int reg = 0; reg < 4; ++reg) {
        int gr = bm0 + wave * 16 + quad * 4 + reg;
        if (gr < M) {
            float s = rs[gr];
            short* cp = Cb + (size_t)gr * 128;
#pragma unroll
            for (int nt = 0; nt < 8; ++nt) cp[nt * 16 + l16] = bf16_rtn(acc[nt][reg] * s);
        }
    }
}

// ---------------- gather 1: hidden = relu(dinv*(self+sum nbrs) + b1) -> bf16 hi/lo ----------------
__global__ __launch_bounds__(TPB) void gather_hidden(const int* __restrict__ csr,
                                                     const int* __restrict__ rowptr,
                                                     const int* __restrict__ cnt,
                                                     const float* __restrict__ dinv,
                                                     const short* __restrict__ hs,
                                                     const float* __restrict__ b1,
                                                     short* __restrict__ hidH,
                                                     short* __restrict__ hidL, int N) {
    size_t t = (size_t)blockIdx.x * TPB + threadIdx.x;
    int nid = (int)(t >> 4);
    int lane = threadIdx.x & 15;
    if (nid >= N) return;
    int start = rowptr[nid];
    int deg = cnt[nid];
    const uint4v* hp = (const uint4v*)hs;  // row = 16 x 16B
    float acc[8] = {0, 0, 0, 0, 0, 0, 0, 0};
    addrow(acc, __builtin_nontemporal_load(&hp[(size_t)nid * 16 + lane]));  // self (read-once)
    gather_accum(acc, csr, start, deg, hp, lane);
    float di = dinv[nid];
    float4 b0 = ((const float4*)b1)[lane * 2];
    float4 b1v = ((const float4*)b1)[lane * 2 + 1];
    float bb[8] = {b0.x, b0.y, b0.z, b0.w, b1v.x, b1v.y, b1v.z, b1v.w};
    unsigned hiw[8];
    short low[8];
#pragma unroll
    for (int i = 0; i < 8; ++i) {
        float h = fmaxf(fmaf(di, acc[i], bb[i]), 0.f);
        unsigned u = __float_as_uint(h);
        hiw[i] = u >> 16;
        float hf = __uint_as_float(u & 0xFFFF0000u);
        low[i] = bf16_rtn(h - hf);
    }
    uint4v ph, pl;
    ph[0] = hiw[0] | (hiw[1] << 16);
    ph[1] = hiw[2] | (hiw[3] << 16);
    ph[2] = hiw[4] | (hiw[5] << 16);
    ph[3] = hiw[6] | (hiw[7] << 16);
    pl[0] = (unsigned short)low[0] | ((unsigned)(unsigned short)low[1] << 16);
    pl[1] = (unsigned short)low[2] | ((unsigned)(unsigned short)low[3] << 16);
    pl[2] = (unsigned short)low[4] | ((unsigned)(unsigned short)low[5] << 16);
    pl[3] = (unsigned short)low[6] | ((unsigned)(unsigned short)low[7] << 16);
    __builtin_nontemporal_store(ph, &((uint4v*)hidH)[(size_t)nid * 16 + lane]);
    __builtin_nontemporal_store(pl, &((uint4v*)hidL)[(size_t)nid * 16 + lane]);
}

// ---------------- gather 2: out = dinv*(self+sum nbrs) + bcat -> f32 mu|logvar ----------------
__global__ __launch_bounds__(TPB) void gather_out(const int* __restrict__ csr,
                                                  const int* __restrict__ rowptr,
                                                  const int* __restrict__ cnt,
                                                  const float* __restrict__ dinv,
                                                  const short* __restrict__ hs,
                                                  const float* __restrict__ bcat,
                                                  float* __restrict__ out, int N) {
    size_t t = (size_t)blockIdx.x * TPB + threadIdx.x;
    int nid = (int)(t >> 4);
    int lane = threadIdx.x & 15;
    if (nid >= N) return;
    int start = rowptr[nid];
    int deg = cnt[nid];
    const uint4v* hp = (const uint4v*)hs;
    float acc[8] = {0, 0, 0, 0, 0, 0, 0, 0};
    addrow(acc, __builtin_nontemporal_load(&hp[(size_t)nid * 16 + lane]));
    gather_accum(acc, csr, start, deg, hp, lane);
    float di = dinv[nid];
    float4 b0 = ((const float4*)bcat)[lane * 2];
    float4 b1v = ((const float4*)bcat)[lane * 2 + 1];
    floatx4 r0, r1;
    r0[0] = fmaf(di, acc[0], b0.x);
    r0[1] = fmaf(di, acc[1], b0.y);
    r0[2] = fmaf(di, acc[2], b0.z);
    r0[3] = fmaf(di, acc[3], b0.w);
    r1[0] = fmaf(di, acc[4], b1v.x);
    r1[1] = fmaf(di, acc[5], b1v.y);
    r1[2] = fmaf(di, acc[6], b1v.z);
    r1[3] = fmaf(di, acc[7], b1v.w);
    int f = lane * 8;  // 0..120
    float* dp = (f < 64) ? (out + (size_t)nid * 64 + f)
                         : (out + (size_t)N * 64 + (size_t)nid * 64 + (f - 64));
    __builtin_nontemporal_store(r0, (floatx4*)dp);
    __builtin_nontemporal_store(r1, (floatx4*)(dp + 4));
}

extern "C" void kernel_launch(void* const* d_in, const int* in_sizes, int n_in,
                              void* d_out, int out_size, void* d_ws, size_t ws_size,
                              hipStream_t stream) {
    const float* x  = (const float*)d_in[0];
    const float* w1 = (const float*)d_in[1];
    const float* b1 = (const float*)d_in[2];
    const float* w2 = (const float*)d_in[3];
    const float* b2 = (const float*)d_in[4];
    const float* w3 = (const float*)d_in[5];
    const float* b3 = (const float*)d_in[6];
    const int*   ei = (const int*)d_in[7];

    const int N = in_sizes[0] / 256;   // 100000
    const int E = in_sizes[7] / 2;     // 1600000
    const int K1 = 256;

    float* out = (float*)d_out;

    // workspace carve-up (R8 layout)
    size_t nh = (size_t)N * 128;
    short* hs1    = (short*)d_ws;          // N*128 bf16
    short* hidH   = hs1 + nh;
    short* hidL   = hidH + nh;
    short* hs2    = hidL + nh;
    int*   cnt    = (int*)(hs2 + nh);
    float* dinv   = (float*)(cnt + N);
    int*   rowptr = (int*)(dinv + N);
    int*   cursor = rowptr + N;            // ghist[256]|gcur[256]|done|goff[257]
    int*   bsum   = cursor + N;
    float* bcat   = (float*)(bsum + 512);
    short* w1t_h  = (short*)(bcat + 128);
    short* w1t_l  = w1t_h + 128 * 256;
    short* wct_h  = w1t_l + 128 * 256;
    short* wct_l  = wct_h + 128 * 128;
    int*   csr    = (int*)(wct_l + 128 * 128);

    const int* srcp = ei;
    const int* dstp = ei + E;

    const int ngrp = (N + GSIZE - 1) >> GSHIFT;   // 196
    int* gcur   = cursor + 256;  // [256]
    int* goff   = cursor + 513;  // [257]
    int* staged = (int*)hs2;     // alias: hs2 not live until gemm2

    // 1) prep (weights + bias + counter zero) — replaces memset + 2 prep kernels
    prep_all<<<193, TPB, 0, stream>>>(w1, w2, b2, w3, b3, w1t_h, w1t_l, wct_h, wct_l,
                                      bcat, cursor);

    // 2) CSR build: group hist (+inline scan in last block) -> partition -> finalize
    int gc_blocks = ((E >> 2) + TPB * 4 - 1) / (TPB * 4);
    group_count<<<gc_blocks, TPB, 0, stream>>>(dstp, cursor, E);
    partition_kernel<<<(E + PART_M - 1) / PART_M, 256, 0, stream>>>(srcp, dstp, goff, gcur,
                                                                    staged, E);
    build_csr<<<ngrp, 512, 0, stream>>>(staged, goff, cnt, dinv, rowptr, csr, N);

    // 3) hs1 = (x @ w1) * dinv  -> bf16
    gemm_mfma_f32in<<<(N + 63) / 64, TPB, 0, stream>>>(x, w1t_h, w1t_l, dinv, hs1, N, K1);

    // 4) hidden = relu(dinv*(self+nbrs) + b1) -> hi/lo bf16
    size_t gthreads = (size_t)N * 16;
    gather_hidden<<<(unsigned)((gthreads + TPB - 1) / TPB), TPB, 0, stream>>>(
        csr, rowptr, cnt, dinv, hs1, b1, hidH, hidL, N);

    // 5) hs2 = (hidden @ wcat) * dinv -> bf16   (overwrites staged — dead by now)
    gemm_mfma_bfin<<<(N + 63) / 64, TPB, 0, stream>>>(hidH, hidL, wct_h, wct_l, dinv, hs2, N, 128);

    // 6) out = dinv*(self+nbrs) + bcat -> mu | logvar (f32)
    gather_out<<<(unsigned)((gthreads + TPB - 1) / TPB), TPB, 0, stream>>>(
        csr, rowptr, cnt, dinv, hs2, bcat, out, N);
}

// Round 7
// 412.682 us; speedup vs baseline: 1.1148x; 1.0314x over previous
//
#include <hip/hip_runtime.h>

// GCN-VAE encoder forward on MI355X — R11: shfl-shared gather indices +
// direct-write partition.
//
// agg[d] = dinv[d] * ( hs[d] + sum_{s in N(d)} hs[s] ),  hs := h*dinv
// hs1, hs2 stored bf16 (RTN); hidden bf16 hi+lo (exact split).
//
// R11a: gathers load csr indices ONCE per 16-row batch (coalesced, 1 lane
//   each) and broadcast via __shfl(.,r,16) -> halves vmem instrs/row
//   (was: all 16 lanes redundantly load the same csr entry per row).
// R11b: partition writes staged[] DIRECTLY at reserved span positions
//   (gb[] exclusive per block x group) -> kills 32KB LDS sort + 8-step
//   binary search per edge; LDS 34KB->3KB; PART_M 8192->4096 (391 blocks
//   covers all 256 CUs).
//
// R10: prep_all (weights+bias+zero), group_count w/ inline last-block scan.
// R9 post-mortem: NO gather/GEMM fusion (occupancy kills the gather).
// R8: gathers at random-256B wall (~3.8TB/s TCC-fetch); NT stores.
// R6: GEMMs are 2-phase global_load_lds pipelines (src-side XOR swizzle).
//
// ws: hs1[N*128]bf | hidH | hidL | hs2 (aliased staged[E] during CSR build) |
//     cnt[N] | dinv[N] | rowptr[N] | cursor (ghist|gcur|done|goff) |
//     bsum[512] | bcat[128] | w1t_h/l | wct_h/l | csr[E]

#define TPB 256
#define GSHIFT 9
#define GSIZE 512
#define PART_M 4096  // edges per partition WG

typedef __attribute__((ext_vector_type(8))) short short8;
typedef __attribute__((ext_vector_type(4))) short short4v;
typedef __attribute__((ext_vector_type(4))) float floatx4;
typedef __attribute__((ext_vector_type(4))) unsigned int uint4v;

__device__ __forceinline__ void split2(float v, short& hi, short& lo) {
    unsigned u = __float_as_uint(v);
    float hf = __uint_as_float(u & 0xFFFF0000u);
    float lf = v - hf;                       // exact
    hi = (short)(u >> 16);
    lo = (short)(__float_as_uint(lf) >> 16);
}

__device__ __forceinline__ short bf16_rtn(float v) {
    unsigned u = __float_as_uint(v);
    u += 0x7FFF + ((u >> 16) & 1);           // round to nearest even
    return (short)(u >> 16);
}

__device__ __forceinline__ void addrow(float* a, uint4v v) {
    a[0] += __uint_as_float(v[0] << 16); a[1] += __uint_as_float(v[0] & 0xFFFF0000u);
    a[2] += __uint_as_float(v[1] << 16); a[3] += __uint_as_float(v[1] & 0xFFFF0000u);
    a[4] += __uint_as_float(v[2] << 16); a[5] += __uint_as_float(v[2] & 0xFFFF0000u);
    a[6] += __uint_as_float(v[3] << 16); a[7] += __uint_as_float(v[3] & 0xFFFF0000u);
}

// gather loop: acc += sum of neighbor rows. Indices loaded cooperatively
// (1 coalesced load / 16 rows) and broadcast via shfl within the 16-lane group.
__device__ __forceinline__ void gather_accum(float* acc, const int* __restrict__ csr,
                                             int start, int deg, const uint4v* hp,
                                             int l16) {
    for (int jj = 0; jj < deg; jj += 16) {
        int rem = deg - jj;
        if (rem > 16) rem = 16;
        int il = (l16 < rem) ? l16 : rem - 1;
        int myIdx = csr[start + jj + il];
        int r = 0;
        for (; r + 3 < rem; r += 4) {
            int i0 = __shfl(myIdx, r + 0, 16);
            int i1 = __shfl(myIdx, r + 1, 16);
            int i2 = __shfl(myIdx, r + 2, 16);
            int i3 = __shfl(myIdx, r + 3, 16);
            uint4v v0 = hp[(size_t)i0 * 16 + l16];
            uint4v v1 = hp[(size_t)i1 * 16 + l16];
            uint4v v2 = hp[(size_t)i2 * 16 + l16];
            uint4v v3 = hp[(size_t)i3 * 16 + l16];
            addrow(acc, v0);
            addrow(acc, v1);
            addrow(acc, v2);
            addrow(acc, v3);
        }
        for (; r < rem; ++r) {
            int i = __shfl(myIdx, r, 16);
            addrow(acc, hp[(size_t)i * 16 + l16]);
        }
    }
}

// async 16B global -> LDS (linear dest: wave-uniform base + lane*16)
__device__ __forceinline__ void gload_lds16(const void* g, void* l) {
    __builtin_amdgcn_global_load_lds(
        (const __attribute__((address_space(1))) unsigned int*)g,
        (__attribute__((address_space(3))) unsigned int*)l, 16, 0, 0);
}

// ---------------- prep_all: weight transpose/split + bias cat + counter zero ----------------
__global__ __launch_bounds__(TPB) void prep_all(const float* __restrict__ w1,
                                                const float* __restrict__ w2,
                                                const float* __restrict__ b2,
                                                const float* __restrict__ w3,
                                                const float* __restrict__ b3,
                                                short* __restrict__ w1t_h,
                                                short* __restrict__ w1t_l,
                                                short* __restrict__ wct_h,
                                                short* __restrict__ wct_l,
                                                float* __restrict__ bcat,
                                                int* __restrict__ cursor) {
    int b = blockIdx.x, t0 = threadIdx.x;
    if (b < 128) {
        int t = b * TPB + t0;                // < 128*256
        int k = t & 255, n = t >> 8;
        float v = w1[(size_t)k * 128 + n];
        short h, l;
        split2(v, h, l);
        w1t_h[t] = h;
        w1t_l[t] = l;
    } else if (b < 192) {
        int t = (b - 128) * TPB + t0;        // < 128*128
        int k = t & 127, n = t >> 7;
        float v = (n < 64) ? w2[(size_t)k * 64 + n] : w3[(size_t)k * 64 + (n - 64)];
        short h, l;
        split2(v, h, l);
        wct_h[t] = h;
        wct_l[t] = l;
        if (t < 64) { bcat[t] = b2[t]; bcat[64 + t] = b3[t]; }
    } else {
        for (int i = t0; i < 513; i += TPB) cursor[i] = 0;  // ghist|gcur|done
    }
}

// ---------------- CSR stage 1: group histogram + inline scan (last block) ----------------
__global__ __launch_bounds__(TPB) void group_count(const int* __restrict__ dst,
                                                   int* __restrict__ cursor, int E) {
    int* ghist = cursor;          // [256]
    int* done  = cursor + 512;    // [1]
    int* goff  = cursor + 513;    // [257]
    __shared__ int h[256];
    __shared__ int lastFlag;
    int t = threadIdx.x;
    h[t] = 0;
    __syncthreads();
    const int4* d4 = (const int4*)dst;
    int E4 = E >> 2;
    int stride = gridDim.x * TPB;
    for (int k = blockIdx.x * TPB + t; k < E4; k += stride) {
        int4 v = d4[k];
        atomicAdd(&h[v.x >> GSHIFT], 1);
        atomicAdd(&h[v.y >> GSHIFT], 1);
        atomicAdd(&h[v.z >> GSHIFT], 1);
        atomicAdd(&h[v.w >> GSHIFT], 1);
    }
    for (int k = (E4 << 2) + blockIdx.x * TPB + t; k < E; k += stride)
        atomicAdd(&h[dst[k] >> GSHIFT], 1);
    __syncthreads();
    if (h[t]) atomicAdd(&ghist[t], h[t]);
    __threadfence();
    __syncthreads();
    if (t == 0) lastFlag = (atomicAdd(done, 1) == (int)gridDim.x - 1);
    __syncthreads();
    if (!lastFlag) return;
    int v = atomicAdd(&ghist[t], 0);     // device-coherent read
    h[t] = v;
    __syncthreads();
#pragma unroll
    for (int off = 1; off < 256; off <<= 1) {
        int x = (t >= off) ? h[t - off] : 0;
        __syncthreads();
        h[t] += x;
        __syncthreads();
    }
    goff[t] = h[t] - v;
    if (t == 255) goff[256] = h[255];
}

// ---------------- stage 3: partition edges, direct write to reserved spans ----------------
__global__ __launch_bounds__(256) void partition_kernel(const int* __restrict__ src,
                                                        const int* __restrict__ dst,
                                                        const int* __restrict__ goff,
                                                        int* __restrict__ gcur,
                                                        int* __restrict__ staged, int E) {
    __shared__ int sc[256];
    __shared__ int cur[256];
    __shared__ int gb[256];
    int t = threadIdx.x;
    int base = blockIdx.x * PART_M;
    int mloc = min(PART_M, E - base);
    int m4 = mloc >> 2;

    sc[t] = 0;
    cur[t] = 0;
    __syncthreads();
    const int4* d4 = (const int4*)(dst + base);
    const int4* s4 = (const int4*)(src + base);
    for (int k = t; k < m4; k += 256) {
        int4 v = d4[k];
        atomicAdd(&sc[v.x >> GSHIFT], 1);
        atomicAdd(&sc[v.y >> GSHIFT], 1);
        atomicAdd(&sc[v.z >> GSHIFT], 1);
        atomicAdd(&sc[v.w >> GSHIFT], 1);
    }
    for (int k = (m4 << 2) + t; k < mloc; k += 256)
        atomicAdd(&sc[dst[base + k] >> GSHIFT], 1);
    __syncthreads();
    int v = sc[t];
    gb[t] = v ? goff[t] + atomicAdd(&gcur[t], v) : 0;   // exclusive span
    __syncthreads();
    for (int k = t; k < m4; k += 256) {
        int4 dv = d4[k];
        int4 sv = s4[k];
        int b0 = dv.x >> GSHIFT;
        staged[gb[b0] + atomicAdd(&cur[b0], 1)] = (sv.x << GSHIFT) | (dv.x & (GSIZE - 1));
        int b1 = dv.y >> GSHIFT;
        staged[gb[b1] + atomicAdd(&cur[b1], 1)] = (sv.y << GSHIFT) | (dv.y & (GSIZE - 1));
        int b2 = dv.z >> GSHIFT;
        staged[gb[b2] + atomicAdd(&cur[b2], 1)] = (sv.z << GSHIFT) | (dv.z & (GSIZE - 1));
        int b3 = dv.w >> GSHIFT;
        staged[gb[b3] + atomicAdd(&cur[b3], 1)] = (sv.w << GSHIFT) | (dv.w & (GSIZE - 1));
    }
    for (int k = (m4 << 2) + t; k < mloc; k += 256) {
        int d = dst[base + k];
        int s = src[base + k];
        int b = d >> GSHIFT;
        staged[gb[b] + atomicAdd(&cur[b], 1)] = (s << GSHIFT) | (d & (GSIZE - 1));
    }
}

// ---------------- stage 4: per-group CSR finalize ----------------
__global__ __launch_bounds__(512) void build_csr(const int* __restrict__ staged,
                                                 const int* __restrict__ goff,
                                                 int* __restrict__ cnt,
                                                 float* __restrict__ dinv,
                                                 int* __restrict__ rowptr,
                                                 int* __restrict__ csr, int N) {
    __shared__ int hist[512];
    __shared__ int sc[512];
    __shared__ int lrow[512];
    __shared__ int cur[512];
    int t = threadIdx.x;
    int g = blockIdx.x;
    int s0 = goff[g], s1 = goff[g + 1];
    hist[t] = 0;
    cur[t] = 0;
    __syncthreads();
    for (int k = s0 + t; k < s1; k += 512)
        atomicAdd(&hist[staged[k] & (GSIZE - 1)], 1);
    __syncthreads();
    int v = hist[t];
    sc[t] = v;
    __syncthreads();
#pragma unroll
    for (int off = 1; off < 512; off <<= 1) {
        int x = (t >= off) ? sc[t - off] : 0;
        __syncthreads();
        sc[t] += x;
        __syncthreads();
    }
    int rp = s0 + sc[t] - v;
    lrow[t] = rp;
    int node = (g << GSHIFT) + t;
    if (node < N) {
        rowptr[node] = rp;
        cnt[node] = v;
        dinv[node] = rsqrtf(1.0f + (float)v);
    }
    __syncthreads();
    for (int k = s0 + t; k < s1; k += 512) {
        int p = staged[k];
        int dl = p & (GSIZE - 1);
        int pos = lrow[dl] + atomicAdd(&cur[dl], 1);
        csr[pos] = p >> GSHIFT;
    }
}

// ---------------- MFMA GEMM1 (pipelined): Cb[M,128]bf = (A_f32[M,K] @ B) * rs ----------------
__global__ __launch_bounds__(TPB) void gemm_mfma_f32in(const float* __restrict__ A,
                                                       const short* __restrict__ Bth,
                                                       const short* __restrict__ Btl,
                                                       const float* __restrict__ rs,
                                                       short* __restrict__ Cb, int M, int K) {
    __shared__ float Af[2][64 * 32];           // 2 x 8KB, granule col ^= (row&7)
    __shared__ short Bh[2][128 * 32];          // 2 x 8KB, granule col ^= ((row>>1)&3)
    __shared__ short Bl[2][128 * 32];
    int t = threadIdx.x;
    int wave = t >> 6, lane = t & 63, quad = lane >> 4, l16 = lane & 15;
    int bm0 = blockIdx.x * 64;

    floatx4 acc[8];
#pragma unroll
    for (int nt = 0; nt < 8; ++nt) acc[nt] = (floatx4){0.f, 0.f, 0.f, 0.f};

    auto stage = [&](int pb, int k0) {
#pragma unroll
        for (int i = 0; i < 2; ++i) {
            int g = i * 256 + t;
            int row = g >> 3, col = g & 7;
            int gr = bm0 + row;
            if (gr >= M) gr = M - 1;           // clamp: no per-lane predication
            int scol = col ^ (row & 7);
            gload_lds16(A + (size_t)gr * K + k0 + scol * 4,
                        &Af[pb][(i * 256 + wave * 64) * 4]);
        }
#pragma unroll
        for (int i = 0; i < 2; ++i) {
            int g = i * 256 + t;
            int row = g >> 2, col = g & 3;
            int scol = col ^ ((row >> 1) & 3);
            size_t off = (size_t)row * K + k0 + scol * 8;
            int lb = (i * 256 + wave * 64) * 8;
            gload_lds16(Bth + off, &Bh[pb][lb]);
            gload_lds16(Btl + off, &Bl[pb][lb]);
        }
    };

    int nk = K >> 5;
    stage(0, 0);
    __syncthreads();
    int am = wave * 16 + l16;
    int ac0 = ((quad * 2 + 0) ^ (am & 7)) * 4;
    int ac1 = ((quad * 2 + 1) ^ (am & 7)) * 4;
    int bc = (quad ^ ((l16 >> 1) & 3)) * 8;
    for (int ks = 0; ks < nk; ++ks) {
        int pb = ks & 1;
        if (ks + 1 < nk) stage(pb ^ 1, (ks + 1) << 5);
        float4 fa0 = *(const float4*)&Af[pb][am * 32 + ac0];
        float4 fa1 = *(const float4*)&Af[pb][am * 32 + ac1];
        short8 a_h, a_l;
        {
            short h, l;
            split2(fa0.x, h, l); a_h[0] = h; a_l[0] = l;
            split2(fa0.y, h, l); a_h[1] = h; a_l[1] = l;
            split2(fa0.z, h, l); a_h[2] = h; a_l[2] = l;
            split2(fa0.w, h, l); a_h[3] = h; a_l[3] = l;
            split2(fa1.x, h, l); a_h[4] = h; a_l[4] = l;
            split2(fa1.y, h, l); a_h[5] = h; a_l[5] = l;
            split2(fa1.z, h, l); a_h[6] = h; a_l[6] = l;
            split2(fa1.w, h, l); a_h[7] = h; a_l[7] = l;
        }
#pragma unroll
        for (int nt = 0; nt < 8; ++nt) {
            int bn = nt * 16 + l16;
            short8 b_h = *(const short8*)&Bh[pb][bn * 32 + bc];
            short8 b_l = *(const short8*)&Bl[pb][bn * 32 + bc];
            acc[nt] = __builtin_amdgcn_mfma_f32_16x16x32_bf16(a_l, b_h, acc[nt], 0, 0, 0);
            acc[nt] = __builtin_amdgcn_mfma_f32_16x16x32_bf16(a_h, b_l, acc[nt], 0, 0, 0);
            acc[nt] = __builtin_amdgcn_mfma_f32_16x16x32_bf16(a_h, b_h, acc[nt], 0, 0, 0);
        }
        __syncthreads();
    }
#pragma unroll
    for (int reg = 0; reg < 4; ++reg) {
        int gr = bm0 + wave * 16 + quad * 4 + reg;
        if (gr < M) {
            float s = rs[gr];
            short* cp = Cb + (size_t)gr * 128;
#pragma unroll
            for (int nt = 0; nt < 8; ++nt) cp[nt * 16 + l16] = bf16_rtn(acc[nt][reg] * s);
        }
    }
}

// ---------------- MFMA GEMM2 (pipelined): Cb[M,128]bf = ((AH+AL)[M,K] @ B) * rs ----------------
__global__ __launch_bounds__(TPB) void gemm_mfma_bfin(const short* __restrict__ AH,
                                                      const short* __restrict__ AL,
                                                      const short* __restrict__ Bth,
                                                      const short* __restrict__ Btl,
                                                      const float* __restrict__ rs,
                                                      short* __restrict__ Cb, int M, int K) {
    __shared__ short Ah[2][64 * 32], Al[2][64 * 32];   // 2 x 4KB each
    __shared__ short Bh[2][128 * 32], Bl[2][128 * 32]; // 2 x 8KB each
    int t = threadIdx.x;
    int wave = t >> 6, lane = t & 63, quad = lane >> 4, l16 = lane & 15;
    int bm0 = blockIdx.x * 64;

    floatx4 acc[8];
#pragma unroll
    for (int nt = 0; nt < 8; ++nt) acc[nt] = (floatx4){0.f, 0.f, 0.f, 0.f};

    auto stage = [&](int pb, int k0) {
        {
            int row = t >> 2, col = t & 3;
            int gr = bm0 + row;
            if (gr >= M) gr = M - 1;
            int scol = col ^ ((row >> 1) & 3);
            size_t off = (size_t)gr * K + k0 + scol * 8;
            int lb = (wave * 64) * 8;
            gload_lds16(AH + off, &Ah[pb][lb]);
            gload_lds16(AL + off, &Al[pb][lb]);
        }
#pragma unroll
        for (int i = 0; i < 2; ++i) {
            int g = i * 256 + t;
            int row = g >> 2, col = g & 3;
            int scol = col ^ ((row >> 1) & 3);
            size_t off = (size_t)row * K + k0 + scol * 8;
            int lb = (i * 256 + wave * 64) * 8;
            gload_lds16(Bth + off, &Bh[pb][lb]);
            gload_lds16(Btl + off, &Bl[pb][lb]);
        }
    };

    int nk = K >> 5;
    stage(0, 0);
    __syncthreads();
    int am = wave * 16 + l16;
    int ac = (quad ^ ((am >> 1) & 3)) * 8;
    int bc = (quad ^ ((l16 >> 1) & 3)) * 8;
    for (int ks = 0; ks < nk; ++ks) {
        int pb = ks & 1;
        if (ks + 1 < nk) stage(pb ^ 1, (ks + 1) << 5);
        short8 a_h = *(const short8*)&Ah[pb][am * 32 + ac];
        short8 a_l = *(const short8*)&Al[pb][am * 32 + ac];
#pragma unroll
        for (int nt = 0; nt < 8; ++nt) {
            int bn = nt * 16 + l16;
            short8 b_h = *(const short8*)&Bh[pb][bn * 32 + bc];
            short8 b_l = *(const short8*)&Bl[pb][bn * 32 + bc];
            acc[nt] = __builtin_amdgcn_mfma_f32_16x16x32_bf16(a_l, b_h, acc[nt], 0, 0, 0);
            acc[nt] = __builtin_amdgcn_mfma_f32_16x16x32_bf16(a_h, b_l, acc[nt], 0, 0, 0);
            acc[nt] = __builtin_amdgcn_mfma_f32_16x16x32_bf16(a_h, b_h, acc[nt], 0, 0, 0);
        }
        __syncthreads();
    }
#pragma unroll
    for (int reg = 0; reg < 4; ++reg) {
        int gr = bm0 + wave * 16 + quad * 4 + reg;
        if (gr < M) {
            float s = rs[gr];
            short* cp = Cb + (size_t)gr * 128;
#pragma unroll
            for (int nt = 0; nt < 8; ++nt) cp[nt * 16 + l16] = bf16_rtn(acc[nt][reg] * s);
        }
    }
}

// ---------------- gather 1: hidden = relu(dinv*(self+sum nbrs) + b1) -> bf16 hi/lo ----------------
__global__ __launch_bounds__(TPB) void gather_hidden(const int* __restrict__ csr,
                                                     const int* __restrict__ rowptr,
                                                     const int* __restrict__ cnt,
                                                     const float* __restrict__ dinv,
                                                     const short* __restrict__ hs,
                                                     const float* __restrict__ b1,
                                                     short* __restrict__ hidH,
                                                     short* __restrict__ hidL, int N) {
    size_t t = (size_t)blockIdx.x * TPB + threadIdx.x;
    int nid = (int)(t >> 4);
    int lane = threadIdx.x & 15;
    if (nid >= N) return;
    int start = rowptr[nid];
    int deg = cnt[nid];
    const uint4v* hp = (const uint4v*)hs;  // row = 16 x 16B
    float acc[8] = {0, 0, 0, 0, 0, 0, 0, 0};
    addrow(acc, __builtin_nontemporal_load(&hp[(size_t)nid * 16 + lane]));  // self (read-once)
    gather_accum(acc, csr, start, deg, hp, lane);
    float di = dinv[nid];
    float4 b0 = ((const float4*)b1)[lane * 2];
    float4 b1v = ((const float4*)b1)[lane * 2 + 1];
    float bb[8] = {b0.x, b0.y, b0.z, b0.w, b1v.x, b1v.y, b1v.z, b1v.w};
    unsigned hiw[8];
    short low[8];
#pragma unroll
    for (int i = 0; i < 8; ++i) {
        float h = fmaxf(fmaf(di, acc[i], bb[i]), 0.f);
        unsigned u = __float_as_uint(h);
        hiw[i] = u >> 16;
        float hf = __uint_as_float(u & 0xFFFF0000u);
        low[i] = bf16_rtn(h - hf);
    }
    uint4v ph, pl;
    ph[0] = hiw[0] | (hiw[1] << 16);
    ph[1] = hiw[2] | (hiw[3] << 16);
    ph[2] = hiw[4] | (hiw[5] << 16);
    ph[3] = hiw[6] | (hiw[7] << 16);
    pl[0] = (unsigned short)low[0] | ((unsigned)(unsigned short)low[1] << 16);
    pl[1] = (unsigned short)low[2] | ((unsigned)(unsigned short)low[3] << 16);
    pl[2] = (unsigned short)low[4] | ((unsigned)(unsigned short)low[5] << 16);
    pl[3] = (unsigned short)low[6] | ((unsigned)(unsigned short)low[7] << 16);
    __builtin_nontemporal_store(ph, &((uint4v*)hidH)[(size_t)nid * 16 + lane]);
    __builtin_nontemporal_store(pl, &((uint4v*)hidL)[(size_t)nid * 16 + lane]);
}

// ---------------- gather 2: out = dinv*(self+sum nbrs) + bcat -> f32 mu|logvar ----------------
__global__ __launch_bounds__(TPB) void gather_out(const int* __restrict__ csr,
                                                  const int* __restrict__ rowptr,
                                                  const int* __restrict__ cnt,
                                                  const float* __restrict__ dinv,
                                                  const short* __restrict__ hs,
                                                  const float* __restrict__ bcat,
                                                  float* __restrict__ out, int N) {
    size_t t = (size_t)blockIdx.x * TPB + threadIdx.x;
    int nid = (int)(t >> 4);
    int lane = threadIdx.x & 15;
    if (nid >= N) return;
    int start = rowptr[nid];
    int deg = cnt[nid];
    const uint4v* hp = (const uint4v*)hs;
    float acc[8] = {0, 0, 0, 0, 0, 0, 0, 0};
    addrow(acc, __builtin_nontemporal_load(&hp[(size_t)nid * 16 + lane]));
    gather_accum(acc, csr, start, deg, hp, lane);
    float di = dinv[nid];
    float4 b0 = ((const float4*)bcat)[lane * 2];
    float4 b1v = ((const float4*)bcat)[lane * 2 + 1];
    floatx4 r0, r1;
    r0[0] = fmaf(di, acc[0], b0.x);
    r0[1] = fmaf(di, acc[1], b0.y);
    r0[2] = fmaf(di, acc[2], b0.z);
    r0[3] = fmaf(di, acc[3], b0.w);
    r1[0] = fmaf(di, acc[4], b1v.x);
    r1[1] = fmaf(di, acc[5], b1v.y);
    r1[2] = fmaf(di, acc[6], b1v.z);
    r1[3] = fmaf(di, acc[7], b1v.w);
    int f = lane * 8;  // 0..120
    float* dp = (f < 64) ? (out + (size_t)nid * 64 + f)
                         : (out + (size_t)N * 64 + (size_t)nid * 64 + (f - 64));
    __builtin_nontemporal_store(r0, (floatx4*)dp);
    __builtin_nontemporal_store(r1, (floatx4*)(dp + 4));
}

extern "C" void kernel_launch(void* const* d_in, const int* in_sizes, int n_in,
                              void* d_out, int out_size, void* d_ws, size_t ws_size,
                              hipStream_t stream) {
    const float* x  = (const float*)d_in[0];
    const float* w1 = (const float*)d_in[1];
    const float* b1 = (const float*)d_in[2];
    const float* w2 = (const float*)d_in[3];
    const float* b2 = (const float*)d_in[4];
    const float* w3 = (const float*)d_in[5];
    const float* b3 = (const float*)d_in[6];
    const int*   ei = (const int*)d_in[7];

    const int N = in_sizes[0] / 256;   // 100000
    const int E = in_sizes[7] / 2;     // 1600000
    const int K1 = 256;

    float* out = (float*)d_out;

    // workspace carve-up (R8 layout)
    size_t nh = (size_t)N * 128;
    short* hs1    = (short*)d_ws;          // N*128 bf16
    short* hidH   = hs1 + nh;
    short* hidL   = hidH + nh;
    short* hs2    = hidL + nh;
    int*   cnt    = (int*)(hs2 + nh);
    float* dinv   = (float*)(cnt + N);
    int*   rowptr = (int*)(dinv + N);
    int*   cursor = rowptr + N;            // ghist[256]|gcur[256]|done|goff[257]
    int*   bsum   = cursor + N;
    float* bcat   = (float*)(bsum + 512);
    short* w1t_h  = (short*)(bcat + 128);
    short* w1t_l  = w1t_h + 128 * 256;
    short* wct_h  = w1t_l + 128 * 256;
    short* wct_l  = wct_h + 128 * 128;
    int*   csr    = (int*)(wct_l + 128 * 128);

    const int* srcp = ei;
    const int* dstp = ei + E;

    const int ngrp = (N + GSIZE - 1) >> GSHIFT;   // 196
    int* gcur   = cursor + 256;  // [256]
    int* goff   = cursor + 513;  // [257]
    int* staged = (int*)hs2;     // alias: hs2 not live until gemm2

    // 1) prep (weights + bias + counter zero)
    prep_all<<<193, TPB, 0, stream>>>(w1, w2, b2, w3, b3, w1t_h, w1t_l, wct_h, wct_l,
                                      bcat, cursor);

    // 2) CSR build: group hist (+inline scan in last block) -> partition -> finalize
    int gc_blocks = ((E >> 2) + TPB * 4 - 1) / (TPB * 4);
    group_count<<<gc_blocks, TPB, 0, stream>>>(dstp, cursor, E);
    partition_kernel<<<(E + PART_M - 1) / PART_M, 256, 0, stream>>>(srcp, dstp, goff, gcur,
                                                                    staged, E);
    build_csr<<<ngrp, 512, 0, stream>>>(staged, goff, cnt, dinv, rowptr, csr, N);

    // 3) hs1 = (x @ w1) * dinv  -> bf16
    gemm_mfma_f32in<<<(N + 63) / 64, TPB, 0, stream>>>(x, w1t_h, w1t_l, dinv, hs1, N, K1);

    // 4) hidden = relu(dinv*(self+nbrs) + b1) -> hi/lo bf16
    size_t gthreads = (size_t)N * 16;
    gather_hidden<<<(unsigned)((gthreads + TPB - 1) / TPB), TPB, 0, stream>>>(
        csr, rowptr, cnt, dinv, hs1, b1, hidH, hidL, N);

    // 5) hs2 = (hidden @ wcat) * dinv -> bf16   (overwrites staged — dead by now)
    gemm_mfma_bfin<<<(N + 63) / 64, TPB, 0, stream>>>(hidH, hidL, wct_h, wct_l, dinv, hs2, N, 128);

    // 6) out = dinv*(self+nbrs) + bcat -> mu | logvar (f32)
    gather_out<<<(unsigned)((gthreads + TPB - 1) / TPB), TPB, 0, stream>>>(
        csr, rowptr, cnt, dinv, hs2, bcat, out, N);
}

// Round 9
// 406.788 us; speedup vs baseline: 1.1309x; 1.0145x over previous
//
#include <hip/hip_runtime.h>

// GCN-VAE encoder forward on MI355X — R12 (resubmit; prior run died to infra):
// 128-row GEMM tiles + cache-policy fix.
//
// agg[d] = dinv[d] * ( hs[d] + sum_{s in N(d)} hs[s] ),  hs := h*dinv
// hs1, hs2 stored bf16 (RTN); hidden bf16 hi+lo (exact split).
//
// R12a: NT reverted on hidH/hidL stores + self-row loads (hidH/hidL is
//   re-read by gemm_bfin one dispatch later -> keep it L3-resident; self
//   rows are other nodes' gather targets). NT kept ONLY on final out store.
// R12b: both GEMMs BM 64->128 (48 MFMA/k-step between barriers, B re-reads
//   halved, LDS 64KB -> 2 blocks/CU; MFMA pipeline tolerates low TLP, unlike
//   R9's gather fusion).
//
// R11: shfl-shared gather indices; direct-write partition (no LDS sort).
// R10: prep_all; group_count w/ inline last-block scan.
// R9 post-mortem: NO gather/GEMM fusion. R8: gathers at random-256B wall.
// R6: GEMMs = 2-phase global_load_lds pipelines (src-side XOR swizzle).
//
// ws: hs1[N*128]bf | hidH | hidL | hs2 (aliased staged[E] during CSR build) |
//     cnt[N] | dinv[N] | rowptr[N] | cursor (ghist|gcur|done|goff) |
//     bsum[512] | bcat[128] | w1t_h/l | wct_h/l | csr[E]

#define TPB 256
#define GSHIFT 9
#define GSIZE 512
#define PART_M 4096  // edges per partition WG

typedef __attribute__((ext_vector_type(8))) short short8;
typedef __attribute__((ext_vector_type(4))) short short4v;
typedef __attribute__((ext_vector_type(4))) float floatx4;
typedef __attribute__((ext_vector_type(4))) unsigned int uint4v;

__device__ __forceinline__ void split2(float v, short& hi, short& lo) {
    unsigned u = __float_as_uint(v);
    float hf = __uint_as_float(u & 0xFFFF0000u);
    float lf = v - hf;                       // exact
    hi = (short)(u >> 16);
    lo = (short)(__float_as_uint(lf) >> 16);
}

__device__ __forceinline__ short bf16_rtn(float v) {
    unsigned u = __float_as_uint(v);
    u += 0x7FFF + ((u >> 16) & 1);           // round to nearest even
    return (short)(u >> 16);
}

__device__ __forceinline__ void addrow(float* a, uint4v v) {
    a[0] += __uint_as_float(v[0] << 16); a[1] += __uint_as_float(v[0] & 0xFFFF0000u);
    a[2] += __uint_as_float(v[1] << 16); a[3] += __uint_as_float(v[1] & 0xFFFF0000u);
    a[4] += __uint_as_float(v[2] << 16); a[5] += __uint_as_float(v[2] & 0xFFFF0000u);
    a[6] += __uint_as_float(v[3] << 16); a[7] += __uint_as_float(v[3] & 0xFFFF0000u);
}

// gather loop: indices loaded once per 16-row batch, broadcast via shfl.
__device__ __forceinline__ void gather_accum(float* acc, const int* __restrict__ csr,
                                             int start, int deg, const uint4v* hp,
                                             int l16) {
    for (int jj = 0; jj < deg; jj += 16) {
        int rem = deg - jj;
        if (rem > 16) rem = 16;
        int il = (l16 < rem) ? l16 : rem - 1;
        int myIdx = csr[start + jj + il];
        int r = 0;
        for (; r + 3 < rem; r += 4) {
            int i0 = __shfl(myIdx, r + 0, 16);
            int i1 = __shfl(myIdx, r + 1, 16);
            int i2 = __shfl(myIdx, r + 2, 16);
            int i3 = __shfl(myIdx, r + 3, 16);
            uint4v v0 = hp[(size_t)i0 * 16 + l16];
            uint4v v1 = hp[(size_t)i1 * 16 + l16];
            uint4v v2 = hp[(size_t)i2 * 16 + l16];
            uint4v v3 = hp[(size_t)i3 * 16 + l16];
            addrow(acc, v0);
            addrow(acc, v1);
            addrow(acc, v2);
            addrow(acc, v3);
        }
        for (; r < rem; ++r) {
            int i = __shfl(myIdx, r, 16);
            addrow(acc, hp[(size_t)i * 16 + l16]);
        }
    }
}

// async 16B global -> LDS (linear dest: wave-uniform base + lane*16)
__device__ __forceinline__ void gload_lds16(const void* g, void* l) {
    __builtin_amdgcn_global_load_lds(
        (const __attribute__((address_space(1))) unsigned int*)g,
        (__attribute__((address_space(3))) unsigned int*)l, 16, 0, 0);
}

// ---------------- prep_all: weight transpose/split + bias cat + counter zero ----------------
__global__ __launch_bounds__(TPB) void prep_all(const float* __restrict__ w1,
                                                const float* __restrict__ w2,
                                                const float* __restrict__ b2,
                                                const float* __restrict__ w3,
                                                const float* __restrict__ b3,
                                                short* __restrict__ w1t_h,
                                                short* __restrict__ w1t_l,
                                                short* __restrict__ wct_h,
                                                short* __restrict__ wct_l,
                                                float* __restrict__ bcat,
                                                int* __restrict__ cursor) {
    int b = blockIdx.x, t0 = threadIdx.x;
    if (b < 128) {
        int t = b * TPB + t0;                // < 128*256
        int k = t & 255, n = t >> 8;
        float v = w1[(size_t)k * 128 + n];
        short h, l;
        split2(v, h, l);
        w1t_h[t] = h;
        w1t_l[t] = l;
    } else if (b < 192) {
        int t = (b - 128) * TPB + t0;        // < 128*128
        int k = t & 127, n = t >> 7;
        float v = (n < 64) ? w2[(size_t)k * 64 + n] : w3[(size_t)k * 64 + (n - 64)];
        short h, l;
        split2(v, h, l);
        wct_h[t] = h;
        wct_l[t] = l;
        if (t < 64) { bcat[t] = b2[t]; bcat[64 + t] = b3[t]; }
    } else {
        for (int i = t0; i < 513; i += TPB) cursor[i] = 0;  // ghist|gcur|done
    }
}

// ---------------- CSR stage 1: group histogram + inline scan (last block) ----------------
__global__ __launch_bounds__(TPB) void group_count(const int* __restrict__ dst,
                                                   int* __restrict__ cursor, int E) {
    int* ghist = cursor;          // [256]
    int* done  = cursor + 512;    // [1]
    int* goff  = cursor + 513;    // [257]
    __shared__ int h[256];
    __shared__ int lastFlag;
    int t = threadIdx.x;
    h[t] = 0;
    __syncthreads();
    const int4* d4 = (const int4*)dst;
    int E4 = E >> 2;
    int stride = gridDim.x * TPB;
    for (int k = blockIdx.x * TPB + t; k < E4; k += stride) {
        int4 v = d4[k];
        atomicAdd(&h[v.x >> GSHIFT], 1);
        atomicAdd(&h[v.y >> GSHIFT], 1);
        atomicAdd(&h[v.z >> GSHIFT], 1);
        atomicAdd(&h[v.w >> GSHIFT], 1);
    }
    for (int k = (E4 << 2) + blockIdx.x * TPB + t; k < E; k += stride)
        atomicAdd(&h[dst[k] >> GSHIFT], 1);
    __syncthreads();
    if (h[t]) atomicAdd(&ghist[t], h[t]);
    __threadfence();
    __syncthreads();
    if (t == 0) lastFlag = (atomicAdd(done, 1) == (int)gridDim.x - 1);
    __syncthreads();
    if (!lastFlag) return;
    int v = atomicAdd(&ghist[t], 0);     // device-coherent read
    h[t] = v;
    __syncthreads();
#pragma unroll
    for (int off = 1; off < 256; off <<= 1) {
        int x = (t >= off) ? h[t - off] : 0;
        __syncthreads();
        h[t] += x;
        __syncthreads();
    }
    goff[t] = h[t] - v;
    if (t == 255) goff[256] = h[255];
}

// ---------------- stage 3: partition edges, direct write to reserved spans ----------------
__global__ __launch_bounds__(256) void partition_kernel(const int* __restrict__ src,
                                                        const int* __restrict__ dst,
                                                        const int* __restrict__ goff,
                                                        int* __restrict__ gcur,
                                                        int* __restrict__ staged, int E) {
    __shared__ int sc[256];
    __shared__ int cur[256];
    __shared__ int gb[256];
    int t = threadIdx.x;
    int base = blockIdx.x * PART_M;
    int mloc = min(PART_M, E - base);
    int m4 = mloc >> 2;

    sc[t] = 0;
    cur[t] = 0;
    __syncthreads();
    const int4* d4 = (const int4*)(dst + base);
    const int4* s4 = (const int4*)(src + base);
    for (int k = t; k < m4; k += 256) {
        int4 v = d4[k];
        atomicAdd(&sc[v.x >> GSHIFT], 1);
        atomicAdd(&sc[v.y >> GSHIFT], 1);
        atomicAdd(&sc[v.z >> GSHIFT], 1);
        atomicAdd(&sc[v.w >> GSHIFT], 1);
    }
    for (int k = (m4 << 2) + t; k < mloc; k += 256)
        atomicAdd(&sc[dst[base + k] >> GSHIFT], 1);
    __syncthreads();
    int v = sc[t];
    gb[t] = v ? goff[t] + atomicAdd(&gcur[t], v) : 0;   // exclusive span
    __syncthreads();
    for (int k = t; k < m4; k += 256) {
        int4 dv = d4[k];
        int4 sv = s4[k];
        int b0 = dv.x >> GSHIFT;
        staged[gb[b0] + atomicAdd(&cur[b0], 1)] = (sv.x << GSHIFT) | (dv.x & (GSIZE - 1));
        int b1 = dv.y >> GSHIFT;
        staged[gb[b1] + atomicAdd(&cur[b1], 1)] = (sv.y << GSHIFT) | (dv.y & (GSIZE - 1));
        int b2 = dv.z >> GSHIFT;
        staged[gb[b2] + atomicAdd(&cur[b2], 1)] = (sv.z << GSHIFT) | (dv.z & (GSIZE - 1));
        int b3 = dv.w >> GSHIFT;
        staged[gb[b3] + atomicAdd(&cur[b3], 1)] = (sv.w << GSHIFT) | (dv.w & (GSIZE - 1));
    }
    for (int k = (m4 << 2) + t; k < mloc; k += 256) {
        int d = dst[base + k];
        int s = src[base + k];
        int b = d >> GSHIFT;
        staged[gb[b] + atomicAdd(&cur[b], 1)] = (s << GSHIFT) | (d & (GSIZE - 1));
    }
}

// ---------------- stage 4: per-group CSR finalize ----------------
__global__ __launch_bounds__(512) void build_csr(const int* __restrict__ staged,
                                                 const int* __restrict__ goff,
                                                 int* __restrict__ cnt,
                                                 float* __restrict__ dinv,
                                                 int* __restrict__ rowptr,
                                                 int* __restrict__ csr, int N) {
    __shared__ int hist[512];
    __shared__ int sc[512];
    __shared__ int lrow[512];
    __shared__ int cur[512];
    int t = threadIdx.x;
    int g = blockIdx.x;
    int s0 = goff[g], s1 = goff[g + 1];
    hist[t] = 0;
    cur[t] = 0;
    __syncthreads();
    for (int k = s0 + t; k < s1; k += 512)
        atomicAdd(&hist[staged[k] & (GSIZE - 1)], 1);
    __syncthreads();
    int v = hist[t];
    sc[t] = v;
    __syncthreads();
#pragma unroll
    for (int off = 1; off < 512; off <<= 1) {
        int x = (t >= off) ? sc[t - off] : 0;
        __syncthreads();
        sc[t] += x;
        __syncthreads();
    }
    int rp = s0 + sc[t] - v;
    lrow[t] = rp;
    int node = (g << GSHIFT) + t;
    if (node < N) {
        rowptr[node] = rp;
        cnt[node] = v;
        dinv[node] = rsqrtf(1.0f + (float)v);
    }
    __syncthreads();
    for (int k = s0 + t; k < s1; k += 512) {
        int p = staged[k];
        int dl = p & (GSIZE - 1);
        int pos = lrow[dl] + atomicAdd(&cur[dl], 1);
        csr[pos] = p >> GSHIFT;
    }
}

// ---------------- MFMA GEMM1 (BM=128, pipelined): Cb = (A_f32 @ B) * rs ----------------
__global__ __launch_bounds__(TPB) void gemm_mfma_f32in(const float* __restrict__ A,
                                                       const short* __restrict__ Bth,
                                                       const short* __restrict__ Btl,
                                                       const float* __restrict__ rs,
                                                       short* __restrict__ Cb, int M, int K) {
    __shared__ float Af[2][128 * 32];          // 2 x 16KB, granule col ^= (row&7)
    __shared__ short Bh[2][128 * 32];          // 2 x 8KB,  granule col ^= ((row>>1)&3)
    __shared__ short Bl[2][128 * 32];
    int t = threadIdx.x;
    int wave = t >> 6, lane = t & 63, quad = lane >> 4, l16 = lane & 15;
    int bm0 = blockIdx.x * 128;

    floatx4 acc[2][8];
#pragma unroll
    for (int mt = 0; mt < 2; ++mt)
#pragma unroll
        for (int nt = 0; nt < 8; ++nt) acc[mt][nt] = (floatx4){0.f, 0.f, 0.f, 0.f};

    auto stage = [&](int pb, int k0) {
#pragma unroll
        for (int i = 0; i < 4; ++i) {          // A: 1024 granules
            int g = i * 256 + t;
            int row = g >> 3, col = g & 7;
            int gr = bm0 + row;
            if (gr >= M) gr = M - 1;
            int scol = col ^ (row & 7);
            gload_lds16(A + (size_t)gr * K + k0 + scol * 4,
                        &Af[pb][(i * 256 + wave * 64) * 4]);
        }
#pragma unroll
        for (int i = 0; i < 2; ++i) {          // B: 512 granules each
            int g = i * 256 + t;
            int row = g >> 2, col = g & 3;
            int scol = col ^ ((row >> 1) & 3);
            size_t off = (size_t)row * K + k0 + scol * 8;
            int lb = (i * 256 + wave * 64) * 8;
            gload_lds16(Bth + off, &Bh[pb][lb]);
            gload_lds16(Btl + off, &Bl[pb][lb]);
        }
    };

    int nk = K >> 5;
    stage(0, 0);
    __syncthreads();
    int r0 = wave * 32 + l16;                  // mt=0 row; mt=1 row = r0+16
    int ac0 = ((quad * 2 + 0) ^ (r0 & 7)) * 4; // (r0&7)==((r0+16)&7)
    int ac1 = ((quad * 2 + 1) ^ (r0 & 7)) * 4;
    int bc = (quad ^ ((l16 >> 1) & 3)) * 8;
    for (int ks = 0; ks < nk; ++ks) {
        int pb = ks & 1;
        if (ks + 1 < nk) stage(pb ^ 1, (ks + 1) << 5);
        short8 a_h[2], a_l[2];
#pragma unroll
        for (int mt = 0; mt < 2; ++mt) {
            int r = r0 + mt * 16;
            float4 fa0 = *(const float4*)&Af[pb][r * 32 + ac0];
            float4 fa1 = *(const float4*)&Af[pb][r * 32 + ac1];
            short h, l;
            split2(fa0.x, h, l); a_h[mt][0] = h; a_l[mt][0] = l;
            split2(fa0.y, h, l); a_h[mt][1] = h; a_l[mt][1] = l;
            split2(fa0.z, h, l); a_h[mt][2] = h; a_l[mt][2] = l;
            split2(fa0.w, h, l); a_h[mt][3] = h; a_l[mt][3] = l;
            split2(fa1.x, h, l); a_h[mt][4] = h; a_l[mt][4] = l;
            split2(fa1.y, h, l); a_h[mt][5] = h; a_l[mt][5] = l;
            split2(fa1.z, h, l); a_h[mt][6] = h; a_l[mt][6] = l;
            split2(fa1.w, h, l); a_h[mt][7] = h; a_l[mt][7] = l;
        }
#pragma unroll
        for (int nt = 0; nt < 8; ++nt) {
            int bn = nt * 16 + l16;
            short8 b_h = *(const short8*)&Bh[pb][bn * 32 + bc];
            short8 b_l = *(const short8*)&Bl[pb][bn * 32 + bc];
#pragma unroll
            for (int mt = 0; mt < 2; ++mt) {
                acc[mt][nt] = __builtin_amdgcn_mfma_f32_16x16x32_bf16(a_l[mt], b_h, acc[mt][nt], 0, 0, 0);
                acc[mt][nt] = __builtin_amdgcn_mfma_f32_16x16x32_bf16(a_h[mt], b_l, acc[mt][nt], 0, 0, 0);
                acc[mt][nt] = __builtin_amdgcn_mfma_f32_16x16x32_bf16(a_h[mt], b_h, acc[mt][nt], 0, 0, 0);
            }
        }
        __syncthreads();
    }
#pragma unroll
    for (int mt = 0; mt < 2; ++mt)
#pragma unroll
        for (int reg = 0; reg < 4; ++reg) {
            int gr = bm0 + wave * 32 + mt * 16 + quad * 4 + reg;
            if (gr < M) {
                float s = rs[gr];
                short* cp = Cb + (size_t)gr * 128;
#pragma unroll
                for (int nt = 0; nt < 8; ++nt) cp[nt * 16 + l16] = bf16_rtn(acc[mt][nt][reg] * s);
            }
        }
}

// ---------------- MFMA GEMM2 (BM=128, pipelined): Cb = ((AH+AL) @ B) * rs ----------------
__global__ __launch_bounds__(TPB) void gemm_mfma_bfin(const short* __restrict__ AH,
                                                      const short* __restrict__ AL,
                                                      const short* __restrict__ Bth,
                                                      const short* __restrict__ Btl,
                                                      const float* __restrict__ rs,
                                                      short* __restrict__ Cb, int M, int K) {
    __shared__ short Ah[2][128 * 32], Al[2][128 * 32];  // 2 x 8KB each
    __shared__ short Bh[2][128 * 32], Bl[2][128 * 32];  // 2 x 8KB each
    int t = threadIdx.x;
    int wave = t >> 6, lane = t & 63, quad = lane >> 4, l16 = lane & 15;
    int bm0 = blockIdx.x * 128;

    floatx4 acc[2][8];
#pragma unroll
    for (int mt = 0; mt < 2; ++mt)
#pragma unroll
        for (int nt = 0; nt < 8; ++nt) acc[mt][nt] = (floatx4){0.f, 0.f, 0.f, 0.f};

    auto stage = [&](int pb, int k0) {
#pragma unroll
        for (int i = 0; i < 2; ++i) {          // A: 512 granules each (hi,lo)
            int g = i * 256 + t;
            int row = g >> 2, col = g & 3;
            int gr = bm0 + row;
            if (gr >= M) gr = M - 1;
            int scol = col ^ ((row >> 1) & 3);
            size_t off = (size_t)gr * K + k0 + scol * 8;
            int lb = (i * 256 + wave * 64) * 8;
            gload_lds16(AH + off, &Ah[pb][lb]);
            gload_lds16(AL + off, &Al[pb][lb]);
        }
#pragma unroll
        for (int i = 0; i < 2; ++i) {          // B: 512 granules each
            int g = i * 256 + t;
            int row = g >> 2, col = g & 3;
            int scol = col ^ ((row >> 1) & 3);
            size_t off = (size_t)row * K + k0 + scol * 8;
            int lb = (i * 256 + wave * 64) * 8;
            gload_lds16(Bth + off, &Bh[pb][lb]);
            gload_lds16(Btl + off, &Bl[pb][lb]);
        }
    };

    int nk = K >> 5;
    stage(0, 0);
    __syncthreads();
    int r0 = wave * 32 + l16;
    int ac = (quad ^ ((r0 >> 1) & 3)) * 8;     // ((r0)>>1&3) == ((r0+16)>>1&3)
    int bc = (quad ^ ((l16 >> 1) & 3)) * 8;
    for (int ks = 0; ks < nk; ++ks) {
        int pb = ks & 1;
        if (ks + 1 < nk) stage(pb ^ 1, (ks + 1) << 5);
        short8 a_h[2], a_l[2];
#pragma unroll
        for (int mt = 0; mt < 2; ++mt) {
            int r = r0 + mt * 16;
            a_h[mt] = *(const short8*)&Ah[pb][r * 32 + ac];
            a_l[mt] = *(const short8*)&Al[pb][r * 32 + ac];
        }
#pragma unroll
        for (int nt = 0; nt < 8; ++nt) {
            int bn = nt * 16 + l16;
            short8 b_h = *(const short8*)&Bh[pb][bn * 32 + bc];
            short8 b_l = *(const short8*)&Bl[pb][bn * 32 + bc];
#pragma unroll
            for (int mt = 0; mt < 2; ++mt) {
                acc[mt][nt] = __builtin_amdgcn_mfma_f32_16x16x32_bf16(a_l[mt], b_h, acc[mt][nt], 0, 0, 0);
                acc[mt][nt] = __builtin_amdgcn_mfma_f32_16x16x32_bf16(a_h[mt], b_l, acc[mt][nt], 0, 0, 0);
                acc[mt][nt] = __builtin_amdgcn_mfma_f32_16x16x32_bf16(a_h[mt], b_h, acc[mt][nt], 0, 0, 0);
            }
        }
        __syncthreads();
    }
#pragma unroll
    for (int mt = 0; mt < 2; ++mt)
#pragma unroll
        for (int reg = 0; reg < 4; ++reg) {
            int gr = bm0 + wave * 32 + mt * 16 + quad * 4 + reg;
            if (gr < M) {
                float s = rs[gr];
                short* cp = Cb + (size_t)gr * 128;
#pragma unroll
                for (int nt = 0; nt < 8; ++nt) cp[nt * 16 + l16] = bf16_rtn(acc[mt][nt][reg] * s);
            }
        }
}

// ---------------- gather 1: hidden = relu(dinv*(self+sum nbrs) + b1) -> bf16 hi/lo ----------------
__global__ __launch_bounds__(TPB) void gather_hidden(const int* __restrict__ csr,
                                                     const int* __restrict__ rowptr,
                                                     const int* __restrict__ cnt,
                                                     const float* __restrict__ dinv,
                                                     const short* __restrict__ hs,
                                                     const float* __restrict__ b1,
                                                     short* __restrict__ hidH,
                                                     short* __restrict__ hidL, int N) {
    size_t t = (size_t)blockIdx.x * TPB + threadIdx.x;
    int nid = (int)(t >> 4);
    int lane = threadIdx.x & 15;
    if (nid >= N) return;
    int start = rowptr[nid];
    int deg = cnt[nid];
    const uint4v* hp = (const uint4v*)hs;  // row = 16 x 16B
    float acc[8] = {0, 0, 0, 0, 0, 0, 0, 0};
    addrow(acc, hp[(size_t)nid * 16 + lane]);  // self
    gather_accum(acc, csr, start, deg, hp, lane);
    float di = dinv[nid];
    float4 b0 = ((const float4*)b1)[lane * 2];
    float4 b1v = ((const float4*)b1)[lane * 2 + 1];
    float bb[8] = {b0.x, b0.y, b0.z, b0.w, b1v.x, b1v.y, b1v.z, b1v.w};
    unsigned hiw[8];
    short low[8];
#pragma unroll
    for (int i = 0; i < 8; ++i) {
        float h = fmaxf(fmaf(di, acc[i], bb[i]), 0.f);
        unsigned u = __float_as_uint(h);
        hiw[i] = u >> 16;
        float hf = __uint_as_float(u & 0xFFFF0000u);
        low[i] = bf16_rtn(h - hf);
    }
    uint4v ph, pl;
    ph[0] = hiw[0] | (hiw[1] << 16);
    ph[1] = hiw[2] | (hiw[3] << 16);
    ph[2] = hiw[4] | (hiw[5] << 16);
    ph[3] = hiw[6] | (hiw[7] << 16);
    pl[0] = (unsigned short)low[0] | ((unsigned)(unsigned short)low[1] << 16);
    pl[1] = (unsigned short)low[2] | ((unsigned)(unsigned short)low[3] << 16);
    pl[2] = (unsigned short)low[4] | ((unsigned)(unsigned short)low[5] << 16);
    pl[3] = (unsigned short)low[6] | ((unsigned)(unsigned short)low[7] << 16);
    ((uint4v*)hidH)[(size_t)nid * 16 + lane] = ph;   // normal store: keep L3-resident
    ((uint4v*)hidL)[(size_t)nid * 16 + lane] = pl;   // (read back by gemm_bfin)
}

// ---------------- gather 2: out = dinv*(self+sum nbrs) + bcat -> f32 mu|logvar ----------------
__global__ __launch_bounds__(TPB) void gather_out(const int* __restrict__ csr,
                                                  const int* __restrict__ rowptr,
                                                  const int* __restrict__ cnt,
                                                  const float* __restrict__ dinv,
                                                  const short* __restrict__ hs,
                                                  const float* __restrict__ bcat,
                                                  float* __restrict__ out, int N) {
    size_t t = (size_t)blockIdx.x * TPB + threadIdx.x;
    int nid = (int)(t >> 4);
    int lane = threadIdx.x & 15;
    if (nid >= N) return;
    int start = rowptr[nid];
    int deg = cnt[nid];
    const uint4v* hp = (const uint4v*)hs;
    float acc[8] = {0, 0, 0, 0, 0, 0, 0, 0};
    addrow(acc, hp[(size_t)nid * 16 + lane]);
    gather_accum(acc, csr, start, deg, hp, lane);
    float di = dinv[nid];
    float4 b0 = ((const float4*)bcat)[lane * 2];
    float4 b1v = ((const float4*)bcat)[lane * 2 + 1];
    floatx4 r0, r1;
    r0[0] = fmaf(di, acc[0], b0.x);
    r0[1] = fmaf(di, acc[1], b0.y);
    r0[2] = fmaf(di, acc[2], b0.z);
    r0[3] = fmaf(di, acc[3], b0.w);
    r1[0] = fmaf(di, acc[4], b1v.x);
    r1[1] = fmaf(di, acc[5], b1v.y);
    r1[2] = fmaf(di, acc[6], b1v.z);
    r1[3] = fmaf(di, acc[7], b1v.w);
    int f = lane * 8;  // 0..120
    float* dp = (f < 64) ? (out + (size_t)nid * 64 + f)
                         : (out + (size_t)N * 64 + (size_t)nid * 64 + (f - 64));
    __builtin_nontemporal_store(r0, (floatx4*)dp);    // final output: never re-read
    __builtin_nontemporal_store(r1, (floatx4*)(dp + 4));
}

extern "C" void kernel_launch(void* const* d_in, const int* in_sizes, int n_in,
                              void* d_out, int out_size, void* d_ws, size_t ws_size,
                              hipStream_t stream) {
    const float* x  = (const float*)d_in[0];
    const float* w1 = (const float*)d_in[1];
    const float* b1 = (const float*)d_in[2];
    const float* w2 = (const float*)d_in[3];
    const float* b2 = (const float*)d_in[4];
    const float* w3 = (const float*)d_in[5];
    const float* b3 = (const float*)d_in[6];
    const int*   ei = (const int*)d_in[7];

    const int N = in_sizes[0] / 256;   // 100000
    const int E = in_sizes[7] / 2;     // 1600000
    const int K1 = 256;

    float* out = (float*)d_out;

    // workspace carve-up (R8 layout)
    size_t nh = (size_t)N * 128;
    short* hs1    = (short*)d_ws;          // N*128 bf16
    short* hidH   = hs1 + nh;
    short* hidL   = hidH + nh;
    short* hs2    = hidL + nh;
    int*   cnt    = (int*)(hs2 + nh);
    float* dinv   = (float*)(cnt + N);
    int*   rowptr = (int*)(dinv + N);
    int*   cursor = rowptr + N;            // ghist[256]|gcur[256]|done|goff[257]
    int*   bsum   = cursor + N;
    float* bcat   = (float*)(bsum + 512);
    short* w1t_h  = (short*)(bcat + 128);
    short* w1t_l  = w1t_h + 128 * 256;
    short* wct_h  = w1t_l + 128 * 256;
    short* wct_l  = wct_h + 128 * 128;
    int*   csr    = (int*)(wct_l + 128 * 128);

    const int* srcp = ei;
    const int* dstp = ei + E;

    const int ngrp = (N + GSIZE - 1) >> GSHIFT;   // 196
    int* gcur   = cursor + 256;  // [256]
    int* goff   = cursor + 513;  // [257]
    int* staged = (int*)hs2;     // alias: hs2 not live until gemm2

    // 1) prep (weights + bias + counter zero)
    prep_all<<<193, TPB, 0, stream>>>(w1, w2, b2, w3, b3, w1t_h, w1t_l, wct_h, wct_l,
                                      bcat, cursor);

    // 2) CSR build: group hist (+inline scan in last block) -> partition -> finalize
    int gc_blocks = ((E >> 2) + TPB * 4 - 1) / (TPB * 4);
    group_count<<<gc_blocks, TPB, 0, stream>>>(dstp, cursor, E);
    partition_kernel<<<(E + PART_M - 1) / PART_M, 256, 0, stream>>>(srcp, dstp, goff, gcur,
                                                                    staged, E);
    build_csr<<<ngrp, 512, 0, stream>>>(staged, goff, cnt, dinv, rowptr, csr, N);

    // 3) hs1 = (x @ w1) * dinv  -> bf16
    gemm_mfma_f32in<<<(N + 127) / 128, TPB, 0, stream>>>(x, w1t_h, w1t_l, dinv, hs1, N, K1);

    // 4) hidden = relu(dinv*(self+nbrs) + b1) -> hi/lo bf16
    size_t gthreads = (size_t)N * 16;
    gather_hidden<<<(unsigned)((gthreads + TPB - 1) / TPB), TPB, 0, stream>>>(
        csr, rowptr, cnt, dinv, hs1, b1, hidH, hidL, N);

    // 5) hs2 = (hidden @ wcat) * dinv -> bf16   (overwrites staged — dead by now)
    gemm_mfma_bfin<<<(N + 127) / 128, TPB, 0, stream>>>(hidH, hidL, wct_h, wct_l, dinv, hs2, N, 128);

    // 6) out = dinv*(self+nbrs) + bcat -> mu | logvar (f32)
    gather_out<<<(unsigned)((gthreads + TPB - 1) / TPB), TPB, 0, stream>>>(
        csr, rowptr, cnt, dinv, hs2, bcat, out, N);
}

// Round 10
// 380.724 us; speedup vs baseline: 1.2084x; 1.0685x over previous
//
#include <hip/hip_runtime.h>

// GCN-VAE encoder forward on MI355X — R13: fixed-capacity group spans
// (group_count + device-scope scan deleted).
//
// agg[d] = dinv[d] * ( hs[d] + sum_{s in N(d)} hs[s] ),  hs := h*dinv
// hs1, hs2 stored bf16 (RTN); hidden bf16 hi+lo (exact split).
//
// R13: partition reserves from gcur[g] and writes staged at g*CAP+off
//   (CAP=12288, 45-sigma headroom; staged=hs2 alias, 9.6MB). build_csr
//   scans the 196-entry gcur per block (L2-hot) to get exact csr offsets
//   -> csr stays E-sized, rowptr/cnt/dinv unchanged. group_count and the
//   threadfence/last-block-done scan are GONE. 8 -> 7 dispatches.
//
// R12: BM=128 GEMM tiles; NT only on final out store (hidH/L L3-resident).
// R11: shfl-shared gather indices; direct-write partition.
// R9 post-mortem: NO gather/GEMM fusion. R8: gathers at random-256B wall
//   (~66us each; depth/issue-count/NT all null).
// R6: GEMMs = 2-phase global_load_lds pipelines (src-side XOR swizzle).
//
// ws: hs1[N*128]bf | hidH | hidL | hs2 (aliased staged[196*CAP] during CSR
//     build) | cnt[N] | dinv[N] | rowptr[N] | cursor (gcur[256]) |
//     bsum[512] | bcat[128] | w1t_h/l | wct_h/l | csr[E]

#define TPB 256
#define GSHIFT 9
#define GSIZE 512
#define PART_M 4096   // edges per partition WG
#define GCAP 12288    // fixed staged span per group

typedef __attribute__((ext_vector_type(8))) short short8;
typedef __attribute__((ext_vector_type(4))) short short4v;
typedef __attribute__((ext_vector_type(4))) float floatx4;
typedef __attribute__((ext_vector_type(4))) unsigned int uint4v;

__device__ __forceinline__ void split2(float v, short& hi, short& lo) {
    unsigned u = __float_as_uint(v);
    float hf = __uint_as_float(u & 0xFFFF0000u);
    float lf = v - hf;                       // exact
    hi = (short)(u >> 16);
    lo = (short)(__float_as_uint(lf) >> 16);
}

__device__ __forceinline__ short bf16_rtn(float v) {
    unsigned u = __float_as_uint(v);
    u += 0x7FFF + ((u >> 16) & 1);           // round to nearest even
    return (short)(u >> 16);
}

__device__ __forceinline__ void addrow(float* a, uint4v v) {
    a[0] += __uint_as_float(v[0] << 16); a[1] += __uint_as_float(v[0] & 0xFFFF0000u);
    a[2] += __uint_as_float(v[1] << 16); a[3] += __uint_as_float(v[1] & 0xFFFF0000u);
    a[4] += __uint_as_float(v[2] << 16); a[5] += __uint_as_float(v[2] & 0xFFFF0000u);
    a[6] += __uint_as_float(v[3] << 16); a[7] += __uint_as_float(v[3] & 0xFFFF0000u);
}

// gather loop: indices loaded once per 16-row batch, broadcast via shfl.
__device__ __forceinline__ void gather_accum(float* acc, const int* __restrict__ csr,
                                             int start, int deg, const uint4v* hp,
                                             int l16) {
    for (int jj = 0; jj < deg; jj += 16) {
        int rem = deg - jj;
        if (rem > 16) rem = 16;
        int il = (l16 < rem) ? l16 : rem - 1;
        int myIdx = csr[start + jj + il];
        int r = 0;
        for (; r + 3 < rem; r += 4) {
            int i0 = __shfl(myIdx, r + 0, 16);
            int i1 = __shfl(myIdx, r + 1, 16);
            int i2 = __shfl(myIdx, r + 2, 16);
            int i3 = __shfl(myIdx, r + 3, 16);
            uint4v v0 = hp[(size_t)i0 * 16 + l16];
            uint4v v1 = hp[(size_t)i1 * 16 + l16];
            uint4v v2 = hp[(size_t)i2 * 16 + l16];
            uint4v v3 = hp[(size_t)i3 * 16 + l16];
            addrow(acc, v0);
            addrow(acc, v1);
            addrow(acc, v2);
            addrow(acc, v3);
        }
        for (; r < rem; ++r) {
            int i = __shfl(myIdx, r, 16);
            addrow(acc, hp[(size_t)i * 16 + l16]);
        }
    }
}

// async 16B global -> LDS (linear dest: wave-uniform base + lane*16)
__device__ __forceinline__ void gload_lds16(const void* g, void* l) {
    __builtin_amdgcn_global_load_lds(
        (const __attribute__((address_space(1))) unsigned int*)g,
        (__attribute__((address_space(3))) unsigned int*)l, 16, 0, 0);
}

// ---------------- prep_all: weight transpose/split + bias cat + counter zero ----------------
__global__ __launch_bounds__(TPB) void prep_all(const float* __restrict__ w1,
                                                const float* __restrict__ w2,
                                                const float* __restrict__ b2,
                                                const float* __restrict__ w3,
                                                const float* __restrict__ b3,
                                                short* __restrict__ w1t_h,
                                                short* __restrict__ w1t_l,
                                                short* __restrict__ wct_h,
                                                short* __restrict__ wct_l,
                                                float* __restrict__ bcat,
                                                int* __restrict__ gcur) {
    int b = blockIdx.x, t0 = threadIdx.x;
    if (b < 128) {
        int t = b * TPB + t0;                // < 128*256
        int k = t & 255, n = t >> 8;
        float v = w1[(size_t)k * 128 + n];
        short h, l;
        split2(v, h, l);
        w1t_h[t] = h;
        w1t_l[t] = l;
    } else if (b < 192) {
        int t = (b - 128) * TPB + t0;        // < 128*128
        int k = t & 127, n = t >> 7;
        float v = (n < 64) ? w2[(size_t)k * 64 + n] : w3[(size_t)k * 64 + (n - 64)];
        short h, l;
        split2(v, h, l);
        wct_h[t] = h;
        wct_l[t] = l;
        if (t < 64) { bcat[t] = b2[t]; bcat[64 + t] = b3[t]; }
    } else {
        gcur[t0] = 0;                        // [256]
    }
}

// ---------------- partition: edges -> fixed-capacity group spans ----------------
__global__ __launch_bounds__(256) void partition_kernel(const int* __restrict__ src,
                                                        const int* __restrict__ dst,
                                                        int* __restrict__ gcur,
                                                        int* __restrict__ staged, int E) {
    __shared__ int sc[256];
    __shared__ int cur[256];
    __shared__ int gb[256];
    int t = threadIdx.x;
    int base = blockIdx.x * PART_M;
    int mloc = min(PART_M, E - base);
    int m4 = mloc >> 2;

    sc[t] = 0;
    cur[t] = 0;
    __syncthreads();
    const int4* d4 = (const int4*)(dst + base);
    const int4* s4 = (const int4*)(src + base);
    for (int k = t; k < m4; k += 256) {
        int4 v = d4[k];
        atomicAdd(&sc[v.x >> GSHIFT], 1);
        atomicAdd(&sc[v.y >> GSHIFT], 1);
        atomicAdd(&sc[v.z >> GSHIFT], 1);
        atomicAdd(&sc[v.w >> GSHIFT], 1);
    }
    for (int k = (m4 << 2) + t; k < mloc; k += 256)
        atomicAdd(&sc[dst[base + k] >> GSHIFT], 1);
    __syncthreads();
    int v = sc[t];
    gb[t] = v ? t * GCAP + atomicAdd(&gcur[t], v) : 0;   // exclusive span slice
    __syncthreads();
    for (int k = t; k < m4; k += 256) {
        int4 dv = d4[k];
        int4 sv = s4[k];
        int b0 = dv.x >> GSHIFT;
        staged[gb[b0] + atomicAdd(&cur[b0], 1)] = (sv.x << GSHIFT) | (dv.x & (GSIZE - 1));
        int b1 = dv.y >> GSHIFT;
        staged[gb[b1] + atomicAdd(&cur[b1], 1)] = (sv.y << GSHIFT) | (dv.y & (GSIZE - 1));
        int b2 = dv.z >> GSHIFT;
        staged[gb[b2] + atomicAdd(&cur[b2], 1)] = (sv.z << GSHIFT) | (dv.z & (GSIZE - 1));
        int b3 = dv.w >> GSHIFT;
        staged[gb[b3] + atomicAdd(&cur[b3], 1)] = (sv.w << GSHIFT) | (dv.w & (GSIZE - 1));
    }
    for (int k = (m4 << 2) + t; k < mloc; k += 256) {
        int d = dst[base + k];
        int s = src[base + k];
        int b = d >> GSHIFT;
        staged[gb[b] + atomicAdd(&cur[b], 1)] = (s << GSHIFT) | (d & (GSIZE - 1));
    }
}

// ---------------- build_csr: per-group finalize (exact offsets via gcur scan) ----------------
__global__ __launch_bounds__(512) void build_csr(const int* __restrict__ staged,
                                                 const int* __restrict__ gcur,
                                                 int* __restrict__ cnt,
                                                 float* __restrict__ dinv,
                                                 int* __restrict__ rowptr,
                                                 int* __restrict__ csr, int N) {
    __shared__ int pre[256];
    __shared__ int hist[512];
    __shared__ int sc[512];
    __shared__ int lrow[512];
    __shared__ int cur[512];
    int t = threadIdx.x;
    int g = blockIdx.x;
    int ngrp = (N + GSIZE - 1) >> GSHIFT;
    // inclusive scan of gcur[0..ngrp) in first 256 lanes (ngrp <= 256)
    if (t < 256) pre[t] = (t < ngrp) ? gcur[t] : 0;
    hist[t] = 0;
    cur[t] = 0;
    __syncthreads();
#pragma unroll
    for (int off = 1; off < 256; off <<= 1) {
        int x = (t < 256 && t >= off) ? pre[t - off] : 0;
        __syncthreads();
        if (t < 256) pre[t] += x;
        __syncthreads();
    }
    int count = gcur[g];
    int s0_out = pre[g] - count;     // exact exclusive offset into csr
    int s0_in = g * GCAP;
    for (int k = t; k < count; k += 512)
        atomicAdd(&hist[staged[s0_in + k] & (GSIZE - 1)], 1);
    __syncthreads();
    int v = hist[t];
    sc[t] = v;
    __syncthreads();
#pragma unroll
    for (int off = 1; off < 512; off <<= 1) {
        int x = (t >= off) ? sc[t - off] : 0;
        __syncthreads();
        sc[t] += x;
        __syncthreads();
    }
    int rp = s0_out + sc[t] - v;
    lrow[t] = rp;
    int node = (g << GSHIFT) + t;
    if (node < N) {
        rowptr[node] = rp;
        cnt[node] = v;
        dinv[node] = rsqrtf(1.0f + (float)v);
    }
    __syncthreads();
    for (int k = t; k < count; k += 512) {
        int p = staged[s0_in + k];
        int dl = p & (GSIZE - 1);
        int pos = lrow[dl] + atomicAdd(&cur[dl], 1);
        csr[pos] = p >> GSHIFT;
    }
}

// ---------------- MFMA GEMM1 (BM=128, pipelined): Cb = (A_f32 @ B) * rs ----------------
__global__ __launch_bounds__(TPB) void gemm_mfma_f32in(const float* __restrict__ A,
                                                       const short* __restrict__ Bth,
                                                       const short* __restrict__ Btl,
                                                       const float* __restrict__ rs,
                                                       short* __restrict__ Cb, int M, int K) {
    __shared__ float Af[2][128 * 32];          // 2 x 16KB, granule col ^= (row&7)
    __shared__ short Bh[2][128 * 32];          // 2 x 8KB,  granule col ^= ((row>>1)&3)
    __shared__ short Bl[2][128 * 32];
    int t = threadIdx.x;
    int wave = t >> 6, lane = t & 63, quad = lane >> 4, l16 = lane & 15;
    int bm0 = blockIdx.x * 128;

    floatx4 acc[2][8];
#pragma unroll
    for (int mt = 0; mt < 2; ++mt)
#pragma unroll
        for (int nt = 0; nt < 8; ++nt) acc[mt][nt] = (floatx4){0.f, 0.f, 0.f, 0.f};

    auto stage = [&](int pb, int k0) {
#pragma unroll
        for (int i = 0; i < 4; ++i) {          // A: 1024 granules
            int g = i * 256 + t;
            int row = g >> 3, col = g & 7;
            int gr = bm0 + row;
            if (gr >= M) gr = M - 1;
            int scol = col ^ (row & 7);
            gload_lds16(A + (size_t)gr * K + k0 + scol * 4,
                        &Af[pb][(i * 256 + wave * 64) * 4]);
        }
#pragma unroll
        for (int i = 0; i < 2; ++i) {          // B: 512 granules each
            int g = i * 256 + t;
            int row = g >> 2, col = g & 3;
            int scol = col ^ ((row >> 1) & 3);
            size_t off = (size_t)row * K + k0 + scol * 8;
            int lb = (i * 256 + wave * 64) * 8;
            gload_lds16(Bth + off, &Bh[pb][lb]);
            gload_lds16(Btl + off, &Bl[pb][lb]);
        }
    };

    int nk = K >> 5;
    stage(0, 0);
    __syncthreads();
    int r0 = wave * 32 + l16;                  // mt=0 row; mt=1 row = r0+16
    int ac0 = ((quad * 2 + 0) ^ (r0 & 7)) * 4; // (r0&7)==((r0+16)&7)
    int ac1 = ((quad * 2 + 1) ^ (r0 & 7)) * 4;
    int bc = (quad ^ ((l16 >> 1) & 3)) * 8;
    for (int ks = 0; ks < nk; ++ks) {
        int pb = ks & 1;
        if (ks + 1 < nk) stage(pb ^ 1, (ks + 1) << 5);
        short8 a_h[2], a_l[2];
#pragma unroll
        for (int mt = 0; mt < 2; ++mt) {
            int r = r0 + mt * 16;
            float4 fa0 = *(const float4*)&Af[pb][r * 32 + ac0];
            float4 fa1 = *(const float4*)&Af[pb][r * 32 + ac1];
            short h, l;
            split2(fa0.x, h, l); a_h[mt][0] = h; a_l[mt][0] = l;
            split2(fa0.y, h, l); a_h[mt][1] = h; a_l[mt][1] = l;
            split2(fa0.z, h, l); a_h[mt][2] = h; a_l[mt][2] = l;
            split2(fa0.w, h, l); a_h[mt][3] = h; a_l[mt][3] = l;
            split2(fa1.x, h, l); a_h[mt][4] = h; a_l[mt][4] = l;
            split2(fa1.y, h, l); a_h[mt][5] = h; a_l[mt][5] = l;
            split2(fa1.z, h, l); a_h[mt][6] = h; a_l[mt][6] = l;
            split2(fa1.w, h, l); a_h[mt][7] = h; a_l[mt][7] = l;
        }
#pragma unroll
        for (int nt = 0; nt < 8; ++nt) {
            int bn = nt * 16 + l16;
            short8 b_h = *(const short8*)&Bh[pb][bn * 32 + bc];
            short8 b_l = *(const short8*)&Bl[pb][bn * 32 + bc];
#pragma unroll
            for (int mt = 0; mt < 2; ++mt) {
                acc[mt][nt] = __builtin_amdgcn_mfma_f32_16x16x32_bf16(a_l[mt], b_h, acc[mt][nt], 0, 0, 0);
                acc[mt][nt] = __builtin_amdgcn_mfma_f32_16x16x32_bf16(a_h[mt], b_l, acc[mt][nt], 0, 0, 0);
                acc[mt][nt] = __builtin_amdgcn_mfma_f32_16x16x32_bf16(a_h[mt], b_h, acc[mt][nt], 0, 0, 0);
            }
        }
        __syncthreads();
    }
#pragma unroll
    for (int mt = 0; mt < 2; ++mt)
#pragma unroll
        for (int reg = 0; reg < 4; ++reg) {
            int gr = bm0 + wave * 32 + mt * 16 + quad * 4 + reg;
            if (gr < M) {
                float s = rs[gr];
                short* cp = Cb + (size_t)gr * 128;
#pragma unroll
                for (int nt = 0; nt < 8; ++nt) cp[nt * 16 + l16] = bf16_rtn(acc[mt][nt][reg] * s);
            }
        }
}

// ---------------- MFMA GEMM2 (BM=128, pipelined): Cb = ((AH+AL) @ B) * rs ----------------
__global__ __launch_bounds__(TPB) void gemm_mfma_bfin(const short* __restrict__ AH,
                                                      const short* __restrict__ AL,
                                                      const short* __restrict__ Bth,
                                                      const short* __restrict__ Btl,
                                                      const float* __restrict__ rs,
                                                      short* __restrict__ Cb, int M, int K) {
    __shared__ short Ah[2][128 * 32], Al[2][128 * 32];  // 2 x 8KB each
    __shared__ short Bh[2][128 * 32], Bl[2][128 * 32];  // 2 x 8KB each
    int t = threadIdx.x;
    int wave = t >> 6, lane = t & 63, quad = lane >> 4, l16 = lane & 15;
    int bm0 = blockIdx.x * 128;

    floatx4 acc[2][8];
#pragma unroll
    for (int mt = 0; mt < 2; ++mt)
#pragma unroll
        for (int nt = 0; nt < 8; ++nt) acc[mt][nt] = (floatx4){0.f, 0.f, 0.f, 0.f};

    auto stage = [&](int pb, int k0) {
#pragma unroll
        for (int i = 0; i < 2; ++i) {          // A: 512 granules each (hi,lo)
            int g = i * 256 + t;
            int row = g >> 2, col = g & 3;
            int gr = bm0 + row;
            if (gr >= M) gr = M - 1;
            int scol = col ^ ((row >> 1) & 3);
            size_t off = (size_t)gr * K + k0 + scol * 8;
            int lb = (i * 256 + wave * 64) * 8;
            gload_lds16(AH + off, &Ah[pb][lb]);
            gload_lds16(AL + off, &Al[pb][lb]);
        }
#pragma unroll
        for (int i = 0; i < 2; ++i) {          // B: 512 granules each
            int g = i * 256 + t;
            int row = g >> 2, col = g & 3;
            int scol = col ^ ((row >> 1) & 3);
            size_t off = (size_t)row * K + k0 + scol * 8;
            int lb = (i * 256 + wave * 64) * 8;
            gload_lds16(Bth + off, &Bh[pb][lb]);
            gload_lds16(Btl + off, &Bl[pb][lb]);
        }
    };

    int nk = K >> 5;
    stage(0, 0);
    __syncthreads();
    int r0 = wave * 32 + l16;
    int ac = (quad ^ ((r0 >> 1) & 3)) * 8;     // ((r0)>>1&3) == ((r0+16)>>1&3)
    int bc = (quad ^ ((l16 >> 1) & 3)) * 8;
    for (int ks = 0; ks < nk; ++ks) {
        int pb = ks & 1;
        if (ks + 1 < nk) stage(pb ^ 1, (ks + 1) << 5);
        short8 a_h[2], a_l[2];
#pragma unroll
        for (int mt = 0; mt < 2; ++mt) {
            int r = r0 + mt * 16;
            a_h[mt] = *(const short8*)&Ah[pb][r * 32 + ac];
            a_l[mt] = *(const short8*)&Al[pb][r * 32 + ac];
        }
#pragma unroll
        for (int nt = 0; nt < 8; ++nt) {
            int bn = nt * 16 + l16;
            short8 b_h = *(const short8*)&Bh[pb][bn * 32 + bc];
            short8 b_l = *(const short8*)&Bl[pb][bn * 32 + bc];
#pragma unroll
            for (int mt = 0; mt < 2; ++mt) {
                acc[mt][nt] = __builtin_amdgcn_mfma_f32_16x16x32_bf16(a_l[mt], b_h, acc[mt][nt], 0, 0, 0);
                acc[mt][nt] = __builtin_amdgcn_mfma_f32_16x16x32_bf16(a_h[mt], b_l, acc[mt][nt], 0, 0, 0);
                acc[mt][nt] = __builtin_amdgcn_mfma_f32_16x16x32_bf16(a_h[mt], b_h, acc[mt][nt], 0, 0, 0);
            }
        }
        __syncthreads();
    }
#pragma unroll
    for (int mt = 0; mt < 2; ++mt)
#pragma unroll
        for (int reg = 0; reg < 4; ++reg) {
            int gr = bm0 + wave * 32 + mt * 16 + quad * 4 + reg;
            if (gr < M) {
                float s = rs[gr];
                short* cp = Cb + (size_t)gr * 128;
#pragma unroll
                for (int nt = 0; nt < 8; ++nt) cp[nt * 16 + l16] = bf16_rtn(acc[mt][nt][reg] * s);
            }
        }
}

// ---------------- gather 1: hidden = relu(dinv*(self+sum nbrs) + b1) -> bf16 hi/lo ----------------
__global__ __launch_bounds__(TPB) void gather_hidden(const int* __restrict__ csr,
                                                     const int* __restrict__ rowptr,
                                                     const int* __restrict__ cnt,
                                                     const float* __restrict__ dinv,
                                                     const short* __restrict__ hs,
                                                     const float* __restrict__ b1,
                                                     short* __restrict__ hidH,
                                                     short* __restrict__ hidL, int N) {
    size_t t = (size_t)blockIdx.x * TPB + threadIdx.x;
    int nid = (int)(t >> 4);
    int lane = threadIdx.x & 15;
    if (nid >= N) return;
    int start = rowptr[nid];
    int deg = cnt[nid];
    const uint4v* hp = (const uint4v*)hs;  // row = 16 x 16B
    float acc[8] = {0, 0, 0, 0, 0, 0, 0, 0};
    addrow(acc, hp[(size_t)nid * 16 + lane]);  // self
    gather_accum(acc, csr, start, deg, hp, lane);
    float di = dinv[nid];
    float4 b0 = ((const float4*)b1)[lane * 2];
    float4 b1v = ((const float4*)b1)[lane * 2 + 1];
    float bb[8] = {b0.x, b0.y, b0.z, b0.w, b1v.x, b1v.y, b1v.z, b1v.w};
    unsigned hiw[8];
    short low[8];
#pragma unroll
    for (int i = 0; i < 8; ++i) {
        float h = fmaxf(fmaf(di, acc[i], bb[i]), 0.f);
        unsigned u = __float_as_uint(h);
        hiw[i] = u >> 16;
        float hf = __uint_as_float(u & 0xFFFF0000u);
        low[i] = bf16_rtn(h - hf);
    }
    uint4v ph, pl;
    ph[0] = hiw[0] | (hiw[1] << 16);
    ph[1] = hiw[2] | (hiw[3] << 16);
    ph[2] = hiw[4] | (hiw[5] << 16);
    ph[3] = hiw[6] | (hiw[7] << 16);
    pl[0] = (unsigned short)low[0] | ((unsigned)(unsigned short)low[1] << 16);
    pl[1] = (unsigned short)low[2] | ((unsigned)(unsigned short)low[3] << 16);
    pl[2] = (unsigned short)low[4] | ((unsigned)(unsigned short)low[5] << 16);
    pl[3] = (unsigned short)low[6] | ((unsigned)(unsigned short)low[7] << 16);
    ((uint4v*)hidH)[(size_t)nid * 16 + lane] = ph;   // normal store: keep L3-resident
    ((uint4v*)hidL)[(size_t)nid * 16 + lane] = pl;   // (read back by gemm_bfin)
}

// ---------------- gather 2: out = dinv*(self+sum nbrs) + bcat -> f32 mu|logvar ----------------
__global__ __launch_bounds__(TPB) void gather_out(const int* __restrict__ csr,
                                                  const int* __restrict__ rowptr,
                                                  const int* __restrict__ cnt,
                                                  const float* __restrict__ dinv,
                                                  const short* __restrict__ hs,
                                                  const float* __restrict__ bcat,
                                                  float* __restrict__ out, int N) {
    size_t t = (size_t)blockIdx.x * TPB + threadIdx.x;
    int nid = (int)(t >> 4);
    int lane = threadIdx.x & 15;
    if (nid >= N) return;
    int start = rowptr[nid];
    int deg = cnt[nid];
    const uint4v* hp = (const uint4v*)hs;
    float acc[8] = {0, 0, 0, 0, 0, 0, 0, 0};
    addrow(acc, hp[(size_t)nid * 16 + lane]);
    gather_accum(acc, csr, start, deg, hp, lane);
    float di = dinv[nid];
    float4 b0 = ((const float4*)bcat)[lane * 2];
    float4 b1v = ((const float4*)bcat)[lane * 2 + 1];
    floatx4 r0, r1;
    r0[0] = fmaf(di, acc[0], b0.x);
    r0[1] = fmaf(di, acc[1], b0.y);
    r0[2] = fmaf(di, acc[2], b0.z);
    r0[3] = fmaf(di, acc[3], b0.w);
    r1[0] = fmaf(di, acc[4], b1v.x);
    r1[1] = fmaf(di, acc[5], b1v.y);
    r1[2] = fmaf(di, acc[6], b1v.z);
    r1[3] = fmaf(di, acc[7], b1v.w);
    int f = lane * 8;  // 0..120
    float* dp = (f < 64) ? (out + (size_t)nid * 64 + f)
                         : (out + (size_t)N * 64 + (size_t)nid * 64 + (f - 64));
    __builtin_nontemporal_store(r0, (floatx4*)dp);    // final output: never re-read
    __builtin_nontemporal_store(r1, (floatx4*)(dp + 4));
}

extern "C" void kernel_launch(void* const* d_in, const int* in_sizes, int n_in,
                              void* d_out, int out_size, void* d_ws, size_t ws_size,
                              hipStream_t stream) {
    const float* x  = (const float*)d_in[0];
    const float* w1 = (const float*)d_in[1];
    const float* b1 = (const float*)d_in[2];
    const float* w2 = (const float*)d_in[3];
    const float* b2 = (const float*)d_in[4];
    const float* w3 = (const float*)d_in[5];
    const float* b3 = (const float*)d_in[6];
    const int*   ei = (const int*)d_in[7];

    const int N = in_sizes[0] / 256;   // 100000
    const int E = in_sizes[7] / 2;     // 1600000
    const int K1 = 256;

    float* out = (float*)d_out;

    // workspace carve-up (R8 layout)
    size_t nh = (size_t)N * 128;
    short* hs1    = (short*)d_ws;          // N*128 bf16
    short* hidH   = hs1 + nh;
    short* hidL   = hidH + nh;
    short* hs2    = hidL + nh;
    int*   cnt    = (int*)(hs2 + nh);
    float* dinv   = (float*)(cnt + N);
    int*   rowptr = (int*)(dinv + N);
    int*   cursor = rowptr + N;            // gcur[256]
    int*   bsum   = cursor + N;
    float* bcat   = (float*)(bsum + 512);
    short* w1t_h  = (short*)(bcat + 128);
    short* w1t_l  = w1t_h + 128 * 256;
    short* wct_h  = w1t_l + 128 * 256;
    short* wct_l  = wct_h + 128 * 128;
    int*   csr    = (int*)(wct_l + 128 * 128);

    const int* srcp = ei;
    const int* dstp = ei + E;

    const int ngrp = (N + GSIZE - 1) >> GSHIFT;   // 196
    int* gcur   = cursor;        // [256]
    int* staged = (int*)hs2;     // alias: 196*GCAP*4 = 9.6MB <= 25.6MB; dead by gemm_bfin

    // 1) prep (weights + bias + gcur zero)
    prep_all<<<193, TPB, 0, stream>>>(w1, w2, b2, w3, b3, w1t_h, w1t_l, wct_h, wct_l,
                                      bcat, gcur);

    // 2) CSR build: partition into fixed-CAP spans -> per-group finalize
    partition_kernel<<<(E + PART_M - 1) / PART_M, 256, 0, stream>>>(srcp, dstp, gcur,
                                                                    staged, E);
    build_csr<<<ngrp, 512, 0, stream>>>(staged, gcur, cnt, dinv, rowptr, csr, N);

    // 3) hs1 = (x @ w1) * dinv  -> bf16
    gemm_mfma_f32in<<<(N + 127) / 128, TPB, 0, stream>>>(x, w1t_h, w1t_l, dinv, hs1, N, K1);

    // 4) hidden = relu(dinv*(self+nbrs) + b1) -> hi/lo bf16
    size_t gthreads = (size_t)N * 16;
    gather_hidden<<<(unsigned)((gthreads + TPB - 1) / TPB), TPB, 0, stream>>>(
        csr, rowptr, cnt, dinv, hs1, b1, hidH, hidL, N);

    // 5) hs2 = (hidden @ wcat) * dinv -> bf16   (overwrites staged — dead by now)
    gemm_mfma_bfin<<<(N + 127) / 128, TPB, 0, stream>>>(hidH, hidL, wct_h, wct_l, dinv, hs2, N, 128);

    // 6) out = dinv*(self+nbrs) + bcat -> mu | logvar (f32)
    gather_out<<<(unsigned)((gthreads + TPB - 1) / TPB), TPB, 0, stream>>>(
        csr, rowptr, cnt, dinv, hs2, bcat, out, N);
}

// Round 11
// 374.487 us; speedup vs baseline: 1.2285x; 1.0167x over previous
//
#include <hip/hip_runtime.h>

// GCN-VAE encoder forward on MI355X — R14: block-range fusion of the serial chain.
//
// agg[d] = dinv[d] * ( dinv[d]*h[d] + sum_s dinv[s]*h[s] )
//
// R14: two fusions (no streams; independent work shares one dispatch):
//   A: prep (192 blocks) || partition (391 blocks). gcur zero -> memset.
//   B: build_csr256 (196 blocks) || gemm1 (782 blocks). Enabled by moving
//      the dinv scale OUT of gemm1 (stores raw bf16(h)); gather_hidden
//      multiplies each neighbor row by dinv[s] (fma-addrow, same inst count,
//      dinv L2-resident). build_csr reworked to 256 threads (pair scan).
//      Combined LDS 72KB -> still 2 blocks/CU. csr blocks schedule first,
//      hide under gemm1. 7 -> 5 dispatches.
//
// R13: fixed-capacity group spans (GCAP). R12: BM=128 GEMMs; NT only on out.
// R11: shfl-shared gather indices; direct-write partition.
// R9 post-mortem: NO gather/GEMM occupancy fusion. R8: gathers at
//   random-256B wall (~65.5us each; depth/issue/NT all null — accepted).
//
// ws: hs1[N*128]bf | hidH | hidL | hs2 (aliased staged during CSR build) |
//     cnt[N] | dinv[N] | rowptr[N] | cursor (gcur[256]) | bsum[512] |
//     bcat[128] | w1t_h/l | wct_h/l | csr[E]

#define TPB 256
#define GSHIFT 9
#define GSIZE 512
#define PART_M 4096   // edges per partition WG
#define GCAP 12288    // fixed staged span per group
#define NPREP 192     // prep blocks in kernel A

typedef __attribute__((ext_vector_type(8))) short short8;
typedef __attribute__((ext_vector_type(4))) short short4v;
typedef __attribute__((ext_vector_type(4))) float floatx4;
typedef __attribute__((ext_vector_type(4))) unsigned int uint4v;

__device__ __forceinline__ void split2(float v, short& hi, short& lo) {
    unsigned u = __float_as_uint(v);
    float hf = __uint_as_float(u & 0xFFFF0000u);
    float lf = v - hf;                       // exact
    hi = (short)(u >> 16);
    lo = (short)(__float_as_uint(lf) >> 16);
}

__device__ __forceinline__ short bf16_rtn(float v) {
    unsigned u = __float_as_uint(v);
    u += 0x7FFF + ((u >> 16) & 1);           // round to nearest even
    return (short)(u >> 16);
}

__device__ __forceinline__ void addrow(float* a, uint4v v) {
    a[0] += __uint_as_float(v[0] << 16); a[1] += __uint_as_float(v[0] & 0xFFFF0000u);
    a[2] += __uint_as_float(v[1] << 16); a[3] += __uint_as_float(v[1] & 0xFFFF0000u);
    a[4] += __uint_as_float(v[2] << 16); a[5] += __uint_as_float(v[2] & 0xFFFF0000u);
    a[6] += __uint_as_float(v[3] << 16); a[7] += __uint_as_float(v[3] & 0xFFFF0000u);
}

// scaled accumulate: a += s * row
__device__ __forceinline__ void addrow_s(float* a, uint4v v, float s) {
    a[0] = fmaf(s, __uint_as_float(v[0] << 16), a[0]);
    a[1] = fmaf(s, __uint_as_float(v[0] & 0xFFFF0000u), a[1]);
    a[2] = fmaf(s, __uint_as_float(v[1] << 16), a[2]);
    a[3] = fmaf(s, __uint_as_float(v[1] & 0xFFFF0000u), a[3]);
    a[4] = fmaf(s, __uint_as_float(v[2] << 16), a[4]);
    a[5] = fmaf(s, __uint_as_float(v[2] & 0xFFFF0000u), a[5]);
    a[6] = fmaf(s, __uint_as_float(v[3] << 16), a[6]);
    a[7] = fmaf(s, __uint_as_float(v[3] & 0xFFFF0000u), a[7]);
}

// unscaled gather (used by gather_out: hs2 already carries dinv)
__device__ __forceinline__ void gather_accum(float* acc, const int* __restrict__ csr,
                                             int start, int deg, const uint4v* hp,
                                             int l16) {
    for (int jj = 0; jj < deg; jj += 16) {
        int rem = deg - jj;
        if (rem > 16) rem = 16;
        int il = (l16 < rem) ? l16 : rem - 1;
        int myIdx = csr[start + jj + il];
        int r = 0;
        for (; r + 3 < rem; r += 4) {
            int i0 = __shfl(myIdx, r + 0, 16);
            int i1 = __shfl(myIdx, r + 1, 16);
            int i2 = __shfl(myIdx, r + 2, 16);
            int i3 = __shfl(myIdx, r + 3, 16);
            uint4v v0 = hp[(size_t)i0 * 16 + l16];
            uint4v v1 = hp[(size_t)i1 * 16 + l16];
            uint4v v2 = hp[(size_t)i2 * 16 + l16];
            uint4v v3 = hp[(size_t)i3 * 16 + l16];
            addrow(acc, v0);
            addrow(acc, v1);
            addrow(acc, v2);
            addrow(acc, v3);
        }
        for (; r < rem; ++r) {
            int i = __shfl(myIdx, r, 16);
            addrow(acc, hp[(size_t)i * 16 + l16]);
        }
    }
}

// dinv-scaled gather (gather_hidden: rows are raw h, scale by dinv[s])
__device__ __forceinline__ void gather_accum_s(float* acc, const int* __restrict__ csr,
                                               const float* __restrict__ dinv,
                                               int start, int deg, const uint4v* hp,
                                               int l16) {
    for (int jj = 0; jj < deg; jj += 16) {
        int rem = deg - jj;
        if (rem > 16) rem = 16;
        int il = (l16 < rem) ? l16 : rem - 1;
        int myIdx = csr[start + jj + il];
        float myD = dinv[myIdx];
        int r = 0;
        for (; r + 3 < rem; r += 4) {
            int i0 = __shfl(myIdx, r + 0, 16);
            int i1 = __shfl(myIdx, r + 1, 16);
            int i2 = __shfl(myIdx, r + 2, 16);
            int i3 = __shfl(myIdx, r + 3, 16);
            float d0 = __shfl(myD, r + 0, 16);
            float d1 = __shfl(myD, r + 1, 16);
            float d2 = __shfl(myD, r + 2, 16);
            float d3 = __shfl(myD, r + 3, 16);
            uint4v v0 = hp[(size_t)i0 * 16 + l16];
            uint4v v1 = hp[(size_t)i1 * 16 + l16];
            uint4v v2 = hp[(size_t)i2 * 16 + l16];
            uint4v v3 = hp[(size_t)i3 * 16 + l16];
            addrow_s(acc, v0, d0);
            addrow_s(acc, v1, d1);
            addrow_s(acc, v2, d2);
            addrow_s(acc, v3, d3);
        }
        for (; r < rem; ++r) {
            int i = __shfl(myIdx, r, 16);
            float d = __shfl(myD, r, 16);
            addrow_s(acc, hp[(size_t)i * 16 + l16], d);
        }
    }
}

// async 16B global -> LDS (linear dest: wave-uniform base + lane*16)
__device__ __forceinline__ void gload_lds16(const void* g, void* l) {
    __builtin_amdgcn_global_load_lds(
        (const __attribute__((address_space(1))) unsigned int*)g,
        (__attribute__((address_space(3))) unsigned int*)l, 16, 0, 0);
}

// ---------------- kernel A: prep (blocks 0..191) || partition (rest) ----------------
__global__ __launch_bounds__(TPB) void prep_part(const float* __restrict__ w1,
                                                 const float* __restrict__ w2,
                                                 const float* __restrict__ b2,
                                                 const float* __restrict__ w3,
                                                 const float* __restrict__ b3,
                                                 short* __restrict__ w1t_h,
                                                 short* __restrict__ w1t_l,
                                                 short* __restrict__ wct_h,
                                                 short* __restrict__ wct_l,
                                                 float* __restrict__ bcat,
                                                 const int* __restrict__ src,
                                                 const int* __restrict__ dst,
                                                 int* __restrict__ gcur,
                                                 int* __restrict__ staged, int E) {
    __shared__ int sc[256];
    __shared__ int cur[256];
    __shared__ int gb[256];
    int b = blockIdx.x, t = threadIdx.x;
    if (b < 128) {
        int i = b * TPB + t;                 // < 128*256
        int k = i & 255, n = i >> 8;
        float v = w1[(size_t)k * 128 + n];
        short h, l;
        split2(v, h, l);
        w1t_h[i] = h;
        w1t_l[i] = l;
        return;
    } else if (b < NPREP) {
        int i = (b - 128) * TPB + t;         // < 128*128
        int k = i & 127, n = i >> 7;
        float v = (n < 64) ? w2[(size_t)k * 64 + n] : w3[(size_t)k * 64 + (n - 64)];
        short h, l;
        split2(v, h, l);
        wct_h[i] = h;
        wct_l[i] = l;
        if (i < 64) { bcat[i] = b2[i]; bcat[64 + i] = b3[i]; }
        return;
    }
    // ---- partition path ----
    int base = (b - NPREP) * PART_M;
    int mloc = min(PART_M, E - base);
    int m4 = mloc >> 2;
    sc[t] = 0;
    cur[t] = 0;
    __syncthreads();
    const int4* d4 = (const int4*)(dst + base);
    const int4* s4 = (const int4*)(src + base);
    for (int k = t; k < m4; k += 256) {
        int4 v = d4[k];
        atomicAdd(&sc[v.x >> GSHIFT], 1);
        atomicAdd(&sc[v.y >> GSHIFT], 1);
        atomicAdd(&sc[v.z >> GSHIFT], 1);
        atomicAdd(&sc[v.w >> GSHIFT], 1);
    }
    for (int k = (m4 << 2) + t; k < mloc; k += 256)
        atomicAdd(&sc[dst[base + k] >> GSHIFT], 1);
    __syncthreads();
    int v = sc[t];
    gb[t] = v ? t * GCAP + atomicAdd(&gcur[t], v) : 0;   // exclusive span slice
    __syncthreads();
    for (int k = t; k < m4; k += 256) {
        int4 dv = d4[k];
        int4 sv = s4[k];
        int b0 = dv.x >> GSHIFT;
        staged[gb[b0] + atomicAdd(&cur[b0], 1)] = (sv.x << GSHIFT) | (dv.x & (GSIZE - 1));
        int b1 = dv.y >> GSHIFT;
        staged[gb[b1] + atomicAdd(&cur[b1], 1)] = (sv.y << GSHIFT) | (dv.y & (GSIZE - 1));
        int b2_ = dv.z >> GSHIFT;
        staged[gb[b2_] + atomicAdd(&cur[b2_], 1)] = (sv.z << GSHIFT) | (dv.z & (GSIZE - 1));
        int b3_ = dv.w >> GSHIFT;
        staged[gb[b3_] + atomicAdd(&cur[b3_], 1)] = (sv.w << GSHIFT) | (dv.w & (GSIZE - 1));
    }
    for (int k = (m4 << 2) + t; k < mloc; k += 256) {
        int d = dst[base + k];
        int s = src[base + k];
        int bb = d >> GSHIFT;
        staged[gb[bb] + atomicAdd(&cur[bb], 1)] = (s << GSHIFT) | (d & (GSIZE - 1));
    }
}

// ---------------- kernel B: build_csr256 (blocks 0..ngrp) || gemm1 (rest) ----------------
// gemm1 stores RAW bf16(h) (no dinv scale) -> independent of build_csr.
__global__ __launch_bounds__(TPB) void csr_gemm1(const int* __restrict__ staged,
                                                 const int* __restrict__ gcur,
                                                 int* __restrict__ cnt,
                                                 float* __restrict__ dinv,
                                                 int* __restrict__ rowptr,
                                                 int* __restrict__ csr,
                                                 const float* __restrict__ A,
                                                 const short* __restrict__ Bth,
                                                 const short* __restrict__ Btl,
                                                 short* __restrict__ Cb,
                                                 int N, int K, int ngrp) {
    // build_csr LDS (8KB) + gemm1 LDS (64KB) = 72KB static -> 2 blocks/CU
    __shared__ int pre[256];
    __shared__ int hist[512];
    __shared__ int psum[256];
    __shared__ int lrow[512];
    __shared__ int curq[512];
    __shared__ float Af[2][128 * 32];
    __shared__ short Bh[2][128 * 32];
    __shared__ short Bl[2][128 * 32];
    int t = threadIdx.x;

    if ((int)blockIdx.x < ngrp) {
        // ---- build_csr path (256 threads, one 512-node group) ----
        int g = blockIdx.x;
        pre[t] = (t < ngrp) ? gcur[t] : 0;
        hist[t] = 0;
        hist[t + 256] = 0;
        curq[t] = 0;
        curq[t + 256] = 0;
        __syncthreads();
#pragma unroll
        for (int off = 1; off < 256; off <<= 1) {
            int x = (t >= off) ? pre[t - off] : 0;
            __syncthreads();
            pre[t] += x;
            __syncthreads();
        }
        int count = gcur[g];
        int s0_out = pre[g] - count;     // exact exclusive offset into csr
        int s0_in = g * GCAP;
        for (int k = t; k < count; k += 256)
            atomicAdd(&hist[staged[s0_in + k] & (GSIZE - 1)], 1);
        __syncthreads();
        int h0 = hist[2 * t], h1 = hist[2 * t + 1];
        int ps = h0 + h1;
        psum[t] = ps;
        __syncthreads();
#pragma unroll
        for (int off = 1; off < 256; off <<= 1) {
            int x = (t >= off) ? psum[t - off] : 0;
            __syncthreads();
            psum[t] += x;
            __syncthreads();
        }
        int excl = psum[t] - ps;         // exclusive pair prefix
        int rp0 = s0_out + excl;
        int rp1 = rp0 + h0;
        lrow[2 * t] = rp0;
        lrow[2 * t + 1] = rp1;
        int node0 = (g << GSHIFT) + 2 * t;
        int node1 = node0 + 1;
        if (node0 < N) {
            rowptr[node0] = rp0;
            cnt[node0] = h0;
            dinv[node0] = rsqrtf(1.0f + (float)h0);
        }
        if (node1 < N) {
            rowptr[node1] = rp1;
            cnt[node1] = h1;
            dinv[node1] = rsqrtf(1.0f + (float)h1);
        }
        __syncthreads();
        for (int k = t; k < count; k += 256) {
            int p = staged[s0_in + k];
            int dl = p & (GSIZE - 1);
            int pos = lrow[dl] + atomicAdd(&curq[dl], 1);
            csr[pos] = p >> GSHIFT;
        }
        return;
    }

    // ---- gemm1 path: Cb[M,128]bf = bf16(A_f32 @ B), no scale ----
    int wave = t >> 6, lane = t & 63, quad = lane >> 4, l16 = lane & 15;
    int bm0 = ((int)blockIdx.x - ngrp) * 128;
    int M = N;

    floatx4 acc[2][8];
#pragma unroll
    for (int mt = 0; mt < 2; ++mt)
#pragma unroll
        for (int nt = 0; nt < 8; ++nt) acc[mt][nt] = (floatx4){0.f, 0.f, 0.f, 0.f};

    auto stage = [&](int pb, int k0) {
#pragma unroll
        for (int i = 0; i < 4; ++i) {          // A: 1024 granules
            int g = i * 256 + t;
            int row = g >> 3, col = g & 7;
            int gr = bm0 + row;
            if (gr >= M) gr = M - 1;
            int scol = col ^ (row & 7);
            gload_lds16(A + (size_t)gr * K + k0 + scol * 4,
                        &Af[pb][(i * 256 + wave * 64) * 4]);
        }
#pragma unroll
        for (int i = 0; i < 2; ++i) {          // B: 512 granules each
            int g = i * 256 + t;
            int row = g >> 2, col = g & 3;
            int scol = col ^ ((row >> 1) & 3);
            size_t off = (size_t)row * K + k0 + scol * 8;
            int lb = (i * 256 + wave * 64) * 8;
            gload_lds16(Bth + off, &Bh[pb][lb]);
            gload_lds16(Btl + off, &Bl[pb][lb]);
        }
    };

    int nk = K >> 5;
    stage(0, 0);
    __syncthreads();
    int r0 = wave * 32 + l16;
    int ac0 = ((quad * 2 + 0) ^ (r0 & 7)) * 4;
    int ac1 = ((quad * 2 + 1) ^ (r0 & 7)) * 4;
    int bc = (quad ^ ((l16 >> 1) & 3)) * 8;
    for (int ks = 0; ks < nk; ++ks) {
        int pb = ks & 1;
        if (ks + 1 < nk) stage(pb ^ 1, (ks + 1) << 5);
        short8 a_h[2], a_l[2];
#pragma unroll
        for (int mt = 0; mt < 2; ++mt) {
            int r = r0 + mt * 16;
            float4 fa0 = *(const float4*)&Af[pb][r * 32 + ac0];
            float4 fa1 = *(const float4*)&Af[pb][r * 32 + ac1];
            short h, l;
            split2(fa0.x, h, l); a_h[mt][0] = h; a_l[mt][0] = l;
            split2(fa0.y, h, l); a_h[mt][1] = h; a_l[mt][1] = l;
            split2(fa0.z, h, l); a_h[mt][2] = h; a_l[mt][2] = l;
            split2(fa0.w, h, l); a_h[mt][3] = h; a_l[mt][3] = l;
            split2(fa1.x, h, l); a_h[mt][4] = h; a_l[mt][4] = l;
            split2(fa1.y, h, l); a_h[mt][5] = h; a_l[mt][5] = l;
            split2(fa1.z, h, l); a_h[mt][6] = h; a_l[mt][6] = l;
            split2(fa1.w, h, l); a_h[mt][7] = h; a_l[mt][7] = l;
        }
#pragma unroll
        for (int nt = 0; nt < 8; ++nt) {
            int bn = nt * 16 + l16;
            short8 b_h = *(const short8*)&Bh[pb][bn * 32 + bc];
            short8 b_l = *(const short8*)&Bl[pb][bn * 32 + bc];
#pragma unroll
            for (int mt = 0; mt < 2; ++mt) {
                acc[mt][nt] = __builtin_amdgcn_mfma_f32_16x16x32_bf16(a_l[mt], b_h, acc[mt][nt], 0, 0, 0);
                acc[mt][nt] = __builtin_amdgcn_mfma_f32_16x16x32_bf16(a_h[mt], b_l, acc[mt][nt], 0, 0, 0);
                acc[mt][nt] = __builtin_amdgcn_mfma_f32_16x16x32_bf16(a_h[mt], b_h, acc[mt][nt], 0, 0, 0);
            }
        }
        __syncthreads();
    }
#pragma unroll
    for (int mt = 0; mt < 2; ++mt)
#pragma unroll
        for (int reg = 0; reg < 4; ++reg) {
            int gr = bm0 + wave * 32 + mt * 16 + quad * 4 + reg;
            if (gr < M) {
                short* cp = Cb + (size_t)gr * 128;
#pragma unroll
                for (int nt = 0; nt < 8; ++nt) cp[nt * 16 + l16] = bf16_rtn(acc[mt][nt][reg]);
            }
        }
}

// ---------------- MFMA GEMM2 (BM=128, pipelined): Cb = ((AH+AL) @ B) * rs ----------------
__global__ __launch_bounds__(TPB) void gemm_mfma_bfin(const short* __restrict__ AH,
                                                      const short* __restrict__ AL,
                                                      const short* __restrict__ Bth,
                                                      const short* __restrict__ Btl,
                                                      const float* __restrict__ rs,
                                                      short* __restrict__ Cb, int M, int K) {
    __shared__ short Ah[2][128 * 32], Al[2][128 * 32];  // 2 x 8KB each
    __shared__ short Bh[2][128 * 32], Bl[2][128 * 32];  // 2 x 8KB each
    int t = threadIdx.x;
    int wave = t >> 6, lane = t & 63, quad = lane >> 4, l16 = lane & 15;
    int bm0 = blockIdx.x * 128;

    floatx4 acc[2][8];
#pragma unroll
    for (int mt = 0; mt < 2; ++mt)
#pragma unroll
        for (int nt = 0; nt < 8; ++nt) acc[mt][nt] = (floatx4){0.f, 0.f, 0.f, 0.f};

    auto stage = [&](int pb, int k0) {
#pragma unroll
        for (int i = 0; i < 2; ++i) {          // A: 512 granules each (hi,lo)
            int g = i * 256 + t;
            int row = g >> 2, col = g & 3;
            int gr = bm0 + row;
            if (gr >= M) gr = M - 1;
            int scol = col ^ ((row >> 1) & 3);
            size_t off = (size_t)gr * K + k0 + scol * 8;
            int lb = (i * 256 + wave * 64) * 8;
            gload_lds16(AH + off, &Ah[pb][lb]);
            gload_lds16(AL + off, &Al[pb][lb]);
        }
#pragma unroll
        for (int i = 0; i < 2; ++i) {          // B: 512 granules each
            int g = i * 256 + t;
            int row = g >> 2, col = g & 3;
            int scol = col ^ ((row >> 1) & 3);
            size_t off = (size_t)row * K + k0 + scol * 8;
            int lb = (i * 256 + wave * 64) * 8;
            gload_lds16(Bth + off, &Bh[pb][lb]);
            gload_lds16(Btl + off, &Bl[pb][lb]);
        }
    };

    int nk = K >> 5;
    stage(0, 0);
    __syncthreads();
    int r0 = wave * 32 + l16;
    int ac = (quad ^ ((r0 >> 1) & 3)) * 8;
    int bc = (quad ^ ((l16 >> 1) & 3)) * 8;
    for (int ks = 0; ks < nk; ++ks) {
        int pb = ks & 1;
        if (ks + 1 < nk) stage(pb ^ 1, (ks + 1) << 5);
        short8 a_h[2], a_l[2];
#pragma unroll
        for (int mt = 0; mt < 2; ++mt) {
            int r = r0 + mt * 16;
            a_h[mt] = *(const short8*)&Ah[pb][r * 32 + ac];
            a_l[mt] = *(const short8*)&Al[pb][r * 32 + ac];
        }
#pragma unroll
        for (int nt = 0; nt < 8; ++nt) {
            int bn = nt * 16 + l16;
            short8 b_h = *(const short8*)&Bh[pb][bn * 32 + bc];
            short8 b_l = *(const short8*)&Bl[pb][bn * 32 + bc];
#pragma unroll
            for (int mt = 0; mt < 2; ++mt) {
                acc[mt][nt] = __builtin_amdgcn_mfma_f32_16x16x32_bf16(a_l[mt], b_h, acc[mt][nt], 0, 0, 0);
                acc[mt][nt] = __builtin_amdgcn_mfma_f32_16x16x32_bf16(a_h[mt], b_l, acc[mt][nt], 0, 0, 0);
                acc[mt][nt] = __builtin_amdgcn_mfma_f32_16x16x32_bf16(a_h[mt], b_h, acc[mt][nt], 0, 0, 0);
            }
        }
        __syncthreads();
    }
#pragma unroll
    for (int mt = 0; mt < 2; ++mt)
#pragma unroll
        for (int reg = 0; reg < 4; ++reg) {
            int gr = bm0 + wave * 32 + mt * 16 + quad * 4 + reg;
            if (gr < M) {
                float s = rs[gr];
                short* cp = Cb + (size_t)gr * 128;
#pragma unroll
                for (int nt = 0; nt < 8; ++nt) cp[nt * 16 + l16] = bf16_rtn(acc[mt][nt][reg] * s);
            }
        }
}

// ---------------- gather 1: hidden = relu(dinv*(dinv*h_self + sum dinv_s*h_s) + b1) ----------------
__global__ __launch_bounds__(TPB) void gather_hidden(const int* __restrict__ csr,
                                                     const int* __restrict__ rowptr,
                                                     const int* __restrict__ cnt,
                                                     const float* __restrict__ dinv,
                                                     const short* __restrict__ hs,
                                                     const float* __restrict__ b1,
                                                     short* __restrict__ hidH,
                                                     short* __restrict__ hidL, int N) {
    size_t t = (size_t)blockIdx.x * TPB + threadIdx.x;
    int nid = (int)(t >> 4);
    int lane = threadIdx.x & 15;
    if (nid >= N) return;
    int start = rowptr[nid];
    int deg = cnt[nid];
    float di = dinv[nid];
    const uint4v* hp = (const uint4v*)hs;  // row = 16 x 16B, raw h bf16
    float acc[8] = {0, 0, 0, 0, 0, 0, 0, 0};
    addrow_s(acc, hp[(size_t)nid * 16 + lane], di);      // self: dinv[d]*h[d]
    gather_accum_s(acc, csr, dinv, start, deg, hp, lane);
    float4 b0 = ((const float4*)b1)[lane * 2];
    float4 b1v = ((const float4*)b1)[lane * 2 + 1];
    float bb[8] = {b0.x, b0.y, b0.z, b0.w, b1v.x, b1v.y, b1v.z, b1v.w};
    unsigned hiw[8];
    short low[8];
#pragma unroll
    for (int i = 0; i < 8; ++i) {
        float h = fmaxf(fmaf(di, acc[i], bb[i]), 0.f);
        unsigned u = __float_as_uint(h);
        hiw[i] = u >> 16;
        float hf = __uint_as_float(u & 0xFFFF0000u);
        low[i] = bf16_rtn(h - hf);
    }
    uint4v ph, pl;
    ph[0] = hiw[0] | (hiw[1] << 16);
    ph[1] = hiw[2] | (hiw[3] << 16);
    ph[2] = hiw[4] | (hiw[5] << 16);
    ph[3] = hiw[6] | (hiw[7] << 16);
    pl[0] = (unsigned short)low[0] | ((unsigned)(unsigned short)low[1] << 16);
    pl[1] = (unsigned short)low[2] | ((unsigned)(unsigned short)low[3] << 16);
    pl[2] = (unsigned short)low[4] | ((unsigned)(unsigned short)low[5] << 16);
    pl[3] = (unsigned short)low[6] | ((unsigned)(unsigned short)low[7] << 16);
    ((uint4v*)hidH)[(size_t)nid * 16 + lane] = ph;   // normal store: keep L3-resident
    ((uint4v*)hidL)[(size_t)nid * 16 + lane] = pl;
}

// ---------------- gather 2: out = dinv*(self+sum nbrs) + bcat -> f32 mu|logvar ----------------
__global__ __launch_bounds__(TPB) void gather_out(const int* __restrict__ csr,
                                                  const int* __restrict__ rowptr,
                                                  const int* __restrict__ cnt,
                                                  const float* __restrict__ dinv,
                                                  const short* __restrict__ hs,
                                                  const float* __restrict__ bcat,
                                                  float* __restrict__ out, int N) {
    size_t t = (size_t)blockIdx.x * TPB + threadIdx.x;
    int nid = (int)(t >> 4);
    int lane = threadIdx.x & 15;
    if (nid >= N) return;
    int start = rowptr[nid];
    int deg = cnt[nid];
    const uint4v* hp = (const uint4v*)hs;   // hs2 already carries dinv
    float acc[8] = {0, 0, 0, 0, 0, 0, 0, 0};
    addrow(acc, hp[(size_t)nid * 16 + lane]);
    gather_accum(acc, csr, start, deg, hp, lane);
    float di = dinv[nid];
    float4 b0 = ((const float4*)bcat)[lane * 2];
    float4 b1v = ((const float4*)bcat)[lane * 2 + 1];
    floatx4 r0, r1;
    r0[0] = fmaf(di, acc[0], b0.x);
    r0[1] = fmaf(di, acc[1], b0.y);
    r0[2] = fmaf(di, acc[2], b0.z);
    r0[3] = fmaf(di, acc[3], b0.w);
    r1[0] = fmaf(di, acc[4], b1v.x);
    r1[1] = fmaf(di, acc[5], b1v.y);
    r1[2] = fmaf(di, acc[6], b1v.z);
    r1[3] = fmaf(di, acc[7], b1v.w);
    int f = lane * 8;  // 0..120
    float* dp = (f < 64) ? (out + (size_t)nid * 64 + f)
                         : (out + (size_t)N * 64 + (size_t)nid * 64 + (f - 64));
    __builtin_nontemporal_store(r0, (floatx4*)dp);    // final output: never re-read
    __builtin_nontemporal_store(r1, (floatx4*)(dp + 4));
}

extern "C" void kernel_launch(void* const* d_in, const int* in_sizes, int n_in,
                              void* d_out, int out_size, void* d_ws, size_t ws_size,
                              hipStream_t stream) {
    const float* x  = (const float*)d_in[0];
    const float* w1 = (const float*)d_in[1];
    const float* b1 = (const float*)d_in[2];
    const float* w2 = (const float*)d_in[3];
    const float* b2 = (const float*)d_in[4];
    const float* w3 = (const float*)d_in[5];
    const float* b3 = (const float*)d_in[6];
    const int*   ei = (const int*)d_in[7];

    const int N = in_sizes[0] / 256;   // 100000
    const int E = in_sizes[7] / 2;     // 1600000
    const int K1 = 256;

    float* out = (float*)d_out;

    // workspace carve-up (layout stable)
    size_t nh = (size_t)N * 128;
    short* hs1    = (short*)d_ws;          // N*128 bf16 (raw h)
    short* hidH   = hs1 + nh;
    short* hidL   = hidH + nh;
    short* hs2    = hidL + nh;
    int*   cnt    = (int*)(hs2 + nh);
    float* dinv   = (float*)(cnt + N);
    int*   rowptr = (int*)(dinv + N);
    int*   cursor = rowptr + N;            // gcur[256]
    int*   bsum   = cursor + N;
    float* bcat   = (float*)(bsum + 512);
    short* w1t_h  = (short*)(bcat + 128);
    short* w1t_l  = w1t_h + 128 * 256;
    short* wct_h  = w1t_l + 128 * 256;
    short* wct_l  = wct_h + 128 * 128;
    int*   csr    = (int*)(wct_l + 128 * 128);

    const int* srcp = ei;
    const int* dstp = ei + E;

    const int ngrp = (N + GSIZE - 1) >> GSHIFT;   // 196
    int* gcur   = cursor;        // [256]
    int* staged = (int*)hs2;     // alias: 9.6MB; dead before gemm_bfin writes hs2

    // 0) zero group cursors (needed before kernel A's partition blocks)
    hipMemsetAsync(gcur, 0, 256 * sizeof(int), stream);

    // 1) A: prep (192 blocks) || partition
    int nPart = (E + PART_M - 1) / PART_M;
    prep_part<<<NPREP + nPart, TPB, 0, stream>>>(w1, w2, b2, w3, b3, w1t_h, w1t_l,
                                                 wct_h, wct_l, bcat, srcp, dstp, gcur,
                                                 staged, E);

    // 2) B: build_csr (196 blocks, schedule first) || gemm1 (782 blocks)
    int gtiles = (N + 127) / 128;
    csr_gemm1<<<ngrp + gtiles, TPB, 0, stream>>>(staged, gcur, cnt, dinv, rowptr, csr,
                                                 x, w1t_h, w1t_l, hs1, N, K1, ngrp);

    // 3) hidden = relu(dinv*(dinv*h_self + sum dinv_s*h_s) + b1) -> hi/lo bf16
    size_t gthreads = (size_t)N * 16;
    gather_hidden<<<(unsigned)((gthreads + TPB - 1) / TPB), TPB, 0, stream>>>(
        csr, rowptr, cnt, dinv, hs1, b1, hidH, hidL, N);

    // 4) hs2 = (hidden @ wcat) * dinv -> bf16   (overwrites staged — dead by now)
    gemm_mfma_bfin<<<(N + 127) / 128, TPB, 0, stream>>>(hidH, hidL, wct_h, wct_l, dinv, hs2, N, 128);

    // 5) out = dinv*(self+nbrs) + bcat -> mu | logvar (f32)
    gather_out<<<(unsigned)((gthreads + TPB - 1) / TPB), TPB, 0, stream>>>(
        csr, rowptr, cnt, dinv, hs2, bcat, out, N);
}

// Round 12
// 372.340 us; speedup vs baseline: 1.2356x; 1.0058x over previous
//
#include <hip/hip_runtime.h>

// GCN-VAE encoder forward on MI355X — R15: occupancy fix for csr_gemm1.
//
// agg[d] = dinv[d] * ( dinv[d]*h[d] + sum_s dinv[s]*h[s] )
//
// R15: csr_gemm1 was latency-bound (69.5us, MfmaUtil 11%, occ 15.8%,
//   2 blocks/CU at 72KB LDS). Fix: gemm1 path BM 128->64 (R6 geometry,
//   48KB dbuf) + LDS UNION with the csr path (8KB overlays the gemm
//   buffers; the two paths never share a block) -> 48KB/block ->
//   3 blocks/CU = 12 waves/CU, 1563 finer tiles.
//
// R14: prep||partition fused; build_csr||gemm1 fused (dinv moved out of
//   gemm1 into gather_hidden's fma-gather). R13: fixed-capacity spans.
// R12: gemm_bfin BM=128 (kept; L3-hot A); NT only on final out store.
// R11: shfl-shared gather indices. R9: NO gather/GEMM occupancy fusion.
// R8: gathers at random-256B wall (~66us each) — accepted.
//
// ws: hs1[N*128]bf | hidH | hidL | hs2 (aliased staged during CSR build) |
//     cnt[N] | dinv[N] | rowptr[N] | cursor (gcur[256]) | bsum[512] |
//     bcat[128] | w1t_h/l | wct_h/l | csr[E]

#define TPB 256
#define GSHIFT 9
#define GSIZE 512
#define PART_M 4096   // edges per partition WG
#define GCAP 12288    // fixed staged span per group
#define NPREP 192     // prep blocks in kernel A

typedef __attribute__((ext_vector_type(8))) short short8;
typedef __attribute__((ext_vector_type(4))) short short4v;
typedef __attribute__((ext_vector_type(4))) float floatx4;
typedef __attribute__((ext_vector_type(4))) unsigned int uint4v;

__device__ __forceinline__ void split2(float v, short& hi, short& lo) {
    unsigned u = __float_as_uint(v);
    float hf = __uint_as_float(u & 0xFFFF0000u);
    float lf = v - hf;                       // exact
    hi = (short)(u >> 16);
    lo = (short)(__float_as_uint(lf) >> 16);
}

__device__ __forceinline__ short bf16_rtn(float v) {
    unsigned u = __float_as_uint(v);
    u += 0x7FFF + ((u >> 16) & 1);           // round to nearest even
    return (short)(u >> 16);
}

__device__ __forceinline__ void addrow(float* a, uint4v v) {
    a[0] += __uint_as_float(v[0] << 16); a[1] += __uint_as_float(v[0] & 0xFFFF0000u);
    a[2] += __uint_as_float(v[1] << 16); a[3] += __uint_as_float(v[1] & 0xFFFF0000u);
    a[4] += __uint_as_float(v[2] << 16); a[5] += __uint_as_float(v[2] & 0xFFFF0000u);
    a[6] += __uint_as_float(v[3] << 16); a[7] += __uint_as_float(v[3] & 0xFFFF0000u);
}

// scaled accumulate: a += s * row
__device__ __forceinline__ void addrow_s(float* a, uint4v v, float s) {
    a[0] = fmaf(s, __uint_as_float(v[0] << 16), a[0]);
    a[1] = fmaf(s, __uint_as_float(v[0] & 0xFFFF0000u), a[1]);
    a[2] = fmaf(s, __uint_as_float(v[1] << 16), a[2]);
    a[3] = fmaf(s, __uint_as_float(v[1] & 0xFFFF0000u), a[3]);
    a[4] = fmaf(s, __uint_as_float(v[2] << 16), a[4]);
    a[5] = fmaf(s, __uint_as_float(v[2] & 0xFFFF0000u), a[5]);
    a[6] = fmaf(s, __uint_as_float(v[3] << 16), a[6]);
    a[7] = fmaf(s, __uint_as_float(v[3] & 0xFFFF0000u), a[7]);
}

// unscaled gather (gather_out: hs2 already carries dinv)
__device__ __forceinline__ void gather_accum(float* acc, const int* __restrict__ csr,
                                             int start, int deg, const uint4v* hp,
                                             int l16) {
    for (int jj = 0; jj < deg; jj += 16) {
        int rem = deg - jj;
        if (rem > 16) rem = 16;
        int il = (l16 < rem) ? l16 : rem - 1;
        int myIdx = csr[start + jj + il];
        int r = 0;
        for (; r + 3 < rem; r += 4) {
            int i0 = __shfl(myIdx, r + 0, 16);
            int i1 = __shfl(myIdx, r + 1, 16);
            int i2 = __shfl(myIdx, r + 2, 16);
            int i3 = __shfl(myIdx, r + 3, 16);
            uint4v v0 = hp[(size_t)i0 * 16 + l16];
            uint4v v1 = hp[(size_t)i1 * 16 + l16];
            uint4v v2 = hp[(size_t)i2 * 16 + l16];
            uint4v v3 = hp[(size_t)i3 * 16 + l16];
            addrow(acc, v0);
            addrow(acc, v1);
            addrow(acc, v2);
            addrow(acc, v3);
        }
        for (; r < rem; ++r) {
            int i = __shfl(myIdx, r, 16);
            addrow(acc, hp[(size_t)i * 16 + l16]);
        }
    }
}

// dinv-scaled gather (gather_hidden: rows are raw h, scale by dinv[s])
__device__ __forceinline__ void gather_accum_s(float* acc, const int* __restrict__ csr,
                                               const float* __restrict__ dinv,
                                               int start, int deg, const uint4v* hp,
                                               int l16) {
    for (int jj = 0; jj < deg; jj += 16) {
        int rem = deg - jj;
        if (rem > 16) rem = 16;
        int il = (l16 < rem) ? l16 : rem - 1;
        int myIdx = csr[start + jj + il];
        float myD = dinv[myIdx];
        int r = 0;
        for (; r + 3 < rem; r += 4) {
            int i0 = __shfl(myIdx, r + 0, 16);
            int i1 = __shfl(myIdx, r + 1, 16);
            int i2 = __shfl(myIdx, r + 2, 16);
            int i3 = __shfl(myIdx, r + 3, 16);
            float d0 = __shfl(myD, r + 0, 16);
            float d1 = __shfl(myD, r + 1, 16);
            float d2 = __shfl(myD, r + 2, 16);
            float d3 = __shfl(myD, r + 3, 16);
            uint4v v0 = hp[(size_t)i0 * 16 + l16];
            uint4v v1 = hp[(size_t)i1 * 16 + l16];
            uint4v v2 = hp[(size_t)i2 * 16 + l16];
            uint4v v3 = hp[(size_t)i3 * 16 + l16];
            addrow_s(acc, v0, d0);
            addrow_s(acc, v1, d1);
            addrow_s(acc, v2, d2);
            addrow_s(acc, v3, d3);
        }
        for (; r < rem; ++r) {
            int i = __shfl(myIdx, r, 16);
            float d = __shfl(myD, r, 16);
            addrow_s(acc, hp[(size_t)i * 16 + l16], d);
        }
    }
}

// async 16B global -> LDS (linear dest: wave-uniform base + lane*16)
__device__ __forceinline__ void gload_lds16(const void* g, void* l) {
    __builtin_amdgcn_global_load_lds(
        (const __attribute__((address_space(1))) unsigned int*)g,
        (__attribute__((address_space(3))) unsigned int*)l, 16, 0, 0);
}

// ---------------- kernel A: prep (blocks 0..191) || partition (rest) ----------------
__global__ __launch_bounds__(TPB) void prep_part(const float* __restrict__ w1,
                                                 const float* __restrict__ w2,
                                                 const float* __restrict__ b2,
                                                 const float* __restrict__ w3,
                                                 const float* __restrict__ b3,
                                                 short* __restrict__ w1t_h,
                                                 short* __restrict__ w1t_l,
                                                 short* __restrict__ wct_h,
                                                 short* __restrict__ wct_l,
                                                 float* __restrict__ bcat,
                                                 const int* __restrict__ src,
                                                 const int* __restrict__ dst,
                                                 int* __restrict__ gcur,
                                                 int* __restrict__ staged, int E) {
    __shared__ int sc[256];
    __shared__ int cur[256];
    __shared__ int gb[256];
    int b = blockIdx.x, t = threadIdx.x;
    if (b < 128) {
        int i = b * TPB + t;                 // < 128*256
        int k = i & 255, n = i >> 8;
        float v = w1[(size_t)k * 128 + n];
        short h, l;
        split2(v, h, l);
        w1t_h[i] = h;
        w1t_l[i] = l;
        return;
    } else if (b < NPREP) {
        int i = (b - 128) * TPB + t;         // < 128*128
        int k = i & 127, n = i >> 7;
        float v = (n < 64) ? w2[(size_t)k * 64 + n] : w3[(size_t)k * 64 + (n - 64)];
        short h, l;
        split2(v, h, l);
        wct_h[i] = h;
        wct_l[i] = l;
        if (i < 64) { bcat[i] = b2[i]; bcat[64 + i] = b3[i]; }
        return;
    }
    // ---- partition path ----
    int base = (b - NPREP) * PART_M;
    int mloc = min(PART_M, E - base);
    int m4 = mloc >> 2;
    sc[t] = 0;
    cur[t] = 0;
    __syncthreads();
    const int4* d4 = (const int4*)(dst + base);
    const int4* s4 = (const int4*)(src + base);
    for (int k = t; k < m4; k += 256) {
        int4 v = d4[k];
        atomicAdd(&sc[v.x >> GSHIFT], 1);
        atomicAdd(&sc[v.y >> GSHIFT], 1);
        atomicAdd(&sc[v.z >> GSHIFT], 1);
        atomicAdd(&sc[v.w >> GSHIFT], 1);
    }
    for (int k = (m4 << 2) + t; k < mloc; k += 256)
        atomicAdd(&sc[dst[base + k] >> GSHIFT], 1);
    __syncthreads();
    int v = sc[t];
    gb[t] = v ? t * GCAP + atomicAdd(&gcur[t], v) : 0;   // exclusive span slice
    __syncthreads();
    for (int k = t; k < m4; k += 256) {
        int4 dv = d4[k];
        int4 sv = s4[k];
        int b0 = dv.x >> GSHIFT;
        staged[gb[b0] + atomicAdd(&cur[b0], 1)] = (sv.x << GSHIFT) | (dv.x & (GSIZE - 1));
        int b1 = dv.y >> GSHIFT;
        staged[gb[b1] + atomicAdd(&cur[b1], 1)] = (sv.y << GSHIFT) | (dv.y & (GSIZE - 1));
        int b2_ = dv.z >> GSHIFT;
        staged[gb[b2_] + atomicAdd(&cur[b2_], 1)] = (sv.z << GSHIFT) | (dv.z & (GSIZE - 1));
        int b3_ = dv.w >> GSHIFT;
        staged[gb[b3_] + atomicAdd(&cur[b3_], 1)] = (sv.w << GSHIFT) | (dv.w & (GSIZE - 1));
    }
    for (int k = (m4 << 2) + t; k < mloc; k += 256) {
        int d = dst[base + k];
        int s = src[base + k];
        int bb = d >> GSHIFT;
        staged[gb[bb] + atomicAdd(&cur[bb], 1)] = (s << GSHIFT) | (d & (GSIZE - 1));
    }
}

// ---------------- kernel B: build_csr256 (blocks 0..ngrp) || gemm1 BM=64 (rest) ----------------
// gemm1 stores RAW bf16(h) (no dinv scale). LDS: 48KB UNION (csr 8KB overlays
// the gemm buffers; paths never share a block) -> 3 blocks/CU.
__global__ __launch_bounds__(TPB) void csr_gemm1(const int* __restrict__ staged,
                                                 const int* __restrict__ gcur,
                                                 int* __restrict__ cnt,
                                                 float* __restrict__ dinv,
                                                 int* __restrict__ rowptr,
                                                 int* __restrict__ csr,
                                                 const float* __restrict__ A,
                                                 const short* __restrict__ Bth,
                                                 const short* __restrict__ Btl,
                                                 short* __restrict__ Cb,
                                                 int N, int K, int ngrp) {
    __shared__ __align__(16) char smem[49152];   // 48KB union
    int t = threadIdx.x;

    if ((int)blockIdx.x < ngrp) {
        // ---- build_csr path (256 threads, one 512-node group; 8KB of smem) ----
        int* pre  = (int*)smem;        // [256]
        int* hist = pre + 256;         // [512]
        int* psum = hist + 512;        // [256]
        int* lrow = psum + 256;        // [512]
        int* curq = lrow + 512;        // [512]
        int g = blockIdx.x;
        pre[t] = (t < ngrp) ? gcur[t] : 0;
        hist[t] = 0;
        hist[t + 256] = 0;
        curq[t] = 0;
        curq[t + 256] = 0;
        __syncthreads();
#pragma unroll
        for (int off = 1; off < 256; off <<= 1) {
            int x = (t >= off) ? pre[t - off] : 0;
            __syncthreads();
            pre[t] += x;
            __syncthreads();
        }
        int count = gcur[g];
        int s0_out = pre[g] - count;     // exact exclusive offset into csr
        int s0_in = g * GCAP;
        for (int k = t; k < count; k += 256)
            atomicAdd(&hist[staged[s0_in + k] & (GSIZE - 1)], 1);
        __syncthreads();
        int h0 = hist[2 * t], h1 = hist[2 * t + 1];
        int ps = h0 + h1;
        psum[t] = ps;
        __syncthreads();
#pragma unroll
        for (int off = 1; off < 256; off <<= 1) {
            int x = (t >= off) ? psum[t - off] : 0;
            __syncthreads();
            psum[t] += x;
            __syncthreads();
        }
        int excl = psum[t] - ps;         // exclusive pair prefix
        int rp0 = s0_out + excl;
        int rp1 = rp0 + h0;
        lrow[2 * t] = rp0;
        lrow[2 * t + 1] = rp1;
        int node0 = (g << GSHIFT) + 2 * t;
        int node1 = node0 + 1;
        if (node0 < N) {
            rowptr[node0] = rp0;
            cnt[node0] = h0;
            dinv[node0] = rsqrtf(1.0f + (float)h0);
        }
        if (node1 < N) {
            rowptr[node1] = rp1;
            cnt[node1] = h1;
            dinv[node1] = rsqrtf(1.0f + (float)h1);
        }
        __syncthreads();
        for (int k = t; k < count; k += 256) {
            int p = staged[s0_in + k];
            int dl = p & (GSIZE - 1);
            int pos = lrow[dl] + atomicAdd(&curq[dl], 1);
            csr[pos] = p >> GSHIFT;
        }
        return;
    }

    // ---- gemm1 path (BM=64, R6 geometry): Cb[M,128]bf = bf16(A_f32 @ B) ----
    float* Af = (float*)smem;                 // [2][64*32]  16KB
    short* Bh = (short*)(smem + 16384);       // [2][128*32] 16KB
    short* Bl = (short*)(smem + 32768);       // [2][128*32] 16KB
    int wave = t >> 6, lane = t & 63, quad = lane >> 4, l16 = lane & 15;
    int bm0 = ((int)blockIdx.x - ngrp) * 64;
    int M = N;

    floatx4 acc[8];
#pragma unroll
    for (int nt = 0; nt < 8; ++nt) acc[nt] = (floatx4){0.f, 0.f, 0.f, 0.f};

    auto stage = [&](int pb, int k0) {
#pragma unroll
        for (int i = 0; i < 2; ++i) {          // A: 512 granules of 16B
            int g = i * 256 + t;
            int row = g >> 3, col = g & 7;
            int gr = bm0 + row;
            if (gr >= M) gr = M - 1;
            int scol = col ^ (row & 7);
            gload_lds16(A + (size_t)gr * K + k0 + scol * 4,
                        &Af[pb * 2048 + (i * 256 + wave * 64) * 4]);
        }
#pragma unroll
        for (int i = 0; i < 2; ++i) {          // B: 512 granules each
            int g = i * 256 + t;
            int row = g >> 2, col = g & 3;
            int scol = col ^ ((row >> 1) & 3);
            size_t off = (size_t)row * K + k0 + scol * 8;
            int lb = (i * 256 + wave * 64) * 8;
            gload_lds16(Bth + off, &Bh[pb * 4096 + lb]);
            gload_lds16(Btl + off, &Bl[pb * 4096 + lb]);
        }
    };

    int nk = K >> 5;
    stage(0, 0);
    __syncthreads();
    int am = wave * 16 + l16;
    int ac0 = ((quad * 2 + 0) ^ (am & 7)) * 4;
    int ac1 = ((quad * 2 + 1) ^ (am & 7)) * 4;
    int bc = (quad ^ ((l16 >> 1) & 3)) * 8;
    for (int ks = 0; ks < nk; ++ks) {
        int pb = ks & 1;
        if (ks + 1 < nk) stage(pb ^ 1, (ks + 1) << 5);
        float4 fa0 = *(const float4*)&Af[pb * 2048 + am * 32 + ac0];
        float4 fa1 = *(const float4*)&Af[pb * 2048 + am * 32 + ac1];
        short8 a_h, a_l;
        {
            short h, l;
            split2(fa0.x, h, l); a_h[0] = h; a_l[0] = l;
            split2(fa0.y, h, l); a_h[1] = h; a_l[1] = l;
            split2(fa0.z, h, l); a_h[2] = h; a_l[2] = l;
            split2(fa0.w, h, l); a_h[3] = h; a_l[3] = l;
            split2(fa1.x, h, l); a_h[4] = h; a_l[4] = l;
            split2(fa1.y, h, l); a_h[5] = h; a_l[5] = l;
            split2(fa1.z, h, l); a_h[6] = h; a_l[6] = l;
            split2(fa1.w, h, l); a_h[7] = h; a_l[7] = l;
        }
#pragma unroll
        for (int nt = 0; nt < 8; ++nt) {
            int bn = nt * 16 + l16;
            short8 b_h = *(const short8*)&Bh[pb * 4096 + bn * 32 + bc];
            short8 b_l = *(const short8*)&Bl[pb * 4096 + bn * 32 + bc];
            acc[nt] = __builtin_amdgcn_mfma_f32_16x16x32_bf16(a_l, b_h, acc[nt], 0, 0, 0);
            acc[nt] = __builtin_amdgcn_mfma_f32_16x16x32_bf16(a_h, b_l, acc[nt], 0, 0, 0);
            acc[nt] = __builtin_amdgcn_mfma_f32_16x16x32_bf16(a_h, b_h, acc[nt], 0, 0, 0);
        }
        __syncthreads();
    }
#pragma unroll
    for (int reg = 0; reg < 4; ++reg) {
        int gr = bm0 + wave * 16 + quad * 4 + reg;
        if (gr < M) {
            short* cp = Cb + (size_t)gr * 128;
#pragma unroll
            for (int nt = 0; nt < 8; ++nt) cp[nt * 16 + l16] = bf16_rtn(acc[nt][reg]);
        }
    }
}

// ---------------- MFMA GEMM2 (BM=128, pipelined): Cb = ((AH+AL) @ B) * rs ----------------
__global__ __launch_bounds__(TPB) void gemm_mfma_bfin(const short* __restrict__ AH,
                                                      const short* __restrict__ AL,
                                                      const short* __restrict__ Bth,
                                                      const short* __restrict__ Btl,
                                                      const float* __restrict__ rs,
                                                      short* __restrict__ Cb, int M, int K) {
    __shared__ short Ah[2][128 * 32], Al[2][128 * 32];  // 2 x 8KB each
    __shared__ short Bh[2][128 * 32], Bl[2][128 * 32];  // 2 x 8KB each
    int t = threadIdx.x;
    int wave = t >> 6, lane = t & 63, quad = lane >> 4, l16 = lane & 15;
    int bm0 = blockIdx.x * 128;

    floatx4 acc[2][8];
#pragma unroll
    for (int mt = 0; mt < 2; ++mt)
#pragma unroll
        for (int nt = 0; nt < 8; ++nt) acc[mt][nt] = (floatx4){0.f, 0.f, 0.f, 0.f};

    auto stage = [&](int pb, int k0) {
#pragma unroll
        for (int i = 0; i < 2; ++i) {          // A: 512 granules each (hi,lo)
            int g = i * 256 + t;
            int row = g >> 2, col = g & 3;
            int gr = bm0 + row;
            if (gr >= M) gr = M - 1;
            int scol = col ^ ((row >> 1) & 3);
            size_t off = (size_t)gr * K + k0 + scol * 8;
            int lb = (i * 256 + wave * 64) * 8;
            gload_lds16(AH + off, &Ah[pb][lb]);
            gload_lds16(AL + off, &Al[pb][lb]);
        }
#pragma unroll
        for (int i = 0; i < 2; ++i) {          // B: 512 granules each
            int g = i * 256 + t;
            int row = g >> 2, col = g & 3;
            int scol = col ^ ((row >> 1) & 3);
            size_t off = (size_t)row * K + k0 + scol * 8;
            int lb = (i * 256 + wave * 64) * 8;
            gload_lds16(Bth + off, &Bh[pb][lb]);
            gload_lds16(Btl + off, &Bl[pb][lb]);
        }
    };

    int nk = K >> 5;
    stage(0, 0);
    __syncthreads();
    int r0 = wave * 32 + l16;
    int ac = (quad ^ ((r0 >> 1) & 3)) * 8;
    int bc = (quad ^ ((l16 >> 1) & 3)) * 8;
    for (int ks = 0; ks < nk; ++ks) {
        int pb = ks & 1;
        if (ks + 1 < nk) stage(pb ^ 1, (ks + 1) << 5);
        short8 a_h[2], a_l[2];
#pragma unroll
        for (int mt = 0; mt < 2; ++mt) {
            int r = r0 + mt * 16;
            a_h[mt] = *(const short8*)&Ah[pb][r * 32 + ac];
            a_l[mt] = *(const short8*)&Al[pb][r * 32 + ac];
        }
#pragma unroll
        for (int nt = 0; nt < 8; ++nt) {
            int bn = nt * 16 + l16;
            short8 b_h = *(const short8*)&Bh[pb][bn * 32 + bc];
            short8 b_l = *(const short8*)&Bl[pb][bn * 32 + bc];
#pragma unroll
            for (int mt = 0; mt < 2; ++mt) {
                acc[mt][nt] = __builtin_amdgcn_mfma_f32_16x16x32_bf16(a_l[mt], b_h, acc[mt][nt], 0, 0, 0);
                acc[mt][nt] = __builtin_amdgcn_mfma_f32_16x16x32_bf16(a_h[mt], b_l, acc[mt][nt], 0, 0, 0);
                acc[mt][nt] = __builtin_amdgcn_mfma_f32_16x16x32_bf16(a_h[mt], b_h, acc[mt][nt], 0, 0, 0);
            }
        }
        __syncthreads();
    }
#pragma unroll
    for (int mt = 0; mt < 2; ++mt)
#pragma unroll
        for (int reg = 0; reg < 4; ++reg) {
            int gr = bm0 + wave * 32 + mt * 16 + quad * 4 + reg;
            if (gr < M) {
                float s = rs[gr];
                short* cp = Cb + (size_t)gr * 128;
#pragma unroll
                for (int nt = 0; nt < 8; ++nt) cp[nt * 16 + l16] = bf16_rtn(acc[mt][nt][reg] * s);
            }
        }
}

// ---------------- gather 1: hidden = relu(dinv*(dinv*h_self + sum dinv_s*h_s) + b1) ----------------
__global__ __launch_bounds__(TPB) void gather_hidden(const int* __restrict__ csr,
                                                     const int* __restrict__ rowptr,
                                                     const int* __restrict__ cnt,
                                                     const float* __restrict__ dinv,
                                                     const short* __restrict__ hs,
                                                     const float* __restrict__ b1,
                                                     short* __restrict__ hidH,
                                                     short* __restrict__ hidL, int N) {
    size_t t = (size_t)blockIdx.x * TPB + threadIdx.x;
    int nid = (int)(t >> 4);
    int lane = threadIdx.x & 15;
    if (nid >= N) return;
    int start = rowptr[nid];
    int deg = cnt[nid];
    float di = dinv[nid];
    const uint4v* hp = (const uint4v*)hs;  // row = 16 x 16B, raw h bf16
    float acc[8] = {0, 0, 0, 0, 0, 0, 0, 0};
    addrow_s(acc, hp[(size_t)nid * 16 + lane], di);      // self: dinv[d]*h[d]
    gather_accum_s(acc, csr, dinv, start, deg, hp, lane);
    float4 b0 = ((const float4*)b1)[lane * 2];
    float4 b1v = ((const float4*)b1)[lane * 2 + 1];
    float bb[8] = {b0.x, b0.y, b0.z, b0.w, b1v.x, b1v.y, b1v.z, b1v.w};
    unsigned hiw[8];
    short low[8];
#pragma unroll
    for (int i = 0; i < 8; ++i) {
        float h = fmaxf(fmaf(di, acc[i], bb[i]), 0.f);
        unsigned u = __float_as_uint(h);
        hiw[i] = u >> 16;
        float hf = __uint_as_float(u & 0xFFFF0000u);
        low[i] = bf16_rtn(h - hf);
    }
    uint4v ph, pl;
    ph[0] = hiw[0] | (hiw[1] << 16);
    ph[1] = hiw[2] | (hiw[3] << 16);
    ph[2] = hiw[4] | (hiw[5] << 16);
    ph[3] = hiw[6] | (hiw[7] << 16);
    pl[0] = (unsigned short)low[0] | ((unsigned)(unsigned short)low[1] << 16);
    pl[1] = (unsigned short)low[2] | ((unsigned)(unsigned short)low[3] << 16);
    pl[2] = (unsigned short)low[4] | ((unsigned)(unsigned short)low[5] << 16);
    pl[3] = (unsigned short)low[6] | ((unsigned)(unsigned short)low[7] << 16);
    ((uint4v*)hidH)[(size_t)nid * 16 + lane] = ph;   // normal store: keep L3-resident
    ((uint4v*)hidL)[(size_t)nid * 16 + lane] = pl;
}

// ---------------- gather 2: out = dinv*(self+sum nbrs) + bcat -> f32 mu|logvar ----------------
__global__ __launch_bounds__(TPB) void gather_out(const int* __restrict__ csr,
                                                  const int* __restrict__ rowptr,
                                                  const int* __restrict__ cnt,
                                                  const float* __restrict__ dinv,
                                                  const short* __restrict__ hs,
                                                  const float* __restrict__ bcat,
                                                  float* __restrict__ out, int N) {
    size_t t = (size_t)blockIdx.x * TPB + threadIdx.x;
    int nid = (int)(t >> 4);
    int lane = threadIdx.x & 15;
    if (nid >= N) return;
    int start = rowptr[nid];
    int deg = cnt[nid];
    const uint4v* hp = (const uint4v*)hs;   // hs2 already carries dinv
    float acc[8] = {0, 0, 0, 0, 0, 0, 0, 0};
    addrow(acc, hp[(size_t)nid * 16 + lane]);
    gather_accum(acc, csr, start, deg, hp, lane);
    float di = dinv[nid];
    float4 b0 = ((const float4*)bcat)[lane * 2];
    float4 b1v = ((const float4*)bcat)[lane * 2 + 1];
    floatx4 r0, r1;
    r0[0] = fmaf(di, acc[0], b0.x);
    r0[1] = fmaf(di, acc[1], b0.y);
    r0[2] = fmaf(di, acc[2], b0.z);
    r0[3] = fmaf(di, acc[3], b0.w);
    r1[0] = fmaf(di, acc[4], b1v.x);
    r1[1] = fmaf(di, acc[5], b1v.y);
    r1[2] = fmaf(di, acc[6], b1v.z);
    r1[3] = fmaf(di, acc[7], b1v.w);
    int f = lane * 8;  // 0..120
    float* dp = (f < 64) ? (out + (size_t)nid * 64 + f)
                         : (out + (size_t)N * 64 + (size_t)nid * 64 + (f - 64));
    __builtin_nontemporal_store(r0, (floatx4*)dp);    // final output: never re-read
    __builtin_nontemporal_store(r1, (floatx4*)(dp + 4));
}

extern "C" void kernel_launch(void* const* d_in, const int* in_sizes, int n_in,
                              void* d_out, int out_size, void* d_ws, size_t ws_size,
                              hipStream_t stream) {
    const float* x  = (const float*)d_in[0];
    const float* w1 = (const float*)d_in[1];
    const float* b1 = (const float*)d_in[2];
    const float* w2 = (const float*)d_in[3];
    const float* b2 = (const float*)d_in[4];
    const float* w3 = (const float*)d_in[5];
    const float* b3 = (const float*)d_in[6];
    const int*   ei = (const int*)d_in[7];

    const int N = in_sizes[0] / 256;   // 100000
    const int E = in_sizes[7] / 2;     // 1600000
    const int K1 = 256;

    float* out = (float*)d_out;

    // workspace carve-up (layout stable)
    size_t nh = (size_t)N * 128;
    short* hs1    = (short*)d_ws;          // N*128 bf16 (raw h)
    short* hidH   = hs1 + nh;
    short* hidL   = hidH + nh;
    short* hs2    = hidL + nh;
    int*   cnt    = (int*)(hs2 + nh);
    float* dinv   = (float*)(cnt + N);
    int*   rowptr = (int*)(dinv + N);
    int*   cursor = rowptr + N;            // gcur[256]
    int*   bsum   = cursor + N;
    float* bcat   = (float*)(bsum + 512);
    short* w1t_h  = (short*)(bcat + 128);
    short* w1t_l  = w1t_h + 128 * 256;
    short* wct_h  = w1t_l + 128 * 256;
    short* wct_l  = wct_h + 128 * 128;
    int*   csr    = (int*)(wct_l + 128 * 128);

    const int* srcp = ei;
    const int* dstp = ei + E;

    const int ngrp = (N + GSIZE - 1) >> GSHIFT;   // 196
    int* gcur   = cursor;        // [256]
    int* staged = (int*)hs2;     // alias: 9.6MB; dead before gemm_bfin writes hs2

    // 0) zero group cursors (needed before kernel A's partition blocks)
    hipMemsetAsync(gcur, 0, 256 * sizeof(int), stream);

    // 1) A: prep (192 blocks) || partition
    int nPart = (E + PART_M - 1) / PART_M;
    prep_part<<<NPREP + nPart, TPB, 0, stream>>>(w1, w2, b2, w3, b3, w1t_h, w1t_l,
                                                 wct_h, wct_l, bcat, srcp, dstp, gcur,
                                                 staged, E);

    // 2) B: build_csr (196 blocks) || gemm1 BM=64 (1563 blocks)
    int gtiles = (N + 63) / 64;
    csr_gemm1<<<ngrp + gtiles, TPB, 0, stream>>>(staged, gcur, cnt, dinv, rowptr, csr,
                                                 x, w1t_h, w1t_l, hs1, N, K1, ngrp);

    // 3) hidden = relu(dinv*(dinv*h_self + sum dinv_s*h_s) + b1) -> hi/lo bf16
    size_t gthreads = (size_t)N * 16;
    gather_hidden<<<(unsigned)((gthreads + TPB - 1) / TPB), TPB, 0, stream>>>(
        csr, rowptr, cnt, dinv, hs1, b1, hidH, hidL, N);

    // 4) hs2 = (hidden @ wcat) * dinv -> bf16   (overwrites staged — dead by now)
    gemm_mfma_bfin<<<(N + 127) / 128, TPB, 0, stream>>>(hidH, hidL, wct_h, wct_l, dinv, hs2, N, 128);

    // 5) out = dinv*(self+nbrs) + bcat -> mu | logvar (f32)
    gather_out<<<(unsigned)((gthreads + TPB - 1) / TPB), TPB, 0, stream>>>(
        csr, rowptr, cnt, dinv, hs2, bcat, out, N);
}